// Round 1
// baseline (2944.259 us; speedup 1.0000x reference)
//
#include <hip/hip_runtime.h>
#include <hip/hip_bf16.h>

typedef __hip_bfloat16 bf16;

constexpr int NN = 307, TT = 12, BB = 32, HH = 64, EE = 10, HEADS = 4, HD = 16, HORIZON = 12;

// ---------------- staged fp32 input offsets ----------------
constexpr int S_SRC = 0,       S_EMB = 117888,  S_GW0 = 120958,  S_GB0 = 287358,
              S_UW0 = 288638,  S_UB0 = 371838,  S_GW1 = 372478,  S_GB1 = 700158,
              S_UW1 = 701438,  S_UB1 = 865278,  S_MLW = 865918,  S_MLB = 865982,
              S_WQ  = 866046,  S_BQ  = 870142,  S_WK  = 870206,  S_BK  = 874302,
              S_WV  = 874366,  S_BV  = 878462,  S_WO  = 878526,  S_BO  = 882622,
              S_FW1 = 882686,  S_FB1 = 948222,  S_FW2 = 949246,  S_FB2 = 1014782,
              S_L1G = 1014846, S_L1B = 1014910, S_L2G = 1014974, S_L2B = 1015038,
              S_WS  = 1015102, S_WT  = 1034750, S_CW  = 1054398, S_CB  = 1055166;

// ---------------- fp32 work regions ----------------
constexpr size_t OFF_A    = 1055178;   // 307*307
constexpr size_t OFF_OUT0 = 1149427;   // [t][n][b][c] 12*307*2048
constexpr size_t OFF_H0   = 8694259;   // [n][b][c] 307*2048 (layer 0)
constexpr size_t OFF_ZH0  = 9322995;
constexpr size_t OFF_R0   = 9951731;
constexpr size_t OFF_AX0  = 11209203;  // [t][n][b] 12*307*32
constexpr size_t OFF_AX1  = 11327091;  // [t][n][b][c] 12*307*2048
constexpr size_t OFF_PE   = 18871923;  // 12*64
constexpr size_t OFF_OLN  = 18872691;
constexpr size_t OFF_O2   = 19501427;
constexpr size_t OFF_WB   = 20130164;  // fp32 reordered per-node GRU weights

// Reordered weight blocks (fp32; bf16 storage fails: scan amplifies to 0.19 absmax — r3)
constexpr size_t G0X = OFF_WB +        0;  // 307*2*128
constexpr size_t G0H = OFF_WB +    78592;  // 307*128*128
constexpr size_t BG0 = OFF_WB +  5108480;  // 307*128
constexpr size_t U0X = OFF_WB +  5147776;  // 307*2*64
constexpr size_t U0H = OFF_WB +  5187072;  // 307*128*64
constexpr size_t BU0 = OFF_WB +  7702016;  // 307*64
constexpr size_t G1X = OFF_WB +  7721664;  // 307*128*128
constexpr size_t G1H = OFF_WB + 12751552;  // 307*128*128
constexpr size_t BG1 = OFF_WB + 17781440;  // 307*128
constexpr size_t U1X = OFF_WB + 17820736;  // 307*128*64
constexpr size_t U1H = OFF_WB + 20335680;  // 307*128*64
constexpr size_t BU1 = OFF_WB + 22850624;  // 307*64
constexpr size_t OFF_GXP = OFF_WB + 22870272;       // [t][n][b][128] L0 preact x-part (bias folded)
constexpr size_t OFF_UXP = OFF_GXP + 15089664;      // [t][n][b][64]
constexpr size_t OFF_H1  = OFF_UXP + 7544832;       // layer-1 state buffers
constexpr size_t OFF_ZH1 = OFF_H1  + 628736;
constexpr size_t OFF_R1  = OFF_ZH1 + 628736;
constexpr size_t OFF_AGG0 = OFF_R1  + 628736;       // A@H (or A@ZH) per layer
constexpr size_t OFF_AGG1 = OFF_AGG0 + 628736;
constexpr size_t G_TOTAL  = OFF_AGG1 + 628736 + 4096;

// r12->r13: (a) k_ffn rewritten — phase1 i4-blocked (float4 broadcast ox reads,
// 4-j register tile: 128 FMA per 8 ds_b128 + 16 glb), phase2 j-split across the
// 4 waves (w2 loaded once per block instead of 4x) + cross-wave LDS reduction
// reusing hid[] (LDS unchanged 34KB). (b) k_attn i4-blocked the same way.
// (c) k_gateM/k_updM: register double-buffer of the W chunk staging (prefetch
// chunk c+1 into regs during compute of c) — hides the per-chunk global-load
// latency that sync->load->sync->compute exposed 8x/4x per block per dispatch.
// Arithmetic order preserved (chunk order, m ascending); ffn/attn reassociate
// fp32 dot4 partials only (~1e-6, absmax dominated by bf16 I/O at 2e-3).

__device__ float g_buf[G_TOTAL];
__device__ int g_flag;   // 1 = inputs are bf16, 0 = fp32

__device__ __forceinline__ float wave_sum(float v) {
    #pragma unroll
    for (int off = 32; off > 0; off >>= 1) v += __shfl_xor(v, off, 64);
    return v;
}

// ---------------- dtype detection ----------------
__global__ void k_detect(const void* emb_raw) {
    const bf16* p = (const bf16*)emb_raw;
    int lane = threadIdx.x;
    float v = __bfloat162float(p[lane]);
    bool plaus = (v == v) && (fabsf(v) <= 1e4f) && (v == 0.f || fabsf(v) >= 1e-4f);
    float c = wave_sum(plaus ? 1.f : 0.f);
    if (lane == 0) g_flag = (c >= 52.f) ? 1 : 0;
}

// ---------------- ingest all inputs as fp32 ----------------
struct PtrPack { const void* p[32]; };
__device__ const int D_CNT[32] = {117888,3070,166400,1280,83200,640,327680,1280,163840,640,
                                  64,64,4096,64,4096,64,4096,64,4096,64,
                                  65536,1024,65536,64,64,64,64,64,19648,19648,768,12};
__device__ const int D_OFF[32] = {S_SRC,S_EMB,S_GW0,S_GB0,S_UW0,S_UB0,S_GW1,S_GB1,S_UW1,S_UB1,
                                  S_MLW,S_MLB,S_WQ,S_BQ,S_WK,S_BK,S_WV,S_BV,S_WO,S_BO,
                                  S_FW1,S_FB1,S_FW2,S_FB2,S_L1G,S_L1B,S_L2G,S_L2B,S_WS,S_WT,S_CW,S_CB};
__device__ const int D_CHK[33] = {0,461,473,1123,1128,1453,1456,2736,2741,3381,3384,3385,3386,
                                  3402,3403,3419,3420,3436,3437,3453,3454,3710,3714,3970,3971,
                                  3972,3973,3974,3975,4052,4129,4132,4133};

__global__ void k_ingest(PtrPack pk) {
    int bid = blockIdx.x;
    int s = 0;
    while (s < 31 && bid >= D_CHK[s + 1]) s++;
    int i = (bid - D_CHK[s]) * 256 + threadIdx.x;
    if (i >= D_CNT[s]) return;
    float v;
    if (g_flag) v = __bfloat162float(((const bf16*)pk.p[s])[i]);
    else        v = ((const float*)pk.p[s])[i];
    g_buf[(size_t)D_OFF[s] + i] = v;
}

// ---------------- adjacency ----------------
__global__ void k_adj() {
    int n = blockIdx.x;
    int tid = threadIdx.x;            // 512
    __shared__ float en[EE];
    __shared__ float red[512];
    if (tid < EE) en[tid] = g_buf[S_EMB + n * EE + tid];
    __syncthreads();
    bool act = tid < NN;
    float d = 0.f;
    if (act) {
        #pragma unroll
        for (int e = 0; e < EE; e++) d += en[e] * g_buf[S_EMB + tid * EE + e];
        d = fmaxf(d, 0.f);
    }
    red[tid] = act ? d : -1e30f;
    __syncthreads();
    for (int s = 256; s > 0; s >>= 1) { if (tid < s) red[tid] = fmaxf(red[tid], red[tid + s]); __syncthreads(); }
    float mx = red[0];
    __syncthreads();
    float ex = act ? expf(d - mx) : 0.f;
    red[tid] = ex;
    __syncthreads();
    for (int s = 256; s > 0; s >>= 1) { if (tid < s) red[tid] += red[tid + s]; __syncthreads(); }
    float inv = 1.f / red[0];
    if (act) g_buf[OFF_A + (size_t)n * NN + tid] = ex * inv;
}

// ---------------- per-node GRU weights -> fp32, reordered into Wx/Wh blocks ----------------
__device__ const unsigned SEGC[9] = {0u,5108480u,5147776u,7702016u,7721664u,17781440u,17820736u,22850624u,22870272u};
__device__ const int SEGJ[8]      = {16640,128,8320,64,32768,128,16384,64};
__device__ const int SEGS[8]      = {S_GW0,S_GB0,S_UW0,S_UB0,S_GW1,S_GB1,S_UW1,S_UB1};

__global__ void k_nodew_all() {
    unsigned idx = blockIdx.x * 256u + threadIdx.x;
    if (idx >= 22870272u) return;
    int s = 0;
    while (s < 7 && idx >= SEGC[s + 1]) s++;
    unsigned rem = idx - SEGC[s];
    unsigned J = (unsigned)SEGJ[s];
    unsigned n = rem / J;
    unsigned j = rem - n * J;
    float acc = 0.f;
    const float* eb = g_buf + S_EMB + n * EE;
    const float* w  = g_buf + SEGS[s];
    #pragma unroll
    for (int e = 0; e < EE; e++) acc += eb[e] * w[(size_t)e * J + j];
    size_t dst;
    if (s == 0) {        // gw0: j = (k*65+i)*128+o
        unsigned o = j & 127, kk = j >> 7, k = kk / 65, i = kk % 65;
        dst = (i == 0) ? G0X + ((size_t)n * 2 + k) * 128 + o
                       : G0H + ((size_t)n * 128 + k * 64 + (i - 1)) * 128 + o;
    } else if (s == 1) { dst = BG0 + (size_t)n * 128 + j;
    } else if (s == 2) { // uw0: j = (k*65+i)*64+o
        unsigned o = j & 63, kk = j >> 6, k = kk / 65, i = kk % 65;
        dst = (i == 0) ? U0X + ((size_t)n * 2 + k) * 64 + o
                       : U0H + ((size_t)n * 128 + k * 64 + (i - 1)) * 64 + o;
    } else if (s == 3) { dst = BU0 + (size_t)n * 64 + j;
    } else if (s == 4) { // gw1: j = (k*128+i)*128+o
        unsigned o = j & 127, kk = j >> 7, k = kk >> 7, i = kk & 127;
        dst = (i < 64) ? G1X + ((size_t)n * 128 + k * 64 + i) * 128 + o
                       : G1H + ((size_t)n * 128 + k * 64 + (i - 64)) * 128 + o;
    } else if (s == 5) { dst = BG1 + (size_t)n * 128 + j;
    } else if (s == 6) { // uw1: j = (k*128+i)*64+o
        unsigned o = j & 63, kk = j >> 6, k = kk >> 7, i = kk & 127;
        dst = (i < 64) ? U1X + ((size_t)n * 128 + k * 64 + i) * 64 + o
                       : U1H + ((size_t)n * 128 + k * 64 + (i - 64)) * 64 + o;
    } else {             dst = BU1 + (size_t)n * 64 + j; }
    g_buf[dst] = acc;
}

// ---------------- positional embedding ----------------
__global__ void k_pe() {
    int tid = threadIdx.x;            // 768
    int t = tid >> 6, h = tid & 63;
    float ex = (float)(h & ~1) / 64.f;
    float ang = (float)t * powf(10000.f, -ex);
    g_buf[OFF_PE + tid] = (h & 1) ? cosf(ang) : sinf(ang);
}

__global__ void k_zero(size_t off, int cnt) {
    int i = blockIdx.x * 256 + threadIdx.x;
    if (i < cnt) g_buf[off + i] = 0.f;
}

// ---------------- AX0[t][n][b] = sum_m A[n,m] * src[b,t,m] ----------------
__global__ __launch_bounds__(256) void k_ax0() {
    int t = blockIdx.y;
    int n0 = blockIdx.x * 8;
    int b = threadIdx.x & 31, nl = threadIdx.x >> 5;
    __shared__ float As[8][68];
    __shared__ float xs[32][65];
    float acc = 0.f;
    for (int m0 = 0; m0 < NN; m0 += 64) {
        int jend = min(64, NN - m0);
        for (int idx = threadIdx.x; idx < 8 * 64; idx += 256) {
            int i = idx >> 6, jj = idx & 63;
            int n = n0 + i, m = m0 + jj;
            As[i][jj] = (n < NN && m < NN) ? g_buf[OFF_A + (size_t)n * NN + m] : 0.f;
        }
        for (int idx = threadIdx.x; idx < 32 * 64; idx += 256) {
            int bb = idx >> 6, jj = idx & 63;
            int m = m0 + jj;
            xs[bb][jj] = (m < NN) ? g_buf[S_SRC + ((size_t)bb * TT + t) * NN + m] : 0.f;
        }
        __syncthreads();
        for (int jj = 0; jj < jend; jj++) acc += As[nl][jj] * xs[b][jj];
        __syncthreads();
    }
    int n = n0 + nl;
    if (n < NN) g_buf[OFF_AX0 + ((size_t)t * NN + n) * 32 + b] = acc;
}

// ---------------- batched agg GEMM: z selects job ----------------
// mode 0 (z<3): H0->AGG0, H1->AGG1, OUT0[s-1]->AX1[s-1]
// mode 1 (z<2): ZH0->AGG0, ZH1->AGG1
__global__ __launch_bounds__(256) void k_aggB(int s, int mode) {
    int z = blockIdx.z;
    size_t srcOff, dstOff;
    if (mode == 0) {
        if (z == 0)      { srcOff = OFF_H0; dstOff = OFF_AGG0; }
        else if (z == 1) { srcOff = OFF_H1; dstOff = OFF_AGG1; }
        else             { srcOff = OFF_OUT0 + (size_t)(s - 1) * 628736;
                           dstOff = OFF_AX1  + (size_t)(s - 1) * 628736; }
    } else {
        srcOff = z ? OFF_ZH1 : OFF_ZH0;
        dstOff = z ? OFF_AGG1 : OFF_AGG0;
    }
    const float* __restrict__ srcp = g_buf + srcOff;
    float* __restrict__ dstp = g_buf + dstOff;
    int n0 = blockIdx.x * 64;
    int col0 = blockIdx.y * 64;
    int tid = threadIdx.x;
    int tn = tid >> 4, tc = tid & 15;
    __shared__ float As[32][68];
    __shared__ float Xs[32][64];
    float acc[4][4];
    #pragma unroll
    for (int i = 0; i < 4; i++)
        #pragma unroll
        for (int j = 0; j < 4; j++) acc[i][j] = 0.f;
    for (int k0 = 0; k0 < NN; k0 += 32) {
        for (int idx = tid; idx < 64 * 32; idx += 256) {
            int k = idx & 31, i = idx >> 5;
            int n = n0 + i, m = k0 + k;
            As[k][i] = (n < NN && m < NN) ? g_buf[OFF_A + (size_t)n * NN + m] : 0.f;
        }
        for (int idx = tid; idx < 32 * 64; idx += 256) {
            int c = idx & 63, k = idx >> 6;
            int m = k0 + k;
            Xs[k][c] = (m < NN) ? srcp[(size_t)m * 2048 + col0 + c] : 0.f;
        }
        __syncthreads();
        #pragma unroll
        for (int k = 0; k < 32; k++) {
            float4 a4 = *(const float4*)&As[k][tn * 4];
            float4 x4 = *(const float4*)&Xs[k][tc * 4];
            const float* aa = (const float*)&a4;
            const float* xx = (const float*)&x4;
            #pragma unroll
            for (int i = 0; i < 4; i++)
                #pragma unroll
                for (int j = 0; j < 4; j++) acc[i][j] += aa[i] * xx[j];
        }
        __syncthreads();
    }
    #pragma unroll
    for (int i = 0; i < 4; i++) {
        int n = n0 + tn * 4 + i;
        if (n < NN) {
            float4 v = make_float4(acc[i][0], acc[i][1], acc[i][2], acc[i][3]);
            *(float4*)&dstp[(size_t)n * 2048 + col0 + tc * 4] = v;
        }
    }
}

// ---------------- x-part preact precompute, layer 0 (K=2); grid (12, NN) ----------------
__global__ __launch_bounds__(256) void k_xprep0() {
    int t = blockIdx.x, n = blockIdx.y, tid = threadIdx.x;
    __shared__ float xv[32], ax[32];
    if (tid < 32) {
        xv[tid] = g_buf[S_SRC + ((size_t)tid * TT + t) * NN + n];
        ax[tid] = g_buf[OFF_AX0 + ((size_t)t * NN + n) * 32 + tid];
    }
    __syncthreads();
    size_t pbase = ((size_t)t * NN + n) * 32;
    for (int idx = tid; idx < 4096; idx += 256) {
        int b = idx >> 7, o = idx & 127;
        g_buf[OFF_GXP + (pbase + b) * 128 + o] =
            g_buf[BG0 + (size_t)n * 128 + o]
          + g_buf[G0X + ((size_t)n * 2 + 0) * 128 + o] * xv[b]
          + g_buf[G0X + ((size_t)n * 2 + 1) * 128 + o] * ax[b];
    }
    for (int idx = tid; idx < 2048; idx += 256) {
        int b = idx >> 6, o = idx & 63;
        g_buf[OFF_UXP + (pbase + b) * 64 + o] =
            g_buf[BU0 + (size_t)n * 64 + o]
          + g_buf[U0X + ((size_t)n * 2 + 0) * 64 + o] * xv[b]
          + g_buf[U0X + ((size_t)n * 2 + 1) * 64 + o] * ax[b];
    }
}

// ======== merged pipelined gate (reg-double-buffered W staging) ========
// smem: xh 32*136 | xx 32*136 | Wl 32*128
__global__ __launch_bounds__(256) void k_gateM(int s) {
    __shared__ float smem[12800];
    float* xh = smem;
    float* xx = smem + 4352;
    float* Wl = smem + 8704;
    int lay = (blockIdx.x >= NN) ? 1 : 0;
    int n = blockIdx.x - lay * NN;
    int t = lay ? (s - 1) : s;
    if (t < 0 || t >= TT) return;
    int tid = threadIdx.x;
    size_t Hoff = lay ? OFF_H1 : OFF_H0;
    size_t Aoff = lay ? OFF_AGG1 : OFF_AGG0;
    for (int idx = tid; idx < 4096; idx += 256) {
        int bl = idx >> 7, c = idx & 127;
        float v = (c < 64) ? g_buf[Hoff + (size_t)n * 2048 + bl * 64 + c]
                           : g_buf[Aoff + (size_t)n * 2048 + bl * 64 + (c - 64)];
        xh[bl * 136 + c] = v;
    }
    if (lay) {
        size_t pb = ((size_t)t * NN + n) * 2048;
        for (int idx = tid; idx < 4096; idx += 256) {
            int bl = idx >> 7, c = idx & 127;
            float v = (c < 64) ? g_buf[OFF_OUT0 + pb + bl * 64 + c]
                               : g_buf[OFF_AX1 + pb + bl * 64 + (c - 64)];
            xx[bl * 136 + c] = v;
        }
    }
    // flattened chunk list (same pass order as r12)
    const float* Wc[2]; const float* Xc[2]; int np = 0;
    if (lay) {
        Wc[0] = g_buf + G1X + (size_t)n * 16384; Xc[0] = xx; np = 1;
        if (t > 0) { Wc[1] = g_buf + G1H + (size_t)n * 16384; Xc[1] = xh; np = 2; }
    } else if (t > 0) {
        Wc[0] = g_buf + G0H + (size_t)n * 16384; Xc[0] = xh; np = 1;
    }
    int nch = np * 4;
    float4 wr0, wr1, wr2, wr3;
    if (nch) {
        const float4* ws = (const float4*)Wc[0];
        wr0 = ws[tid]; wr1 = ws[tid + 256]; wr2 = ws[tid + 512]; wr3 = ws[tid + 768];
    }
    __syncthreads();
    int o = tid & 63, bl0 = (tid >> 6) * 8;
    size_t pbase = ((size_t)t * NN + n) * 32;
    float accz[8], accr[8];
    if (lay) {
        #pragma unroll
        for (int j = 0; j < 8; j++) {
            accz[j] = g_buf[BG1 + (size_t)n * 128 + o];
            accr[j] = g_buf[BG1 + (size_t)n * 128 + o + 64];
        }
    } else {
        #pragma unroll
        for (int j = 0; j < 8; j++) {
            accz[j] = g_buf[OFF_GXP + (pbase + bl0 + j) * 128 + o];
            accr[j] = g_buf[OFF_GXP + (pbase + bl0 + j) * 128 + o + 64];
        }
    }
    for (int c = 0; c < nch; c++) {
        __syncthreads();                       // prev compute done reading Wl
        float4* wdst = (float4*)Wl;
        wdst[tid] = wr0; wdst[tid + 256] = wr1; wdst[tid + 512] = wr2; wdst[tid + 768] = wr3;
        if (c + 1 < nch) {                     // prefetch next chunk -> regs (overlaps compute)
            const float4* ws = (const float4*)Wc[(c + 1) >> 2] + ((c + 1) & 3) * 1024;
            wr0 = ws[tid]; wr1 = ws[tid + 256]; wr2 = ws[tid + 512]; wr3 = ws[tid + 768];
        }
        __syncthreads();                       // Wl ready
        const float* X = Xc[c >> 2];
        int ch = c & 3;
        #pragma unroll 4
        for (int kq = 0; kq < 32; kq += 4) {
            float4 xv[8];
            #pragma unroll
            for (int j = 0; j < 8; j++) xv[j] = *(const float4*)&X[(bl0 + j) * 136 + ch * 32 + kq];
            #pragma unroll
            for (int q = 0; q < 4; q++) {
                float w0 = Wl[(kq + q) * 128 + o];
                float w1 = Wl[(kq + q) * 128 + o + 64];
                #pragma unroll
                for (int j = 0; j < 8; j++) {
                    float xxv = ((const float*)&xv[j])[q];
                    accz[j] += xxv * w0;
                    accr[j] += xxv * w1;
                }
            }
        }
    }
    size_t ZHoff = lay ? OFF_ZH1 : OFF_ZH0;
    size_t Roff  = lay ? OFF_R1 : OFF_R0;
    #pragma unroll
    for (int j = 0; j < 8; j++) {
        int b = bl0 + j;
        float z = 1.f / (1.f + expf(-accz[j]));
        float r = 1.f / (1.f + expf(-accr[j]));
        float hv = xh[b * 136 + o];
        g_buf[ZHoff + (size_t)n * 2048 + (size_t)b * 64 + o] = z * hv;
        g_buf[Roff  + (size_t)n * 2048 + (size_t)b * 64 + o] = r;
    }
}

// ======== merged pipelined update (reg-double-buffered W staging) ========
__global__ __launch_bounds__(256) void k_updM(int s) {
    __shared__ float smem[10752];
    float* xh = smem;
    float* xx = smem + 4352;
    float* Wl = smem + 8704;   // 32*64
    int lay = (blockIdx.x >= NN) ? 1 : 0;
    int n = blockIdx.x - lay * NN;
    int t = lay ? (s - 1) : s;
    if (t < 0 || t >= TT) return;
    int tid = threadIdx.x;
    size_t ZHoff = lay ? OFF_ZH1 : OFF_ZH0;
    size_t Aoff  = lay ? OFF_AGG1 : OFF_AGG0;
    for (int idx = tid; idx < 4096; idx += 256) {
        int bl = idx >> 7, c = idx & 127;
        float v = (c < 64) ? g_buf[ZHoff + (size_t)n * 2048 + bl * 64 + c]
                           : g_buf[Aoff + (size_t)n * 2048 + bl * 64 + (c - 64)];
        xh[bl * 136 + c] = v;
    }
    if (lay) {
        size_t pb = ((size_t)t * NN + n) * 2048;
        for (int idx = tid; idx < 4096; idx += 256) {
            int bl = idx >> 7, c = idx & 127;
            float v = (c < 64) ? g_buf[OFF_OUT0 + pb + bl * 64 + c]
                               : g_buf[OFF_AX1 + pb + bl * 64 + (c - 64)];
            xx[bl * 136 + c] = v;
        }
    }
    const float* Wc[2]; const float* Xc[2]; int np = 0;
    if (lay) {
        Wc[0] = g_buf + U1X + (size_t)n * 8192; Xc[0] = xx; np = 1;
        if (t > 0) { Wc[1] = g_buf + U1H + (size_t)n * 8192; Xc[1] = xh; np = 2; }
    } else if (t > 0) {
        Wc[0] = g_buf + U0H + (size_t)n * 8192; Xc[0] = xh; np = 1;
    }
    int nch = np * 4;
    float4 wr0, wr1;
    if (nch) {
        const float4* ws = (const float4*)Wc[0];
        wr0 = ws[tid]; wr1 = ws[tid + 256];
    }
    __syncthreads();
    int o = tid & 63, bl0 = (tid >> 6) * 8;
    size_t pbase = ((size_t)t * NN + n) * 32;
    float acc[8];
    if (lay) {
        #pragma unroll
        for (int j = 0; j < 8; j++) acc[j] = g_buf[BU1 + (size_t)n * 64 + o];
    } else {
        #pragma unroll
        for (int j = 0; j < 8; j++) acc[j] = g_buf[OFF_UXP + (pbase + bl0 + j) * 64 + o];
    }
    for (int c = 0; c < nch; c++) {
        __syncthreads();
        float4* wdst = (float4*)Wl;
        wdst[tid] = wr0; wdst[tid + 256] = wr1;
        if (c + 1 < nch) {
            const float4* ws = (const float4*)Wc[(c + 1) >> 2] + ((c + 1) & 3) * 512;
            wr0 = ws[tid]; wr1 = ws[tid + 256];
        }
        __syncthreads();
        const float* X = Xc[c >> 2];
        int ch = c & 3;
        #pragma unroll 4
        for (int kq = 0; kq < 32; kq += 4) {
            float4 xv[8];
            #pragma unroll
            for (int j = 0; j < 8; j++) xv[j] = *(const float4*)&X[(bl0 + j) * 136 + ch * 32 + kq];
            #pragma unroll
            for (int q = 0; q < 4; q++) {
                float w = Wl[(kq + q) * 64 + o];
                #pragma unroll
                for (int j = 0; j < 8; j++) acc[j] += ((const float*)&xv[j])[q] * w;
            }
        }
    }
    size_t Hoff = lay ? OFF_H1 : OFF_H0;
    size_t Roff = lay ? OFF_R1 : OFF_R0;
    #pragma unroll
    for (int j = 0; j < 8; j++) {
        int b = bl0 + j;
        size_t base = (size_t)n * 2048 + (size_t)b * 64 + o;
        float hc = tanhf(acc[j]);
        float r = g_buf[Roff + base];
        float hold = g_buf[Hoff + base];
        float hn = r * hold + (1.f - r) * hc;
        g_buf[Hoff + base] = hn;
        if (!lay) g_buf[OFF_OUT0 + (pbase + b) * 64 + o] = hn;
    }
}

// ---------------- fused attention (t=T-1 only) + LN1; 4 (b,n) per block ----------------
// r13: i4-blocked projection — float4 broadcast x reads (13 ds_b128 vs 52 ds_b32
// per i4), 12 coalesced scalar w loads, 100 FMA.
__global__ __launch_bounds__(256) void k_attn() {
    int wid = threadIdx.x >> 6;
    int lane = threadIdx.x & 63;
    int g = blockIdx.x * 4 + wid;
    int b = g / NN, n = g - b * NN;
    __shared__ float x[4][TT][HH], kk[4][TT][HH], vv[4][TT][HH];
    __shared__ float q[4][HH], o1[4][HH], sc[4][HEADS][TT], aw[4][HEADS][TT];
    float mw = g_buf[S_MLW + lane];
    float mb = g_buf[S_MLB + lane];
    #pragma unroll
    for (int tt = 0; tt < TT; tt++) {
        float s = g_buf[S_SRC + ((size_t)b * TT + tt) * NN + n];
        x[wid][tt][lane] = s * mw + mb + g_buf[OFF_PE + tt * HH + lane];
    }
    __syncthreads();
    float ka[TT], va[TT];
    #pragma unroll
    for (int tt = 0; tt < TT; tt++) { ka[tt] = g_buf[S_BK + lane]; va[tt] = g_buf[S_BV + lane]; }
    float qa = g_buf[S_BQ + lane];
    for (int i0 = 0; i0 < HH; i0 += 4) {
        float wk0 = g_buf[S_WK + (i0 + 0) * HH + lane];
        float wk1 = g_buf[S_WK + (i0 + 1) * HH + lane];
        float wk2 = g_buf[S_WK + (i0 + 2) * HH + lane];
        float wk3 = g_buf[S_WK + (i0 + 3) * HH + lane];
        float wv0 = g_buf[S_WV + (i0 + 0) * HH + lane];
        float wv1 = g_buf[S_WV + (i0 + 1) * HH + lane];
        float wv2 = g_buf[S_WV + (i0 + 2) * HH + lane];
        float wv3 = g_buf[S_WV + (i0 + 3) * HH + lane];
        float wq0 = g_buf[S_WQ + (i0 + 0) * HH + lane];
        float wq1 = g_buf[S_WQ + (i0 + 1) * HH + lane];
        float wq2 = g_buf[S_WQ + (i0 + 2) * HH + lane];
        float wq3 = g_buf[S_WQ + (i0 + 3) * HH + lane];
        float4 xq = *(const float4*)&x[wid][TT - 1][i0];
        qa += xq.x * wq0 + xq.y * wq1 + xq.z * wq2 + xq.w * wq3;
        #pragma unroll
        for (int tt = 0; tt < TT; tt++) {
            float4 xv4 = *(const float4*)&x[wid][tt][i0];   // broadcast b128
            ka[tt] += xv4.x * wk0 + xv4.y * wk1 + xv4.z * wk2 + xv4.w * wk3;
            va[tt] += xv4.x * wv0 + xv4.y * wv1 + xv4.z * wv2 + xv4.w * wv3;
        }
    }
    #pragma unroll
    for (int tt = 0; tt < TT; tt++) { kk[wid][tt][lane] = ka[tt]; vv[wid][tt][lane] = va[tt]; }
    q[wid][lane] = qa;
    __syncthreads();
    if (lane < HEADS * TT) {
        int head = lane / TT, ts = lane - head * TT;
        float s = 0.f;
        #pragma unroll
        for (int d = 0; d < HD; d++) s += q[wid][head * HD + d] * kk[wid][ts][head * HD + d];
        sc[wid][head][ts] = s * 0.25f;
    }
    __syncthreads();
    if (lane < HEADS * TT) {
        int head = lane / TT, ts = lane - head * TT;
        float mx = -1e30f;
        #pragma unroll
        for (int j = 0; j < TT; j++) mx = fmaxf(mx, sc[wid][head][j]);
        float sm = 0.f;
        #pragma unroll
        for (int j = 0; j < TT; j++) sm += expf(sc[wid][head][j] - mx);
        aw[wid][head][ts] = expf(sc[wid][head][ts] - mx) / sm;
    }
    __syncthreads();
    int head = lane >> 4;
    float oa = 0.f;
    #pragma unroll
    for (int tt = 0; tt < TT; tt++) oa += aw[wid][head][tt] * vv[wid][tt][lane];
    o1[wid][lane] = oa;
    __syncthreads();
    float acc = g_buf[S_BO + lane];
    for (int i0 = 0; i0 < HH; i0 += 4) {
        float w0 = g_buf[S_WO + (i0 + 0) * HH + lane];
        float w1 = g_buf[S_WO + (i0 + 1) * HH + lane];
        float w2 = g_buf[S_WO + (i0 + 2) * HH + lane];
        float w3 = g_buf[S_WO + (i0 + 3) * HH + lane];
        float4 ov = *(const float4*)&o1[wid][i0];
        acc += ov.x * w0 + ov.y * w1 + ov.z * w2 + ov.w * w3;
    }
    float res = x[wid][TT - 1][lane] + acc;
    float mean = wave_sum(res) * (1.f / 64.f);
    float dv = res - mean;
    float var = wave_sum(dv * dv) * (1.f / 64.f);
    float ln = dv * rsqrtf(var + 1e-5f) * g_buf[S_L1G + lane] + g_buf[S_L1B + lane];
    g_buf[OFF_OLN + ((size_t)b * NN + n) * HH + lane] = ln;
}

// ---------------- FFN + LN2; 8 tokens per block ----------------
// r13 rewrite: phase1 i4-blocked 4-j register tile (128 FMA : 8 ds_b128 : 16 glb
// per i4); phase2 j-range split across the 4 waves (w2 loaded 1x/block, was 4x)
// with cross-wave reduction reusing hid[] LDS. LDS stays 34KB -> 4 blocks/CU.
__global__ __launch_bounds__(256) void k_ffn() {
    int tok0 = blockIdx.x * 8;
    int tid = threadIdx.x;
    int lane = tid & 63, wvid = tid >> 6;
    __shared__ float ox[8][HH];
    __shared__ float hid[8][1024];
    for (int idx = tid; idx < 8 * HH; idx += 256) {
        int tk = idx >> 6, hh = idx & 63;
        ox[tk][hh] = g_buf[OFF_OLN + (size_t)(tok0 + tk) * HH + hh];
    }
    __syncthreads();
    // ---- phase 1: hid = relu(ox @ w1 + b1); thread owns 4 j (tid+256p) x 8 tk ----
    {
        float acc[4][8];
        #pragma unroll
        for (int p = 0; p < 4; p++) {
            float bj = g_buf[S_FB1 + tid + 256 * p];
            #pragma unroll
            for (int tk = 0; tk < 8; tk++) acc[p][tk] = bj;
        }
        for (int i0 = 0; i0 < HH; i0 += 4) {
            float w1r[4][4];
            #pragma unroll
            for (int qq = 0; qq < 4; qq++)
                #pragma unroll
                for (int p = 0; p < 4; p++)
                    w1r[p][qq] = g_buf[S_FW1 + (size_t)(i0 + qq) * 1024 + tid + 256 * p];
            #pragma unroll
            for (int tk = 0; tk < 8; tk++) {
                float4 xo = *(const float4*)&ox[tk][i0];    // broadcast b128
                const float* xp = (const float*)&xo;
                #pragma unroll
                for (int p = 0; p < 4; p++)
                    acc[p][tk] += xp[0] * w1r[p][0] + xp[1] * w1r[p][1]
                                + xp[2] * w1r[p][2] + xp[3] * w1r[p][3];
            }
        }
        #pragma unroll
        for (int p = 0; p < 4; p++)
            #pragma unroll
            for (int tk = 0; tk < 8; tk++)
                hid[tk][tid + 256 * p] = fmaxf(acc[p][tk], 0.f);
    }
    __syncthreads();
    // ---- phase 2: each wave covers j in [wvid*256, wvid*256+256) for ALL 8 tk ----
    float pa[8], pb[8];
    #pragma unroll
    for (int tk = 0; tk < 8; tk++) { pa[tk] = 0.f; pb[tk] = 0.f; }
    {
        int jbase = wvid * 256;
        #pragma unroll 2
        for (int j4 = 0; j4 < 256; j4 += 4) {
            int j0 = jbase + j4;
            float w0 = g_buf[S_FW2 + (size_t)(j0 + 0) * HH + lane];
            float w1 = g_buf[S_FW2 + (size_t)(j0 + 1) * HH + lane];
            float w2 = g_buf[S_FW2 + (size_t)(j0 + 2) * HH + lane];
            float w3 = g_buf[S_FW2 + (size_t)(j0 + 3) * HH + lane];
            #pragma unroll
            for (int tk = 0; tk < 8; tk++) {
                float4 h4 = *(const float4*)&hid[tk][j0];   // broadcast b128
                pa[tk] += h4.x * w0 + h4.y * w1;
                pb[tk] += h4.z * w2 + h4.w * w3;
            }
        }
    }
    __syncthreads();                       // all waves done reading hid
    {
        float* rp = &hid[0][0];            // reuse hid LDS as red[4][8][64]
        #pragma unroll
        for (int tk = 0; tk < 8; tk++)
            rp[(wvid * 8 + tk) * 64 + lane] = pa[tk] + pb[tk];
    }
    __syncthreads();
    int tk = wvid, hh = lane;
    float acc0 = g_buf[S_FB2 + hh], acc1 = acc0;
    {
        const float* rp = &hid[0][0];
        #pragma unroll
        for (int w = 0; w < 4; w++) {
            acc0 += rp[(w * 8 + tk) * 64 + hh];
            acc1 += rp[(w * 8 + tk + 4) * 64 + hh];
        }
    }
    #pragma unroll
    for (int ph = 0; ph < 2; ph++) {
        int tkk = tk + 4 * ph;
        float res = ox[tkk][hh] + (ph ? acc1 : acc0);
        float mean = wave_sum(res) * (1.f / 64.f);
        float dv = res - mean;
        float var = wave_sum(dv * dv) * (1.f / 64.f);
        float ln = dv * rsqrtf(var + 1e-5f) * g_buf[S_L2G + hh] + g_buf[S_L2B + hh];
        g_buf[OFF_O2 + (size_t)(tok0 + tkk) * HH + hh] = ln;
    }
}

// ---------------- final combine + horizon conv (layer-1 h is OFF_H1) ----------------
__global__ void k_final(void* out) {
    int n = blockIdx.x, b = blockIdx.y;
    int h = threadIdx.x;
    __shared__ float comb[HH];
    comb[h] = g_buf[OFF_H1 + ((size_t)n * 32 + b) * 64 + h] * g_buf[S_WS + n * HH + h]
            + g_buf[OFF_O2 + ((size_t)b * NN + n) * 64 + h] * g_buf[S_WT + n * HH + h];
    __syncthreads();
    if (h < HORIZON) {
        float acc = g_buf[S_CB + h];
        #pragma unroll
        for (int i = 0; i < HH; i++) acc += comb[i] * g_buf[S_CW + h * HH + i];
        size_t oi = ((size_t)b * HORIZON + h) * NN + n;
        if (g_flag) ((bf16*)out)[oi] = __float2bfloat16(acc);
        else        ((float*)out)[oi] = acc;
    }
}

extern "C" void kernel_launch(void* const* d_in, const int* in_sizes, int n_in,
                              void* d_out, int out_size, void* d_ws, size_t ws_size,
                              hipStream_t stream) {
    PtrPack pk;
    for (int i = 0; i < 32; i++) pk.p[i] = d_in[i];

    k_detect<<<1, 64, 0, stream>>>(d_in[1]);
    k_ingest<<<4133, 256, 0, stream>>>(pk);
    k_adj<<<NN, 512, 0, stream>>>();
    k_nodew_all<<<89337, 256, 0, stream>>>();
    k_pe<<<1, 768, 0, stream>>>();
    k_ax0<<<dim3(39, 12), 256, 0, stream>>>();
    k_xprep0<<<dim3(12, NN), 256, 0, stream>>>();
    k_zero<<<2456, 256, 0, stream>>>(OFF_H0, 628736);
    k_zero<<<2456, 256, 0, stream>>>(OFF_H1, 628736);

    // ---- pipelined supersteps: L0 t=s, L1 t=s-1 ----
    k_gateM<<<2 * NN, 256, 0, stream>>>(0);
    k_updM<<<2 * NN, 256, 0, stream>>>(0);
    for (int s = 1; s <= TT; s++) {
        k_aggB<<<dim3(5, 32, 3), 256, 0, stream>>>(s, 0);  // A@H0, A@H1, AX1[s-1]
        k_gateM<<<2 * NN, 256, 0, stream>>>(s);
        k_aggB<<<dim3(5, 32, 2), 256, 0, stream>>>(s, 1);  // A@ZH0, A@ZH1
        k_updM<<<2 * NN, 256, 0, stream>>>(s);
    }

    // ---- transformer branch ----
    k_attn<<<2456, 256, 0, stream>>>();
    k_ffn<<<1228, 256, 0, stream>>>();
    // ---- combine + conv ----
    k_final<<<dim3(NN, BB), 64, 0, stream>>>(d_out);
}

// Round 2
// 2657.811 us; speedup vs baseline: 1.1078x; 1.1078x over previous
//
#include <hip/hip_runtime.h>
#include <hip/hip_bf16.h>

typedef __hip_bfloat16 bf16;

constexpr int NN = 307, TT = 12, BB = 32, HH = 64, EE = 10, HEADS = 4, HD = 16, HORIZON = 12;

// ---------------- staged fp32 input offsets ----------------
constexpr int S_SRC = 0,       S_EMB = 117888,  S_GW0 = 120958,  S_GB0 = 287358,
              S_UW0 = 288638,  S_UB0 = 371838,  S_GW1 = 372478,  S_GB1 = 700158,
              S_UW1 = 701438,  S_UB1 = 865278,  S_MLW = 865918,  S_MLB = 865982,
              S_WQ  = 866046,  S_BQ  = 870142,  S_WK  = 870206,  S_BK  = 874302,
              S_WV  = 874366,  S_BV  = 878462,  S_WO  = 878526,  S_BO  = 882622,
              S_FW1 = 882686,  S_FB1 = 948222,  S_FW2 = 949246,  S_FB2 = 1014782,
              S_L1G = 1014846, S_L1B = 1014910, S_L2G = 1014974, S_L2B = 1015038,
              S_WS  = 1015102, S_WT  = 1034750, S_CW  = 1054398, S_CB  = 1055166;

// ---------------- fp32 work regions ----------------
constexpr size_t OFF_A    = 1055178;   // 307*307
constexpr size_t OFF_OUT0 = 1149427;   // [t][n][b][c] 12*307*2048
constexpr size_t OFF_H0   = 8694259;   // [n][b][c] 307*2048 (layer 0)
constexpr size_t OFF_ZH0  = 9322995;
constexpr size_t OFF_R0   = 9951731;
constexpr size_t OFF_AX0  = 11209203;  // [t][n][b] 12*307*32
constexpr size_t OFF_AX1  = 11327091;  // [t][n][b][c] 12*307*2048
constexpr size_t OFF_PE   = 18871923;  // 12*64
constexpr size_t OFF_OLN  = 18872691;
constexpr size_t OFF_O2   = 19501427;
constexpr size_t OFF_WB   = 20130164;  // fp32 reordered per-node GRU weights

// Reordered weight blocks (fp32; bf16 storage fails: scan amplifies to 0.19 absmax — r3)
constexpr size_t G0X = OFF_WB +        0;  // 307*2*128
constexpr size_t G0H = OFF_WB +    78592;  // 307*128*128
constexpr size_t BG0 = OFF_WB +  5108480;  // 307*128
constexpr size_t U0X = OFF_WB +  5147776;  // 307*2*64
constexpr size_t U0H = OFF_WB +  5187072;  // 307*128*64
constexpr size_t BU0 = OFF_WB +  7702016;  // 307*64
constexpr size_t G1X = OFF_WB +  7721664;  // 307*128*128
constexpr size_t G1H = OFF_WB + 12751552;  // 307*128*128
constexpr size_t BG1 = OFF_WB + 17781440;  // 307*128
constexpr size_t U1X = OFF_WB + 17820736;  // 307*128*64
constexpr size_t U1H = OFF_WB + 20335680;  // 307*128*64
constexpr size_t BU1 = OFF_WB + 22850624;  // 307*64
constexpr size_t OFF_GXP = OFF_WB + 22870272;       // [t][n][b][128] L0 preact x-part (bias folded)
constexpr size_t OFF_UXP = OFF_GXP + 15089664;      // [t][n][b][64]
constexpr size_t OFF_H1  = OFF_UXP + 7544832;       // layer-1 state buffers
constexpr size_t OFF_ZH1 = OFF_H1  + 628736;
constexpr size_t OFF_R1  = OFF_ZH1 + 628736;
constexpr size_t OFF_AGG0 = OFF_R1  + 628736;       // A@H (or A@ZH) per layer
constexpr size_t OFF_AGG1 = OFF_AGG0 + 628736;
constexpr size_t G_TOTAL  = OFF_AGG1 + 628736 + 4096;

// r13->r14 post-mortem: r13's gateM/updM reg-double-buffer REGRESSED (~+250us
// total): runtime-indexed Wc[c>>2]/Xc[c>>2] pointer arrays go to scratch
// (rule #20) on the serial GRU critical path, and the r12 staging was already
// latency-hidden by 2.4 blocks/CU TLP. -> reverted to r12 staging verbatim.
// k_ffn/k_attn r13 rewrites kept (k_ffn dropped out of top-5: 114 -> <84us).
// r14 new: k_nodew_all was the top dispatch (84us, VALUBusy 63%, WRITE 89MB at
// only 1.1TB/s) — VALU-bound on runtime-divisor integer division (rem/J with J
// from a __device__ array) per output element. Rewritten: per-segment branches
// with compile-time divisors (magic-mul / shifts; /65 -> compare since kk<130)
// + 4 outputs/thread (float4 store; dst bases all 16B-aligned). Predicted
// 84 -> ~25us (write-BW floor 14.5us).

__device__ float g_buf[G_TOTAL];
__device__ int g_flag;   // 1 = inputs are bf16, 0 = fp32

__device__ __forceinline__ float wave_sum(float v) {
    #pragma unroll
    for (int off = 32; off > 0; off >>= 1) v += __shfl_xor(v, off, 64);
    return v;
}

// ---------------- dtype detection ----------------
__global__ void k_detect(const void* emb_raw) {
    const bf16* p = (const bf16*)emb_raw;
    int lane = threadIdx.x;
    float v = __bfloat162float(p[lane]);
    bool plaus = (v == v) && (fabsf(v) <= 1e4f) && (v == 0.f || fabsf(v) >= 1e-4f);
    float c = wave_sum(plaus ? 1.f : 0.f);
    if (lane == 0) g_flag = (c >= 52.f) ? 1 : 0;
}

// ---------------- ingest all inputs as fp32 ----------------
struct PtrPack { const void* p[32]; };
__device__ const int D_CNT[32] = {117888,3070,166400,1280,83200,640,327680,1280,163840,640,
                                  64,64,4096,64,4096,64,4096,64,4096,64,
                                  65536,1024,65536,64,64,64,64,64,19648,19648,768,12};
__device__ const int D_OFF[32] = {S_SRC,S_EMB,S_GW0,S_GB0,S_UW0,S_UB0,S_GW1,S_GB1,S_UW1,S_UB1,
                                  S_MLW,S_MLB,S_WQ,S_BQ,S_WK,S_BK,S_WV,S_BV,S_WO,S_BO,
                                  S_FW1,S_FB1,S_FW2,S_FB2,S_L1G,S_L1B,S_L2G,S_L2B,S_WS,S_WT,S_CW,S_CB};
__device__ const int D_CHK[33] = {0,461,473,1123,1128,1453,1456,2736,2741,3381,3384,3385,3386,
                                  3402,3403,3419,3420,3436,3437,3453,3454,3710,3714,3970,3971,
                                  3972,3973,3974,3975,4052,4129,4132,4133};

__global__ void k_ingest(PtrPack pk) {
    int bid = blockIdx.x;
    int s = 0;
    while (s < 31 && bid >= D_CHK[s + 1]) s++;
    int i = (bid - D_CHK[s]) * 256 + threadIdx.x;
    if (i >= D_CNT[s]) return;
    float v;
    if (g_flag) v = __bfloat162float(((const bf16*)pk.p[s])[i]);
    else        v = ((const float*)pk.p[s])[i];
    g_buf[(size_t)D_OFF[s] + i] = v;
}

// ---------------- adjacency ----------------
__global__ void k_adj() {
    int n = blockIdx.x;
    int tid = threadIdx.x;            // 512
    __shared__ float en[EE];
    __shared__ float red[512];
    if (tid < EE) en[tid] = g_buf[S_EMB + n * EE + tid];
    __syncthreads();
    bool act = tid < NN;
    float d = 0.f;
    if (act) {
        #pragma unroll
        for (int e = 0; e < EE; e++) d += en[e] * g_buf[S_EMB + tid * EE + e];
        d = fmaxf(d, 0.f);
    }
    red[tid] = act ? d : -1e30f;
    __syncthreads();
    for (int s = 256; s > 0; s >>= 1) { if (tid < s) red[tid] = fmaxf(red[tid], red[tid + s]); __syncthreads(); }
    float mx = red[0];
    __syncthreads();
    float ex = act ? expf(d - mx) : 0.f;
    red[tid] = ex;
    __syncthreads();
    for (int s = 256; s > 0; s >>= 1) { if (tid < s) red[tid] += red[tid + s]; __syncthreads(); }
    float inv = 1.f / red[0];
    if (act) g_buf[OFF_A + (size_t)n * NN + tid] = ex * inv;
}

// ---------------- per-node GRU weights -> fp32, reordered into Wx/Wh blocks ----------------
// r14: 4 outputs/thread, compile-time divisors per segment, float4 stores.
// float4-unit segment boundaries: SEGC/4.
__global__ void k_nodew_all() {
    unsigned i4 = blockIdx.x * 256u + threadIdx.x;
    if (i4 >= 5717568u) return;
    float a0 = 0.f, a1 = 0.f, a2 = 0.f, a3 = 0.f;
    size_t dst;
    unsigned n;

    #define NW_ACCUM(SRCOFF, JCONST) do {                                  \
        const float* eb = g_buf + S_EMB + n * EE;                          \
        const float* wp = g_buf + (SRCOFF) + j;                            \
        _Pragma("unroll")                                                  \
        for (int e = 0; e < EE; e++) {                                     \
            float ev = eb[e];                                              \
            a0 += ev * wp[0]; a1 += ev * wp[1];                            \
            a2 += ev * wp[2]; a3 += ev * wp[3];                            \
            wp += (JCONST);                                                \
        }                                                                  \
    } while (0)

    if (i4 < 1277120u) {               // s0: gw0, J=16640 (J4=4160)
        unsigned rem = i4;
        n = rem / 4160u;
        unsigned j = (rem - n * 4160u) * 4u;
        unsigned o = j & 127u, kk = j >> 7;
        unsigned k = (kk >= 65u) ? 1u : 0u, i = kk - k * 65u;
        dst = (i == 0u) ? G0X + ((size_t)(n * 2u + k)) * 128u + o
                        : G0H + ((size_t)(n * 128u + k * 64u + (i - 1u))) * 128u + o;
        NW_ACCUM(S_GW0, 16640u);
    } else if (i4 < 1286944u) {        // s1: gb0, J=128 (J4=32)
        unsigned rem = i4 - 1277120u;
        n = rem >> 5;
        unsigned j = (rem & 31u) * 4u;
        dst = BG0 + (size_t)n * 128u + j;
        NW_ACCUM(S_GB0, 128u);
    } else if (i4 < 1925504u) {        // s2: uw0, J=8320 (J4=2080)
        unsigned rem = i4 - 1286944u;
        n = rem / 2080u;
        unsigned j = (rem - n * 2080u) * 4u;
        unsigned o = j & 63u, kk = j >> 6;
        unsigned k = (kk >= 65u) ? 1u : 0u, i = kk - k * 65u;
        dst = (i == 0u) ? U0X + ((size_t)(n * 2u + k)) * 64u + o
                        : U0H + ((size_t)(n * 128u + k * 64u + (i - 1u))) * 64u + o;
        NW_ACCUM(S_UW0, 8320u);
    } else if (i4 < 1930416u) {        // s3: ub0, J=64 (J4=16)
        unsigned rem = i4 - 1925504u;
        n = rem >> 4;
        unsigned j = (rem & 15u) * 4u;
        dst = BU0 + (size_t)n * 64u + j;
        NW_ACCUM(S_UB0, 64u);
    } else if (i4 < 4445360u) {        // s4: gw1, J=32768 (J4=8192)
        unsigned rem = i4 - 1930416u;
        n = rem >> 13;
        unsigned j = (rem & 8191u) * 4u;
        unsigned o = j & 127u, kk = j >> 7;
        unsigned k = kk >> 7, i = kk & 127u;
        dst = (i < 64u) ? G1X + ((size_t)(n * 128u + k * 64u + i)) * 128u + o
                        : G1H + ((size_t)(n * 128u + k * 64u + (i - 64u))) * 128u + o;
        NW_ACCUM(S_GW1, 32768u);
    } else if (i4 < 4455184u) {        // s5: gb1, J=128 (J4=32)
        unsigned rem = i4 - 4445360u;
        n = rem >> 5;
        unsigned j = (rem & 31u) * 4u;
        dst = BG1 + (size_t)n * 128u + j;
        NW_ACCUM(S_GB1, 128u);
    } else if (i4 < 5712656u) {        // s6: uw1, J=16384 (J4=4096)
        unsigned rem = i4 - 4455184u;
        n = rem >> 12;
        unsigned j = (rem & 4095u) * 4u;
        unsigned o = j & 63u, kk = j >> 6;
        unsigned k = kk >> 7, i = kk & 127u;
        dst = (i < 64u) ? U1X + ((size_t)(n * 128u + k * 64u + i)) * 64u + o
                        : U1H + ((size_t)(n * 128u + k * 64u + (i - 64u))) * 64u + o;
        NW_ACCUM(S_UW1, 16384u);
    } else {                           // s7: ub1, J=64 (J4=16)
        unsigned rem = i4 - 5712656u;
        n = rem >> 4;
        unsigned j = (rem & 15u) * 4u;
        dst = BU1 + (size_t)n * 64u + j;
        NW_ACCUM(S_UB1, 64u);
    }
    #undef NW_ACCUM
    *(float4*)&g_buf[dst] = make_float4(a0, a1, a2, a3);
}

// ---------------- positional embedding ----------------
__global__ void k_pe() {
    int tid = threadIdx.x;            // 768
    int t = tid >> 6, h = tid & 63;
    float ex = (float)(h & ~1) / 64.f;
    float ang = (float)t * powf(10000.f, -ex);
    g_buf[OFF_PE + tid] = (h & 1) ? cosf(ang) : sinf(ang);
}

__global__ void k_zero(size_t off, int cnt) {
    int i = blockIdx.x * 256 + threadIdx.x;
    if (i < cnt) g_buf[off + i] = 0.f;
}

// ---------------- AX0[t][n][b] = sum_m A[n,m] * src[b,t,m] ----------------
__global__ __launch_bounds__(256) void k_ax0() {
    int t = blockIdx.y;
    int n0 = blockIdx.x * 8;
    int b = threadIdx.x & 31, nl = threadIdx.x >> 5;
    __shared__ float As[8][68];
    __shared__ float xs[32][65];
    float acc = 0.f;
    for (int m0 = 0; m0 < NN; m0 += 64) {
        int jend = min(64, NN - m0);
        for (int idx = threadIdx.x; idx < 8 * 64; idx += 256) {
            int i = idx >> 6, jj = idx & 63;
            int n = n0 + i, m = m0 + jj;
            As[i][jj] = (n < NN && m < NN) ? g_buf[OFF_A + (size_t)n * NN + m] : 0.f;
        }
        for (int idx = threadIdx.x; idx < 32 * 64; idx += 256) {
            int bb = idx >> 6, jj = idx & 63;
            int m = m0 + jj;
            xs[bb][jj] = (m < NN) ? g_buf[S_SRC + ((size_t)bb * TT + t) * NN + m] : 0.f;
        }
        __syncthreads();
        for (int jj = 0; jj < jend; jj++) acc += As[nl][jj] * xs[b][jj];
        __syncthreads();
    }
    int n = n0 + nl;
    if (n < NN) g_buf[OFF_AX0 + ((size_t)t * NN + n) * 32 + b] = acc;
}

// ---------------- batched agg GEMM: z selects job ----------------
// mode 0 (z<3): H0->AGG0, H1->AGG1, OUT0[s-1]->AX1[s-1]
// mode 1 (z<2): ZH0->AGG0, ZH1->AGG1
__global__ __launch_bounds__(256) void k_aggB(int s, int mode) {
    int z = blockIdx.z;
    size_t srcOff, dstOff;
    if (mode == 0) {
        if (z == 0)      { srcOff = OFF_H0; dstOff = OFF_AGG0; }
        else if (z == 1) { srcOff = OFF_H1; dstOff = OFF_AGG1; }
        else             { srcOff = OFF_OUT0 + (size_t)(s - 1) * 628736;
                           dstOff = OFF_AX1  + (size_t)(s - 1) * 628736; }
    } else {
        srcOff = z ? OFF_ZH1 : OFF_ZH0;
        dstOff = z ? OFF_AGG1 : OFF_AGG0;
    }
    const float* __restrict__ srcp = g_buf + srcOff;
    float* __restrict__ dstp = g_buf + dstOff;
    int n0 = blockIdx.x * 64;
    int col0 = blockIdx.y * 64;
    int tid = threadIdx.x;
    int tn = tid >> 4, tc = tid & 15;
    __shared__ float As[32][68];
    __shared__ float Xs[32][64];
    float acc[4][4];
    #pragma unroll
    for (int i = 0; i < 4; i++)
        #pragma unroll
        for (int j = 0; j < 4; j++) acc[i][j] = 0.f;
    for (int k0 = 0; k0 < NN; k0 += 32) {
        for (int idx = tid; idx < 64 * 32; idx += 256) {
            int k = idx & 31, i = idx >> 5;
            int n = n0 + i, m = k0 + k;
            As[k][i] = (n < NN && m < NN) ? g_buf[OFF_A + (size_t)n * NN + m] : 0.f;
        }
        for (int idx = tid; idx < 32 * 64; idx += 256) {
            int c = idx & 63, k = idx >> 6;
            int m = k0 + k;
            Xs[k][c] = (m < NN) ? srcp[(size_t)m * 2048 + col0 + c] : 0.f;
        }
        __syncthreads();
        #pragma unroll
        for (int k = 0; k < 32; k++) {
            float4 a4 = *(const float4*)&As[k][tn * 4];
            float4 x4 = *(const float4*)&Xs[k][tc * 4];
            const float* aa = (const float*)&a4;
            const float* xx = (const float*)&x4;
            #pragma unroll
            for (int i = 0; i < 4; i++)
                #pragma unroll
                for (int j = 0; j < 4; j++) acc[i][j] += aa[i] * xx[j];
        }
        __syncthreads();
    }
    #pragma unroll
    for (int i = 0; i < 4; i++) {
        int n = n0 + tn * 4 + i;
        if (n < NN) {
            float4 v = make_float4(acc[i][0], acc[i][1], acc[i][2], acc[i][3]);
            *(float4*)&dstp[(size_t)n * 2048 + col0 + tc * 4] = v;
        }
    }
}

// ---------------- x-part preact precompute, layer 0 (K=2); grid (12, NN) ----------------
__global__ __launch_bounds__(256) void k_xprep0() {
    int t = blockIdx.x, n = blockIdx.y, tid = threadIdx.x;
    __shared__ float xv[32], ax[32];
    if (tid < 32) {
        xv[tid] = g_buf[S_SRC + ((size_t)tid * TT + t) * NN + n];
        ax[tid] = g_buf[OFF_AX0 + ((size_t)t * NN + n) * 32 + tid];
    }
    __syncthreads();
    size_t pbase = ((size_t)t * NN + n) * 32;
    for (int idx = tid; idx < 4096; idx += 256) {
        int b = idx >> 7, o = idx & 127;
        g_buf[OFF_GXP + (pbase + b) * 128 + o] =
            g_buf[BG0 + (size_t)n * 128 + o]
          + g_buf[G0X + ((size_t)n * 2 + 0) * 128 + o] * xv[b]
          + g_buf[G0X + ((size_t)n * 2 + 1) * 128 + o] * ax[b];
    }
    for (int idx = tid; idx < 2048; idx += 256) {
        int b = idx >> 6, o = idx & 63;
        g_buf[OFF_UXP + (pbase + b) * 64 + o] =
            g_buf[BU0 + (size_t)n * 64 + o]
          + g_buf[U0X + ((size_t)n * 2 + 0) * 64 + o] * xv[b]
          + g_buf[U0X + ((size_t)n * 2 + 1) * 64 + o] * ax[b];
    }
}

// ======== merged pipelined gate (r12 staging — sync/stage/sync/compute) ========
// smem: xh 32*136 | xx 32*136 | Wl 32*128
__global__ __launch_bounds__(256) void k_gateM(int s) {
    __shared__ float smem[12800];
    float* xh = smem;
    float* xx = smem + 4352;
    float* Wl = smem + 8704;
    int lay = (blockIdx.x >= NN) ? 1 : 0;
    int n = blockIdx.x - lay * NN;
    int t = lay ? (s - 1) : s;
    if (t < 0 || t >= TT) return;
    int tid = threadIdx.x;
    size_t Hoff = lay ? OFF_H1 : OFF_H0;
    size_t Aoff = lay ? OFF_AGG1 : OFF_AGG0;
    for (int idx = tid; idx < 4096; idx += 256) {
        int bl = idx >> 7, c = idx & 127;
        float v = (c < 64) ? g_buf[Hoff + (size_t)n * 2048 + bl * 64 + c]
                           : g_buf[Aoff + (size_t)n * 2048 + bl * 64 + (c - 64)];
        xh[bl * 136 + c] = v;
    }
    if (lay) {
        size_t pb = ((size_t)t * NN + n) * 2048;
        for (int idx = tid; idx < 4096; idx += 256) {
            int bl = idx >> 7, c = idx & 127;
            float v = (c < 64) ? g_buf[OFF_OUT0 + pb + bl * 64 + c]
                               : g_buf[OFF_AX1 + pb + bl * 64 + (c - 64)];
            xx[bl * 136 + c] = v;
        }
    }
    __syncthreads();
    int o = tid & 63, bl0 = (tid >> 6) * 8;
    size_t pbase = ((size_t)t * NN + n) * 32;
    float accz[8], accr[8];
    if (lay) {
        #pragma unroll
        for (int j = 0; j < 8; j++) {
            accz[j] = g_buf[BG1 + (size_t)n * 128 + o];
            accr[j] = g_buf[BG1 + (size_t)n * 128 + o + 64];
        }
    } else {
        #pragma unroll
        for (int j = 0; j < 8; j++) {
            accz[j] = g_buf[OFF_GXP + (pbase + bl0 + j) * 128 + o];
            accr[j] = g_buf[OFF_GXP + (pbase + bl0 + j) * 128 + o + 64];
        }
    }
    for (int pass = 0; pass < 2; pass++) {
        const float* Wbase;
        const float* X;
        if (lay) {
            if (pass == 0) { Wbase = g_buf + G1X + (size_t)n * 16384; X = xx; }
            else           { if (t == 0) break; Wbase = g_buf + G1H + (size_t)n * 16384; X = xh; }
        } else {
            if (pass == 0) { if (t == 0) break; Wbase = g_buf + G0H + (size_t)n * 16384; X = xh; }
            else break;
        }
        for (int ch = 0; ch < 4; ch++) {
            __syncthreads();
            const float4* wsrc = (const float4*)(Wbase + ch * 4096);
            float4* wdst = (float4*)Wl;
            for (int idx = tid; idx < 1024; idx += 256) wdst[idx] = wsrc[idx];
            __syncthreads();
            #pragma unroll 4
            for (int kq = 0; kq < 32; kq += 4) {
                float4 xv[8];
                #pragma unroll
                for (int j = 0; j < 8; j++) xv[j] = *(const float4*)&X[(bl0 + j) * 136 + ch * 32 + kq];
                #pragma unroll
                for (int q = 0; q < 4; q++) {
                    float w0 = Wl[(kq + q) * 128 + o];
                    float w1 = Wl[(kq + q) * 128 + o + 64];
                    #pragma unroll
                    for (int j = 0; j < 8; j++) {
                        float xxv = ((const float*)&xv[j])[q];
                        accz[j] += xxv * w0;
                        accr[j] += xxv * w1;
                    }
                }
            }
        }
    }
    size_t ZHoff = lay ? OFF_ZH1 : OFF_ZH0;
    size_t Roff  = lay ? OFF_R1 : OFF_R0;
    #pragma unroll
    for (int j = 0; j < 8; j++) {
        int b = bl0 + j;
        float z = 1.f / (1.f + expf(-accz[j]));
        float r = 1.f / (1.f + expf(-accr[j]));
        float hv = xh[b * 136 + o];
        g_buf[ZHoff + (size_t)n * 2048 + (size_t)b * 64 + o] = z * hv;
        g_buf[Roff  + (size_t)n * 2048 + (size_t)b * 64 + o] = r;
    }
}

// ======== merged pipelined update (r12 staging) ========
__global__ __launch_bounds__(256) void k_updM(int s) {
    __shared__ float smem[10752];
    float* xh = smem;
    float* xx = smem + 4352;
    float* Wl = smem + 8704;   // 32*64
    int lay = (blockIdx.x >= NN) ? 1 : 0;
    int n = blockIdx.x - lay * NN;
    int t = lay ? (s - 1) : s;
    if (t < 0 || t >= TT) return;
    int tid = threadIdx.x;
    size_t ZHoff = lay ? OFF_ZH1 : OFF_ZH0;
    size_t Aoff  = lay ? OFF_AGG1 : OFF_AGG0;
    for (int idx = tid; idx < 4096; idx += 256) {
        int bl = idx >> 7, c = idx & 127;
        float v = (c < 64) ? g_buf[ZHoff + (size_t)n * 2048 + bl * 64 + c]
                           : g_buf[Aoff + (size_t)n * 2048 + bl * 64 + (c - 64)];
        xh[bl * 136 + c] = v;
    }
    if (lay) {
        size_t pb = ((size_t)t * NN + n) * 2048;
        for (int idx = tid; idx < 4096; idx += 256) {
            int bl = idx >> 7, c = idx & 127;
            float v = (c < 64) ? g_buf[OFF_OUT0 + pb + bl * 64 + c]
                               : g_buf[OFF_AX1 + pb + bl * 64 + (c - 64)];
            xx[bl * 136 + c] = v;
        }
    }
    __syncthreads();
    int o = tid & 63, bl0 = (tid >> 6) * 8;
    size_t pbase = ((size_t)t * NN + n) * 32;
    float acc[8];
    if (lay) {
        #pragma unroll
        for (int j = 0; j < 8; j++) acc[j] = g_buf[BU1 + (size_t)n * 64 + o];
    } else {
        #pragma unroll
        for (int j = 0; j < 8; j++) acc[j] = g_buf[OFF_UXP + (pbase + bl0 + j) * 64 + o];
    }
    for (int pass = 0; pass < 2; pass++) {
        const float* Wbase;
        const float* X;
        if (lay) {
            if (pass == 0) { Wbase = g_buf + U1X + (size_t)n * 8192; X = xx; }
            else           { if (t == 0) break; Wbase = g_buf + U1H + (size_t)n * 8192; X = xh; }
        } else {
            if (pass == 0) { if (t == 0) break; Wbase = g_buf + U0H + (size_t)n * 8192; X = xh; }
            else break;
        }
        for (int ch = 0; ch < 4; ch++) {
            __syncthreads();
            const float4* wsrc = (const float4*)(Wbase + ch * 2048);
            float4* wdst = (float4*)Wl;
            for (int idx = tid; idx < 512; idx += 256) wdst[idx] = wsrc[idx];
            __syncthreads();
            #pragma unroll 4
            for (int kq = 0; kq < 32; kq += 4) {
                float4 xv[8];
                #pragma unroll
                for (int j = 0; j < 8; j++) xv[j] = *(const float4*)&X[(bl0 + j) * 136 + ch * 32 + kq];
                #pragma unroll
                for (int q = 0; q < 4; q++) {
                    float w = Wl[(kq + q) * 64 + o];
                    #pragma unroll
                    for (int j = 0; j < 8; j++) acc[j] += ((const float*)&xv[j])[q] * w;
                }
            }
        }
    }
    size_t Hoff = lay ? OFF_H1 : OFF_H0;
    size_t Roff = lay ? OFF_R1 : OFF_R0;
    #pragma unroll
    for (int j = 0; j < 8; j++) {
        int b = bl0 + j;
        size_t base = (size_t)n * 2048 + (size_t)b * 64 + o;
        float hc = tanhf(acc[j]);
        float r = g_buf[Roff + base];
        float hold = g_buf[Hoff + base];
        float hn = r * hold + (1.f - r) * hc;
        g_buf[Hoff + base] = hn;
        if (!lay) g_buf[OFF_OUT0 + (pbase + b) * 64 + o] = hn;
    }
}

// ---------------- fused attention (t=T-1 only) + LN1; 4 (b,n) per block ----------------
// r13: i4-blocked projection — float4 broadcast x reads, coalesced w loads.
__global__ __launch_bounds__(256) void k_attn() {
    int wid = threadIdx.x >> 6;
    int lane = threadIdx.x & 63;
    int g = blockIdx.x * 4 + wid;
    int b = g / NN, n = g - b * NN;
    __shared__ float x[4][TT][HH], kk[4][TT][HH], vv[4][TT][HH];
    __shared__ float q[4][HH], o1[4][HH], sc[4][HEADS][TT], aw[4][HEADS][TT];
    float mw = g_buf[S_MLW + lane];
    float mb = g_buf[S_MLB + lane];
    #pragma unroll
    for (int tt = 0; tt < TT; tt++) {
        float s = g_buf[S_SRC + ((size_t)b * TT + tt) * NN + n];
        x[wid][tt][lane] = s * mw + mb + g_buf[OFF_PE + tt * HH + lane];
    }
    __syncthreads();
    float ka[TT], va[TT];
    #pragma unroll
    for (int tt = 0; tt < TT; tt++) { ka[tt] = g_buf[S_BK + lane]; va[tt] = g_buf[S_BV + lane]; }
    float qa = g_buf[S_BQ + lane];
    for (int i0 = 0; i0 < HH; i0 += 4) {
        float wk0 = g_buf[S_WK + (i0 + 0) * HH + lane];
        float wk1 = g_buf[S_WK + (i0 + 1) * HH + lane];
        float wk2 = g_buf[S_WK + (i0 + 2) * HH + lane];
        float wk3 = g_buf[S_WK + (i0 + 3) * HH + lane];
        float wv0 = g_buf[S_WV + (i0 + 0) * HH + lane];
        float wv1 = g_buf[S_WV + (i0 + 1) * HH + lane];
        float wv2 = g_buf[S_WV + (i0 + 2) * HH + lane];
        float wv3 = g_buf[S_WV + (i0 + 3) * HH + lane];
        float wq0 = g_buf[S_WQ + (i0 + 0) * HH + lane];
        float wq1 = g_buf[S_WQ + (i0 + 1) * HH + lane];
        float wq2 = g_buf[S_WQ + (i0 + 2) * HH + lane];
        float wq3 = g_buf[S_WQ + (i0 + 3) * HH + lane];
        float4 xq = *(const float4*)&x[wid][TT - 1][i0];
        qa += xq.x * wq0 + xq.y * wq1 + xq.z * wq2 + xq.w * wq3;
        #pragma unroll
        for (int tt = 0; tt < TT; tt++) {
            float4 xv4 = *(const float4*)&x[wid][tt][i0];   // broadcast b128
            ka[tt] += xv4.x * wk0 + xv4.y * wk1 + xv4.z * wk2 + xv4.w * wk3;
            va[tt] += xv4.x * wv0 + xv4.y * wv1 + xv4.z * wv2 + xv4.w * wv3;
        }
    }
    #pragma unroll
    for (int tt = 0; tt < TT; tt++) { kk[wid][tt][lane] = ka[tt]; vv[wid][tt][lane] = va[tt]; }
    q[wid][lane] = qa;
    __syncthreads();
    if (lane < HEADS * TT) {
        int head = lane / TT, ts = lane - head * TT;
        float s = 0.f;
        #pragma unroll
        for (int d = 0; d < HD; d++) s += q[wid][head * HD + d] * kk[wid][ts][head * HD + d];
        sc[wid][head][ts] = s * 0.25f;
    }
    __syncthreads();
    if (lane < HEADS * TT) {
        int head = lane / TT, ts = lane - head * TT;
        float mx = -1e30f;
        #pragma unroll
        for (int j = 0; j < TT; j++) mx = fmaxf(mx, sc[wid][head][j]);
        float sm = 0.f;
        #pragma unroll
        for (int j = 0; j < TT; j++) sm += expf(sc[wid][head][j] - mx);
        aw[wid][head][ts] = expf(sc[wid][head][ts] - mx) / sm;
    }
    __syncthreads();
    int head = lane >> 4;
    float oa = 0.f;
    #pragma unroll
    for (int tt = 0; tt < TT; tt++) oa += aw[wid][head][tt] * vv[wid][tt][lane];
    o1[wid][lane] = oa;
    __syncthreads();
    float acc = g_buf[S_BO + lane];
    for (int i0 = 0; i0 < HH; i0 += 4) {
        float w0 = g_buf[S_WO + (i0 + 0) * HH + lane];
        float w1 = g_buf[S_WO + (i0 + 1) * HH + lane];
        float w2 = g_buf[S_WO + (i0 + 2) * HH + lane];
        float w3 = g_buf[S_WO + (i0 + 3) * HH + lane];
        float4 ov = *(const float4*)&o1[wid][i0];
        acc += ov.x * w0 + ov.y * w1 + ov.z * w2 + ov.w * w3;
    }
    float res = x[wid][TT - 1][lane] + acc;
    float mean = wave_sum(res) * (1.f / 64.f);
    float dv = res - mean;
    float var = wave_sum(dv * dv) * (1.f / 64.f);
    float ln = dv * rsqrtf(var + 1e-5f) * g_buf[S_L1G + lane] + g_buf[S_L1B + lane];
    g_buf[OFF_OLN + ((size_t)b * NN + n) * HH + lane] = ln;
}

// ---------------- FFN + LN2; 8 tokens per block ----------------
// r13 rewrite: phase1 i4-blocked 4-j register tile; phase2 j-split across the
// 4 waves (w2 loaded 1x/block) + cross-wave reduction reusing hid[] LDS.
__global__ __launch_bounds__(256) void k_ffn() {
    int tok0 = blockIdx.x * 8;
    int tid = threadIdx.x;
    int lane = tid & 63, wvid = tid >> 6;
    __shared__ float ox[8][HH];
    __shared__ float hid[8][1024];
    for (int idx = tid; idx < 8 * HH; idx += 256) {
        int tk = idx >> 6, hh = idx & 63;
        ox[tk][hh] = g_buf[OFF_OLN + (size_t)(tok0 + tk) * HH + hh];
    }
    __syncthreads();
    // ---- phase 1: hid = relu(ox @ w1 + b1); thread owns 4 j (tid+256p) x 8 tk ----
    {
        float acc[4][8];
        #pragma unroll
        for (int p = 0; p < 4; p++) {
            float bj = g_buf[S_FB1 + tid + 256 * p];
            #pragma unroll
            for (int tk = 0; tk < 8; tk++) acc[p][tk] = bj;
        }
        for (int i0 = 0; i0 < HH; i0 += 4) {
            float w1r[4][4];
            #pragma unroll
            for (int qq = 0; qq < 4; qq++)
                #pragma unroll
                for (int p = 0; p < 4; p++)
                    w1r[p][qq] = g_buf[S_FW1 + (size_t)(i0 + qq) * 1024 + tid + 256 * p];
            #pragma unroll
            for (int tk = 0; tk < 8; tk++) {
                float4 xo = *(const float4*)&ox[tk][i0];    // broadcast b128
                const float* xp = (const float*)&xo;
                #pragma unroll
                for (int p = 0; p < 4; p++)
                    acc[p][tk] += xp[0] * w1r[p][0] + xp[1] * w1r[p][1]
                                + xp[2] * w1r[p][2] + xp[3] * w1r[p][3];
            }
        }
        #pragma unroll
        for (int p = 0; p < 4; p++)
            #pragma unroll
            for (int tk = 0; tk < 8; tk++)
                hid[tk][tid + 256 * p] = fmaxf(acc[p][tk], 0.f);
    }
    __syncthreads();
    // ---- phase 2: each wave covers j in [wvid*256, wvid*256+256) for ALL 8 tk ----
    float pa[8], pb[8];
    #pragma unroll
    for (int tk = 0; tk < 8; tk++) { pa[tk] = 0.f; pb[tk] = 0.f; }
    {
        int jbase = wvid * 256;
        #pragma unroll 2
        for (int j4 = 0; j4 < 256; j4 += 4) {
            int j0 = jbase + j4;
            float w0 = g_buf[S_FW2 + (size_t)(j0 + 0) * HH + lane];
            float w1 = g_buf[S_FW2 + (size_t)(j0 + 1) * HH + lane];
            float w2 = g_buf[S_FW2 + (size_t)(j0 + 2) * HH + lane];
            float w3 = g_buf[S_FW2 + (size_t)(j0 + 3) * HH + lane];
            #pragma unroll
            for (int tk = 0; tk < 8; tk++) {
                float4 h4 = *(const float4*)&hid[tk][j0];   // broadcast b128
                pa[tk] += h4.x * w0 + h4.y * w1;
                pb[tk] += h4.z * w2 + h4.w * w3;
            }
        }
    }
    __syncthreads();                       // all waves done reading hid
    {
        float* rp = &hid[0][0];            // reuse hid LDS as red[4][8][64]
        #pragma unroll
        for (int tk = 0; tk < 8; tk++)
            rp[(wvid * 8 + tk) * 64 + lane] = pa[tk] + pb[tk];
    }
    __syncthreads();
    int tk = wvid, hh = lane;
    float acc0 = g_buf[S_FB2 + hh], acc1 = acc0;
    {
        const float* rp = &hid[0][0];
        #pragma unroll
        for (int w = 0; w < 4; w++) {
            acc0 += rp[(w * 8 + tk) * 64 + hh];
            acc1 += rp[(w * 8 + tk + 4) * 64 + hh];
        }
    }
    #pragma unroll
    for (int ph = 0; ph < 2; ph++) {
        int tkk = tk + 4 * ph;
        float res = ox[tkk][hh] + (ph ? acc1 : acc0);
        float mean = wave_sum(res) * (1.f / 64.f);
        float dv = res - mean;
        float var = wave_sum(dv * dv) * (1.f / 64.f);
        float ln = dv * rsqrtf(var + 1e-5f) * g_buf[S_L2G + hh] + g_buf[S_L2B + hh];
        g_buf[OFF_O2 + (size_t)(tok0 + tkk) * HH + hh] = ln;
    }
}

// ---------------- final combine + horizon conv (layer-1 h is OFF_H1) ----------------
__global__ void k_final(void* out) {
    int n = blockIdx.x, b = blockIdx.y;
    int h = threadIdx.x;
    __shared__ float comb[HH];
    comb[h] = g_buf[OFF_H1 + ((size_t)n * 32 + b) * 64 + h] * g_buf[S_WS + n * HH + h]
            + g_buf[OFF_O2 + ((size_t)b * NN + n) * 64 + h] * g_buf[S_WT + n * HH + h];
    __syncthreads();
    if (h < HORIZON) {
        float acc = g_buf[S_CB + h];
        #pragma unroll
        for (int i = 0; i < HH; i++) acc += comb[i] * g_buf[S_CW + h * HH + i];
        size_t oi = ((size_t)b * HORIZON + h) * NN + n;
        if (g_flag) ((bf16*)out)[oi] = __float2bfloat16(acc);
        else        ((float*)out)[oi] = acc;
    }
}

extern "C" void kernel_launch(void* const* d_in, const int* in_sizes, int n_in,
                              void* d_out, int out_size, void* d_ws, size_t ws_size,
                              hipStream_t stream) {
    PtrPack pk;
    for (int i = 0; i < 32; i++) pk.p[i] = d_in[i];

    k_detect<<<1, 64, 0, stream>>>(d_in[1]);
    k_ingest<<<4133, 256, 0, stream>>>(pk);
    k_adj<<<NN, 512, 0, stream>>>();
    k_nodew_all<<<22335, 256, 0, stream>>>();
    k_pe<<<1, 768, 0, stream>>>();
    k_ax0<<<dim3(39, 12), 256, 0, stream>>>();
    k_xprep0<<<dim3(12, NN), 256, 0, stream>>>();
    k_zero<<<2456, 256, 0, stream>>>(OFF_H0, 628736);
    k_zero<<<2456, 256, 0, stream>>>(OFF_H1, 628736);

    // ---- pipelined supersteps: L0 t=s, L1 t=s-1 ----
    k_gateM<<<2 * NN, 256, 0, stream>>>(0);
    k_updM<<<2 * NN, 256, 0, stream>>>(0);
    for (int s = 1; s <= TT; s++) {
        k_aggB<<<dim3(5, 32, 3), 256, 0, stream>>>(s, 0);  // A@H0, A@H1, AX1[s-1]
        k_gateM<<<2 * NN, 256, 0, stream>>>(s);
        k_aggB<<<dim3(5, 32, 2), 256, 0, stream>>>(s, 1);  // A@ZH0, A@ZH1
        k_updM<<<2 * NN, 256, 0, stream>>>(s);
    }

    // ---- transformer branch ----
    k_attn<<<2456, 256, 0, stream>>>();
    k_ffn<<<1228, 256, 0, stream>>>();
    // ---- combine + conv ----
    k_final<<<dim3(NN, BB), 64, 0, stream>>>(d_out);
}

// Round 3
// 2184.614 us; speedup vs baseline: 1.3477x; 1.2166x over previous
//
#include <hip/hip_runtime.h>
#include <hip/hip_bf16.h>

typedef __hip_bfloat16 bf16;

constexpr int NN = 307, TT = 12, BB = 32, HH = 64, EE = 10, HEADS = 4, HD = 16, HORIZON = 12;

// ---------------- staged fp32 input offsets ----------------
constexpr int S_SRC = 0,       S_EMB = 117888,  S_GW0 = 120958,  S_GB0 = 287358,
              S_UW0 = 288638,  S_UB0 = 371838,  S_GW1 = 372478,  S_GB1 = 700158,
              S_UW1 = 701438,  S_UB1 = 865278,  S_MLW = 865918,  S_MLB = 865982,
              S_WQ  = 866046,  S_BQ  = 870142,  S_WK  = 870206,  S_BK  = 874302,
              S_WV  = 874366,  S_BV  = 878462,  S_WO  = 878526,  S_BO  = 882622,
              S_FW1 = 882686,  S_FB1 = 948222,  S_FW2 = 949246,  S_FB2 = 1014782,
              S_L1G = 1014846, S_L1B = 1014910, S_L2G = 1014974, S_L2B = 1015038,
              S_WS  = 1015102, S_WT  = 1034750, S_CW  = 1054398, S_CB  = 1055166;

// ---------------- fp32 work regions ----------------
constexpr size_t OFF_A    = 1055178;   // 307*307
constexpr size_t OFF_OUT0 = 1149427;   // [t][n][b][c] 12*307*2048
constexpr size_t OFF_H0   = 8694259;   // [n][b][c] 307*2048 (layer 0)
constexpr size_t OFF_ZH0  = 9322995;
constexpr size_t OFF_R0   = 9951731;
constexpr size_t OFF_AX0  = 11209203;  // [t][n][b] 12*307*32
constexpr size_t OFF_AX1  = 11327091;  // [t][n][b][c] 12*307*2048
constexpr size_t OFF_PE   = 18871923;  // 12*64
constexpr size_t OFF_OLN  = 18872691;
constexpr size_t OFF_O2   = 19501427;
constexpr size_t OFF_WB   = 20130164;  // fp32 reordered per-node GRU weights

// Reordered weight blocks (fp32; bf16 storage fails: scan amplifies to 0.19 absmax — r3)
constexpr size_t G0X = OFF_WB +        0;  // 307*2*128
constexpr size_t G0H = OFF_WB +    78592;  // 307*128*128
constexpr size_t BG0 = OFF_WB +  5108480;  // 307*128
constexpr size_t U0X = OFF_WB +  5147776;  // 307*2*64
constexpr size_t U0H = OFF_WB +  5187072;  // 307*128*64
constexpr size_t BU0 = OFF_WB +  7702016;  // 307*64
constexpr size_t G1X = OFF_WB +  7721664;  // 307*128*128
constexpr size_t G1H = OFF_WB + 12751552;  // 307*128*128
constexpr size_t BG1 = OFF_WB + 17781440;  // 307*128
constexpr size_t U1X = OFF_WB + 17820736;  // 307*128*64
constexpr size_t U1H = OFF_WB + 20335680;  // 307*128*64
constexpr size_t BU1 = OFF_WB + 22850624;  // 307*64
constexpr size_t OFF_GXP = OFF_WB + 22870272;       // [t][n][b][128] L0 preact x-part (bias folded)
constexpr size_t OFF_UXP = OFF_GXP + 15089664;      // [t][n][b][64]
constexpr size_t OFF_H1  = OFF_UXP + 7544832;       // layer-1 state buffers
constexpr size_t OFF_ZH1 = OFF_H1  + 628736;
constexpr size_t OFF_R1  = OFF_ZH1 + 628736;
constexpr size_t OFF_AGG0 = OFF_R1  + 628736;       // A@H (or A@ZH) per layer
constexpr size_t OFF_AGG1 = OFF_AGG0 + 628736;
constexpr size_t G_TOTAL  = OFF_AGG1 + 628736 + 4096;

// r14->r15: GRU chain (~85% of runtime, ~190us/superstep vs ~70us floor) was
// barrier-serialized-staging bound. (a) gateM/updM: weight LDS staging REMOVED —
// compute reads W directly from global (lane-coalesced, L2/L3-served; each W
// block read by the 4 waves of one block). Kills the 16 K-loop barriers + the
// global->LDS->reg round-trip; LDS 51->35KB. No pointer arrays / held prefetch
// regs (r13's scratch failure mode avoided). (b) aggB: K-chunk 32->64 (10
// barriers instead of 20), Xs staged via float4. Same accumulation order
// everywhere (k ascending, m ascending) -> absmax unchanged.

__device__ float g_buf[G_TOTAL];
__device__ int g_flag;   // 1 = inputs are bf16, 0 = fp32

__device__ __forceinline__ float wave_sum(float v) {
    #pragma unroll
    for (int off = 32; off > 0; off >>= 1) v += __shfl_xor(v, off, 64);
    return v;
}

// ---------------- dtype detection ----------------
__global__ void k_detect(const void* emb_raw) {
    const bf16* p = (const bf16*)emb_raw;
    int lane = threadIdx.x;
    float v = __bfloat162float(p[lane]);
    bool plaus = (v == v) && (fabsf(v) <= 1e4f) && (v == 0.f || fabsf(v) >= 1e-4f);
    float c = wave_sum(plaus ? 1.f : 0.f);
    if (lane == 0) g_flag = (c >= 52.f) ? 1 : 0;
}

// ---------------- ingest all inputs as fp32 ----------------
struct PtrPack { const void* p[32]; };
__device__ const int D_CNT[32] = {117888,3070,166400,1280,83200,640,327680,1280,163840,640,
                                  64,64,4096,64,4096,64,4096,64,4096,64,
                                  65536,1024,65536,64,64,64,64,64,19648,19648,768,12};
__device__ const int D_OFF[32] = {S_SRC,S_EMB,S_GW0,S_GB0,S_UW0,S_UB0,S_GW1,S_GB1,S_UW1,S_UB1,
                                  S_MLW,S_MLB,S_WQ,S_BQ,S_WK,S_BK,S_WV,S_BV,S_WO,S_BO,
                                  S_FW1,S_FB1,S_FW2,S_FB2,S_L1G,S_L1B,S_L2G,S_L2B,S_WS,S_WT,S_CW,S_CB};
__device__ const int D_CHK[33] = {0,461,473,1123,1128,1453,1456,2736,2741,3381,3384,3385,3386,
                                  3402,3403,3419,3420,3436,3437,3453,3454,3710,3714,3970,3971,
                                  3972,3973,3974,3975,4052,4129,4132,4133};

__global__ void k_ingest(PtrPack pk) {
    int bid = blockIdx.x;
    int s = 0;
    while (s < 31 && bid >= D_CHK[s + 1]) s++;
    int i = (bid - D_CHK[s]) * 256 + threadIdx.x;
    if (i >= D_CNT[s]) return;
    float v;
    if (g_flag) v = __bfloat162float(((const bf16*)pk.p[s])[i]);
    else        v = ((const float*)pk.p[s])[i];
    g_buf[(size_t)D_OFF[s] + i] = v;
}

// ---------------- adjacency ----------------
__global__ void k_adj() {
    int n = blockIdx.x;
    int tid = threadIdx.x;            // 512
    __shared__ float en[EE];
    __shared__ float red[512];
    if (tid < EE) en[tid] = g_buf[S_EMB + n * EE + tid];
    __syncthreads();
    bool act = tid < NN;
    float d = 0.f;
    if (act) {
        #pragma unroll
        for (int e = 0; e < EE; e++) d += en[e] * g_buf[S_EMB + tid * EE + e];
        d = fmaxf(d, 0.f);
    }
    red[tid] = act ? d : -1e30f;
    __syncthreads();
    for (int s = 256; s > 0; s >>= 1) { if (tid < s) red[tid] = fmaxf(red[tid], red[tid + s]); __syncthreads(); }
    float mx = red[0];
    __syncthreads();
    float ex = act ? expf(d - mx) : 0.f;
    red[tid] = ex;
    __syncthreads();
    for (int s = 256; s > 0; s >>= 1) { if (tid < s) red[tid] += red[tid + s]; __syncthreads(); }
    float inv = 1.f / red[0];
    if (act) g_buf[OFF_A + (size_t)n * NN + tid] = ex * inv;
}

// ---------------- per-node GRU weights -> fp32, reordered into Wx/Wh blocks ----------------
// r14: 4 outputs/thread, compile-time divisors per segment, float4 stores.
__global__ void k_nodew_all() {
    unsigned i4 = blockIdx.x * 256u + threadIdx.x;
    if (i4 >= 5717568u) return;
    float a0 = 0.f, a1 = 0.f, a2 = 0.f, a3 = 0.f;
    size_t dst;
    unsigned n;

    #define NW_ACCUM(SRCOFF, JCONST) do {                                  \
        const float* eb = g_buf + S_EMB + n * EE;                          \
        const float* wp = g_buf + (SRCOFF) + j;                            \
        _Pragma("unroll")                                                  \
        for (int e = 0; e < EE; e++) {                                     \
            float ev = eb[e];                                              \
            a0 += ev * wp[0]; a1 += ev * wp[1];                            \
            a2 += ev * wp[2]; a3 += ev * wp[3];                            \
            wp += (JCONST);                                                \
        }                                                                  \
    } while (0)

    if (i4 < 1277120u) {               // s0: gw0, J=16640 (J4=4160)
        unsigned rem = i4;
        n = rem / 4160u;
        unsigned j = (rem - n * 4160u) * 4u;
        unsigned o = j & 127u, kk = j >> 7;
        unsigned k = (kk >= 65u) ? 1u : 0u, i = kk - k * 65u;
        dst = (i == 0u) ? G0X + ((size_t)(n * 2u + k)) * 128u + o
                        : G0H + ((size_t)(n * 128u + k * 64u + (i - 1u))) * 128u + o;
        NW_ACCUM(S_GW0, 16640u);
    } else if (i4 < 1286944u) {        // s1: gb0, J=128 (J4=32)
        unsigned rem = i4 - 1277120u;
        n = rem >> 5;
        unsigned j = (rem & 31u) * 4u;
        dst = BG0 + (size_t)n * 128u + j;
        NW_ACCUM(S_GB0, 128u);
    } else if (i4 < 1925504u) {        // s2: uw0, J=8320 (J4=2080)
        unsigned rem = i4 - 1286944u;
        n = rem / 2080u;
        unsigned j = (rem - n * 2080u) * 4u;
        unsigned o = j & 63u, kk = j >> 6;
        unsigned k = (kk >= 65u) ? 1u : 0u, i = kk - k * 65u;
        dst = (i == 0u) ? U0X + ((size_t)(n * 2u + k)) * 64u + o
                        : U0H + ((size_t)(n * 128u + k * 64u + (i - 1u))) * 64u + o;
        NW_ACCUM(S_UW0, 8320u);
    } else if (i4 < 1930416u) {        // s3: ub0, J=64 (J4=16)
        unsigned rem = i4 - 1925504u;
        n = rem >> 4;
        unsigned j = (rem & 15u) * 4u;
        dst = BU0 + (size_t)n * 64u + j;
        NW_ACCUM(S_UB0, 64u);
    } else if (i4 < 4445360u) {        // s4: gw1, J=32768 (J4=8192)
        unsigned rem = i4 - 1930416u;
        n = rem >> 13;
        unsigned j = (rem & 8191u) * 4u;
        unsigned o = j & 127u, kk = j >> 7;
        unsigned k = kk >> 7, i = kk & 127u;
        dst = (i < 64u) ? G1X + ((size_t)(n * 128u + k * 64u + i)) * 128u + o
                        : G1H + ((size_t)(n * 128u + k * 64u + (i - 64u))) * 128u + o;
        NW_ACCUM(S_GW1, 32768u);
    } else if (i4 < 4455184u) {        // s5: gb1, J=128 (J4=32)
        unsigned rem = i4 - 4445360u;
        n = rem >> 5;
        unsigned j = (rem & 31u) * 4u;
        dst = BG1 + (size_t)n * 128u + j;
        NW_ACCUM(S_GB1, 128u);
    } else if (i4 < 5712656u) {        // s6: uw1, J=16384 (J4=4096)
        unsigned rem = i4 - 4455184u;
        n = rem >> 12;
        unsigned j = (rem & 4095u) * 4u;
        unsigned o = j & 63u, kk = j >> 6;
        unsigned k = kk >> 7, i = kk & 127u;
        dst = (i < 64u) ? U1X + ((size_t)(n * 128u + k * 64u + i)) * 64u + o
                        : U1H + ((size_t)(n * 128u + k * 64u + (i - 64u))) * 64u + o;
        NW_ACCUM(S_UW1, 16384u);
    } else {                           // s7: ub1, J=64 (J4=16)
        unsigned rem = i4 - 5712656u;
        n = rem >> 4;
        unsigned j = (rem & 15u) * 4u;
        dst = BU1 + (size_t)n * 64u + j;
        NW_ACCUM(S_UB1, 64u);
    }
    #undef NW_ACCUM
    *(float4*)&g_buf[dst] = make_float4(a0, a1, a2, a3);
}

// ---------------- positional embedding ----------------
__global__ void k_pe() {
    int tid = threadIdx.x;            // 768
    int t = tid >> 6, h = tid & 63;
    float ex = (float)(h & ~1) / 64.f;
    float ang = (float)t * powf(10000.f, -ex);
    g_buf[OFF_PE + tid] = (h & 1) ? cosf(ang) : sinf(ang);
}

__global__ void k_zero(size_t off, int cnt) {
    int i = blockIdx.x * 256 + threadIdx.x;
    if (i < cnt) g_buf[off + i] = 0.f;
}

// ---------------- AX0[t][n][b] = sum_m A[n,m] * src[b,t,m] ----------------
__global__ __launch_bounds__(256) void k_ax0() {
    int t = blockIdx.y;
    int n0 = blockIdx.x * 8;
    int b = threadIdx.x & 31, nl = threadIdx.x >> 5;
    __shared__ float As[8][68];
    __shared__ float xs[32][65];
    float acc = 0.f;
    for (int m0 = 0; m0 < NN; m0 += 64) {
        int jend = min(64, NN - m0);
        for (int idx = threadIdx.x; idx < 8 * 64; idx += 256) {
            int i = idx >> 6, jj = idx & 63;
            int n = n0 + i, m = m0 + jj;
            As[i][jj] = (n < NN && m < NN) ? g_buf[OFF_A + (size_t)n * NN + m] : 0.f;
        }
        for (int idx = threadIdx.x; idx < 32 * 64; idx += 256) {
            int bb = idx >> 6, jj = idx & 63;
            int m = m0 + jj;
            xs[bb][jj] = (m < NN) ? g_buf[S_SRC + ((size_t)bb * TT + t) * NN + m] : 0.f;
        }
        __syncthreads();
        for (int jj = 0; jj < jend; jj++) acc += As[nl][jj] * xs[b][jj];
        __syncthreads();
    }
    int n = n0 + nl;
    if (n < NN) g_buf[OFF_AX0 + ((size_t)t * NN + n) * 32 + b] = acc;
}

// ---------------- batched agg GEMM: z selects job ----------------
// mode 0 (z<3): H0->AGG0, H1->AGG1, OUT0[s-1]->AX1[s-1]
// mode 1 (z<2): ZH0->AGG0, ZH1->AGG1
// r15: K-chunk 64 (5 chunks, 10 barriers vs 20), float4 Xs staging.
__global__ __launch_bounds__(256) void k_aggB(int s, int mode) {
    int z = blockIdx.z;
    size_t srcOff, dstOff;
    if (mode == 0) {
        if (z == 0)      { srcOff = OFF_H0; dstOff = OFF_AGG0; }
        else if (z == 1) { srcOff = OFF_H1; dstOff = OFF_AGG1; }
        else             { srcOff = OFF_OUT0 + (size_t)(s - 1) * 628736;
                           dstOff = OFF_AX1  + (size_t)(s - 1) * 628736; }
    } else {
        srcOff = z ? OFF_ZH1 : OFF_ZH0;
        dstOff = z ? OFF_AGG1 : OFF_AGG0;
    }
    const float* __restrict__ srcp = g_buf + srcOff;
    float* __restrict__ dstp = g_buf + dstOff;
    int n0 = blockIdx.x * 64;
    int col0 = blockIdx.y * 64;
    int tid = threadIdx.x;
    int tn = tid >> 4, tc = tid & 15;
    __shared__ float As[64][68];
    __shared__ float Xs[64][64];
    float acc[4][4];
    #pragma unroll
    for (int i = 0; i < 4; i++)
        #pragma unroll
        for (int j = 0; j < 4; j++) acc[i][j] = 0.f;
    for (int k0 = 0; k0 < NN; k0 += 64) {
        for (int idx = tid; idx < 64 * 64; idx += 256) {
            int k = idx & 63, i = idx >> 6;
            int n = n0 + i, m = k0 + k;
            As[k][i] = (n < NN && m < NN) ? g_buf[OFF_A + (size_t)n * NN + m] : 0.f;
        }
        for (int idx = tid; idx < 64 * 16; idx += 256) {
            int c4 = idx & 15, k = idx >> 4;
            int m = k0 + k;
            float4 v = (m < NN) ? *(const float4*)&srcp[(size_t)m * 2048 + col0 + c4 * 4]
                                : make_float4(0.f, 0.f, 0.f, 0.f);
            *(float4*)&Xs[k][c4 * 4] = v;
        }
        __syncthreads();
        #pragma unroll
        for (int k = 0; k < 64; k++) {
            float4 a4 = *(const float4*)&As[k][tn * 4];
            float4 x4 = *(const float4*)&Xs[k][tc * 4];
            const float* aa = (const float*)&a4;
            const float* xx = (const float*)&x4;
            #pragma unroll
            for (int i = 0; i < 4; i++)
                #pragma unroll
                for (int j = 0; j < 4; j++) acc[i][j] += aa[i] * xx[j];
        }
        __syncthreads();
    }
    #pragma unroll
    for (int i = 0; i < 4; i++) {
        int n = n0 + tn * 4 + i;
        if (n < NN) {
            float4 v = make_float4(acc[i][0], acc[i][1], acc[i][2], acc[i][3]);
            *(float4*)&dstp[(size_t)n * 2048 + col0 + tc * 4] = v;
        }
    }
}

// ---------------- x-part preact precompute, layer 0 (K=2); grid (12, NN) ----------------
__global__ __launch_bounds__(256) void k_xprep0() {
    int t = blockIdx.x, n = blockIdx.y, tid = threadIdx.x;
    __shared__ float xv[32], ax[32];
    if (tid < 32) {
        xv[tid] = g_buf[S_SRC + ((size_t)tid * TT + t) * NN + n];
        ax[tid] = g_buf[OFF_AX0 + ((size_t)t * NN + n) * 32 + tid];
    }
    __syncthreads();
    size_t pbase = ((size_t)t * NN + n) * 32;
    for (int idx = tid; idx < 4096; idx += 256) {
        int b = idx >> 7, o = idx & 127;
        g_buf[OFF_GXP + (pbase + b) * 128 + o] =
            g_buf[BG0 + (size_t)n * 128 + o]
          + g_buf[G0X + ((size_t)n * 2 + 0) * 128 + o] * xv[b]
          + g_buf[G0X + ((size_t)n * 2 + 1) * 128 + o] * ax[b];
    }
    for (int idx = tid; idx < 2048; idx += 256) {
        int b = idx >> 6, o = idx & 63;
        g_buf[OFF_UXP + (pbase + b) * 64 + o] =
            g_buf[BU0 + (size_t)n * 64 + o]
          + g_buf[U0X + ((size_t)n * 2 + 0) * 64 + o] * xv[b]
          + g_buf[U0X + ((size_t)n * 2 + 1) * 64 + o] * ax[b];
    }
}

// ======== merged pipelined gate (r15: direct global weight streaming) ========
// smem: xh 32*136 | xx 32*136 (no Wl; no K-loop barriers)
__global__ __launch_bounds__(256) void k_gateM(int s) {
    __shared__ float smem[8704];
    float* xh = smem;
    float* xx = smem + 4352;
    int lay = (blockIdx.x >= NN) ? 1 : 0;
    int n = blockIdx.x - lay * NN;
    int t = lay ? (s - 1) : s;
    if (t < 0 || t >= TT) return;
    int tid = threadIdx.x;
    size_t Hoff = lay ? OFF_H1 : OFF_H0;
    size_t Aoff = lay ? OFF_AGG1 : OFF_AGG0;
    for (int idx = tid; idx < 4096; idx += 256) {
        int bl = idx >> 7, c = idx & 127;
        float v = (c < 64) ? g_buf[Hoff + (size_t)n * 2048 + bl * 64 + c]
                           : g_buf[Aoff + (size_t)n * 2048 + bl * 64 + (c - 64)];
        xh[bl * 136 + c] = v;
    }
    if (lay) {
        size_t pb = ((size_t)t * NN + n) * 2048;
        for (int idx = tid; idx < 4096; idx += 256) {
            int bl = idx >> 7, c = idx & 127;
            float v = (c < 64) ? g_buf[OFF_OUT0 + pb + bl * 64 + c]
                               : g_buf[OFF_AX1 + pb + bl * 64 + (c - 64)];
            xx[bl * 136 + c] = v;
        }
    }
    __syncthreads();
    int o = tid & 63, bl0 = (tid >> 6) * 8;
    size_t pbase = ((size_t)t * NN + n) * 32;
    float accz[8], accr[8];
    if (lay) {
        #pragma unroll
        for (int j = 0; j < 8; j++) {
            accz[j] = g_buf[BG1 + (size_t)n * 128 + o];
            accr[j] = g_buf[BG1 + (size_t)n * 128 + o + 64];
        }
    } else {
        #pragma unroll
        for (int j = 0; j < 8; j++) {
            accz[j] = g_buf[OFF_GXP + (pbase + bl0 + j) * 128 + o];
            accr[j] = g_buf[OFF_GXP + (pbase + bl0 + j) * 128 + o + 64];
        }
    }

#define GATE_MAC(WP, XP)                                                       \
    _Pragma("unroll 2")                                                        \
    for (int kq = 0; kq < 128; kq += 4) {                                      \
        float w00 = (WP)[(kq + 0) * 128 + o], w01 = (WP)[(kq + 0) * 128 + o + 64]; \
        float w10 = (WP)[(kq + 1) * 128 + o], w11 = (WP)[(kq + 1) * 128 + o + 64]; \
        float w20 = (WP)[(kq + 2) * 128 + o], w21 = (WP)[(kq + 2) * 128 + o + 64]; \
        float w30 = (WP)[(kq + 3) * 128 + o], w31 = (WP)[(kq + 3) * 128 + o + 64]; \
        _Pragma("unroll")                                                      \
        for (int j = 0; j < 8; j++) {                                          \
            float4 xv = *(const float4*)&(XP)[(bl0 + j) * 136 + kq];           \
            accz[j] += xv.x * w00 + xv.y * w10 + xv.z * w20 + xv.w * w30;      \
            accr[j] += xv.x * w01 + xv.y * w11 + xv.z * w21 + xv.w * w31;      \
        }                                                                      \
    }

    if (lay) {
        const float* __restrict__ W0 = g_buf + G1X + (size_t)n * 16384;
        GATE_MAC(W0, xx);
        if (t > 0) {
            const float* __restrict__ W1 = g_buf + G1H + (size_t)n * 16384;
            GATE_MAC(W1, xh);
        }
    } else if (t > 0) {
        const float* __restrict__ W0 = g_buf + G0H + (size_t)n * 16384;
        GATE_MAC(W0, xh);
    }
#undef GATE_MAC

    size_t ZHoff = lay ? OFF_ZH1 : OFF_ZH0;
    size_t Roff  = lay ? OFF_R1 : OFF_R0;
    #pragma unroll
    for (int j = 0; j < 8; j++) {
        int b = bl0 + j;
        float z = 1.f / (1.f + expf(-accz[j]));
        float r = 1.f / (1.f + expf(-accr[j]));
        float hv = xh[b * 136 + o];
        g_buf[ZHoff + (size_t)n * 2048 + (size_t)b * 64 + o] = z * hv;
        g_buf[Roff  + (size_t)n * 2048 + (size_t)b * 64 + o] = r;
    }
}

// ======== merged pipelined update (r15: direct global weight streaming) ========
__global__ __launch_bounds__(256) void k_updM(int s) {
    __shared__ float smem[8704];
    float* xh = smem;
    float* xx = smem + 4352;
    int lay = (blockIdx.x >= NN) ? 1 : 0;
    int n = blockIdx.x - lay * NN;
    int t = lay ? (s - 1) : s;
    if (t < 0 || t >= TT) return;
    int tid = threadIdx.x;
    size_t ZHoff = lay ? OFF_ZH1 : OFF_ZH0;
    size_t Aoff  = lay ? OFF_AGG1 : OFF_AGG0;
    for (int idx = tid; idx < 4096; idx += 256) {
        int bl = idx >> 7, c = idx & 127;
        float v = (c < 64) ? g_buf[ZHoff + (size_t)n * 2048 + bl * 64 + c]
                           : g_buf[Aoff + (size_t)n * 2048 + bl * 64 + (c - 64)];
        xh[bl * 136 + c] = v;
    }
    if (lay) {
        size_t pb = ((size_t)t * NN + n) * 2048;
        for (int idx = tid; idx < 4096; idx += 256) {
            int bl = idx >> 7, c = idx & 127;
            float v = (c < 64) ? g_buf[OFF_OUT0 + pb + bl * 64 + c]
                               : g_buf[OFF_AX1 + pb + bl * 64 + (c - 64)];
            xx[bl * 136 + c] = v;
        }
    }
    __syncthreads();
    int o = tid & 63, bl0 = (tid >> 6) * 8;
    size_t pbase = ((size_t)t * NN + n) * 32;
    float acc[8];
    if (lay) {
        #pragma unroll
        for (int j = 0; j < 8; j++) acc[j] = g_buf[BU1 + (size_t)n * 64 + o];
    } else {
        #pragma unroll
        for (int j = 0; j < 8; j++) acc[j] = g_buf[OFF_UXP + (pbase + bl0 + j) * 64 + o];
    }

#define UPD_MAC(WP, XP)                                                        \
    _Pragma("unroll 2")                                                        \
    for (int kq = 0; kq < 128; kq += 4) {                                      \
        float w0 = (WP)[(kq + 0) * 64 + o];                                    \
        float w1 = (WP)[(kq + 1) * 64 + o];                                    \
        float w2 = (WP)[(kq + 2) * 64 + o];                                    \
        float w3 = (WP)[(kq + 3) * 64 + o];                                    \
        _Pragma("unroll")                                                      \
        for (int j = 0; j < 8; j++) {                                          \
            float4 xv = *(const float4*)&(XP)[(bl0 + j) * 136 + kq];           \
            acc[j] += xv.x * w0 + xv.y * w1 + xv.z * w2 + xv.w * w3;           \
        }                                                                      \
    }

    if (lay) {
        const float* __restrict__ W0 = g_buf + U1X + (size_t)n * 8192;
        UPD_MAC(W0, xx);
        if (t > 0) {
            const float* __restrict__ W1 = g_buf + U1H + (size_t)n * 8192;
            UPD_MAC(W1, xh);
        }
    } else if (t > 0) {
        const float* __restrict__ W0 = g_buf + U0H + (size_t)n * 8192;
        UPD_MAC(W0, xh);
    }
#undef UPD_MAC

    size_t Hoff = lay ? OFF_H1 : OFF_H0;
    size_t Roff = lay ? OFF_R1 : OFF_R0;
    #pragma unroll
    for (int j = 0; j < 8; j++) {
        int b = bl0 + j;
        size_t base = (size_t)n * 2048 + (size_t)b * 64 + o;
        float hc = tanhf(acc[j]);
        float r = g_buf[Roff + base];
        float hold = g_buf[Hoff + base];
        float hn = r * hold + (1.f - r) * hc;
        g_buf[Hoff + base] = hn;
        if (!lay) g_buf[OFF_OUT0 + (pbase + b) * 64 + o] = hn;
    }
}

// ---------------- fused attention (t=T-1 only) + LN1; 4 (b,n) per block ----------------
// r13: i4-blocked projection — float4 broadcast x reads, coalesced w loads.
__global__ __launch_bounds__(256) void k_attn() {
    int wid = threadIdx.x >> 6;
    int lane = threadIdx.x & 63;
    int g = blockIdx.x * 4 + wid;
    int b = g / NN, n = g - b * NN;
    __shared__ float x[4][TT][HH], kk[4][TT][HH], vv[4][TT][HH];
    __shared__ float q[4][HH], o1[4][HH], sc[4][HEADS][TT], aw[4][HEADS][TT];
    float mw = g_buf[S_MLW + lane];
    float mb = g_buf[S_MLB + lane];
    #pragma unroll
    for (int tt = 0; tt < TT; tt++) {
        float s = g_buf[S_SRC + ((size_t)b * TT + tt) * NN + n];
        x[wid][tt][lane] = s * mw + mb + g_buf[OFF_PE + tt * HH + lane];
    }
    __syncthreads();
    float ka[TT], va[TT];
    #pragma unroll
    for (int tt = 0; tt < TT; tt++) { ka[tt] = g_buf[S_BK + lane]; va[tt] = g_buf[S_BV + lane]; }
    float qa = g_buf[S_BQ + lane];
    for (int i0 = 0; i0 < HH; i0 += 4) {
        float wk0 = g_buf[S_WK + (i0 + 0) * HH + lane];
        float wk1 = g_buf[S_WK + (i0 + 1) * HH + lane];
        float wk2 = g_buf[S_WK + (i0 + 2) * HH + lane];
        float wk3 = g_buf[S_WK + (i0 + 3) * HH + lane];
        float wv0 = g_buf[S_WV + (i0 + 0) * HH + lane];
        float wv1 = g_buf[S_WV + (i0 + 1) * HH + lane];
        float wv2 = g_buf[S_WV + (i0 + 2) * HH + lane];
        float wv3 = g_buf[S_WV + (i0 + 3) * HH + lane];
        float wq0 = g_buf[S_WQ + (i0 + 0) * HH + lane];
        float wq1 = g_buf[S_WQ + (i0 + 1) * HH + lane];
        float wq2 = g_buf[S_WQ + (i0 + 2) * HH + lane];
        float wq3 = g_buf[S_WQ + (i0 + 3) * HH + lane];
        float4 xq = *(const float4*)&x[wid][TT - 1][i0];
        qa += xq.x * wq0 + xq.y * wq1 + xq.z * wq2 + xq.w * wq3;
        #pragma unroll
        for (int tt = 0; tt < TT; tt++) {
            float4 xv4 = *(const float4*)&x[wid][tt][i0];   // broadcast b128
            ka[tt] += xv4.x * wk0 + xv4.y * wk1 + xv4.z * wk2 + xv4.w * wk3;
            va[tt] += xv4.x * wv0 + xv4.y * wv1 + xv4.z * wv2 + xv4.w * wv3;
        }
    }
    #pragma unroll
    for (int tt = 0; tt < TT; tt++) { kk[wid][tt][lane] = ka[tt]; vv[wid][tt][lane] = va[tt]; }
    q[wid][lane] = qa;
    __syncthreads();
    if (lane < HEADS * TT) {
        int head = lane / TT, ts = lane - head * TT;
        float s = 0.f;
        #pragma unroll
        for (int d = 0; d < HD; d++) s += q[wid][head * HD + d] * kk[wid][ts][head * HD + d];
        sc[wid][head][ts] = s * 0.25f;
    }
    __syncthreads();
    if (lane < HEADS * TT) {
        int head = lane / TT, ts = lane - head * TT;
        float mx = -1e30f;
        #pragma unroll
        for (int j = 0; j < TT; j++) mx = fmaxf(mx, sc[wid][head][j]);
        float sm = 0.f;
        #pragma unroll
        for (int j = 0; j < TT; j++) sm += expf(sc[wid][head][j] - mx);
        aw[wid][head][ts] = expf(sc[wid][head][ts] - mx) / sm;
    }
    __syncthreads();
    int head = lane >> 4;
    float oa = 0.f;
    #pragma unroll
    for (int tt = 0; tt < TT; tt++) oa += aw[wid][head][tt] * vv[wid][tt][lane];
    o1[wid][lane] = oa;
    __syncthreads();
    float acc = g_buf[S_BO + lane];
    for (int i0 = 0; i0 < HH; i0 += 4) {
        float w0 = g_buf[S_WO + (i0 + 0) * HH + lane];
        float w1 = g_buf[S_WO + (i0 + 1) * HH + lane];
        float w2 = g_buf[S_WO + (i0 + 2) * HH + lane];
        float w3 = g_buf[S_WO + (i0 + 3) * HH + lane];
        float4 ov = *(const float4*)&o1[wid][i0];
        acc += ov.x * w0 + ov.y * w1 + ov.z * w2 + ov.w * w3;
    }
    float res = x[wid][TT - 1][lane] + acc;
    float mean = wave_sum(res) * (1.f / 64.f);
    float dv = res - mean;
    float var = wave_sum(dv * dv) * (1.f / 64.f);
    float ln = dv * rsqrtf(var + 1e-5f) * g_buf[S_L1G + lane] + g_buf[S_L1B + lane];
    g_buf[OFF_OLN + ((size_t)b * NN + n) * HH + lane] = ln;
}

// ---------------- FFN + LN2; 8 tokens per block ----------------
// r13 rewrite: phase1 i4-blocked 4-j register tile; phase2 j-split across the
// 4 waves (w2 loaded 1x/block) + cross-wave reduction reusing hid[] LDS.
__global__ __launch_bounds__(256) void k_ffn() {
    int tok0 = blockIdx.x * 8;
    int tid = threadIdx.x;
    int lane = tid & 63, wvid = tid >> 6;
    __shared__ float ox[8][HH];
    __shared__ float hid[8][1024];
    for (int idx = tid; idx < 8 * HH; idx += 256) {
        int tk = idx >> 6, hh = idx & 63;
        ox[tk][hh] = g_buf[OFF_OLN + (size_t)(tok0 + tk) * HH + hh];
    }
    __syncthreads();
    // ---- phase 1: hid = relu(ox @ w1 + b1); thread owns 4 j (tid+256p) x 8 tk ----
    {
        float acc[4][8];
        #pragma unroll
        for (int p = 0; p < 4; p++) {
            float bj = g_buf[S_FB1 + tid + 256 * p];
            #pragma unroll
            for (int tk = 0; tk < 8; tk++) acc[p][tk] = bj;
        }
        for (int i0 = 0; i0 < HH; i0 += 4) {
            float w1r[4][4];
            #pragma unroll
            for (int qq = 0; qq < 4; qq++)
                #pragma unroll
                for (int p = 0; p < 4; p++)
                    w1r[p][qq] = g_buf[S_FW1 + (size_t)(i0 + qq) * 1024 + tid + 256 * p];
            #pragma unroll
            for (int tk = 0; tk < 8; tk++) {
                float4 xo = *(const float4*)&ox[tk][i0];    // broadcast b128
                const float* xp = (const float*)&xo;
                #pragma unroll
                for (int p = 0; p < 4; p++)
                    acc[p][tk] += xp[0] * w1r[p][0] + xp[1] * w1r[p][1]
                                + xp[2] * w1r[p][2] + xp[3] * w1r[p][3];
            }
        }
        #pragma unroll
        for (int p = 0; p < 4; p++)
            #pragma unroll
            for (int tk = 0; tk < 8; tk++)
                hid[tk][tid + 256 * p] = fmaxf(acc[p][tk], 0.f);
    }
    __syncthreads();
    // ---- phase 2: each wave covers j in [wvid*256, wvid*256+256) for ALL 8 tk ----
    float pa[8], pb[8];
    #pragma unroll
    for (int tk = 0; tk < 8; tk++) { pa[tk] = 0.f; pb[tk] = 0.f; }
    {
        int jbase = wvid * 256;
        #pragma unroll 2
        for (int j4 = 0; j4 < 256; j4 += 4) {
            int j0 = jbase + j4;
            float w0 = g_buf[S_FW2 + (size_t)(j0 + 0) * HH + lane];
            float w1 = g_buf[S_FW2 + (size_t)(j0 + 1) * HH + lane];
            float w2 = g_buf[S_FW2 + (size_t)(j0 + 2) * HH + lane];
            float w3 = g_buf[S_FW2 + (size_t)(j0 + 3) * HH + lane];
            #pragma unroll
            for (int tk = 0; tk < 8; tk++) {
                float4 h4 = *(const float4*)&hid[tk][j0];   // broadcast b128
                pa[tk] += h4.x * w0 + h4.y * w1;
                pb[tk] += h4.z * w2 + h4.w * w3;
            }
        }
    }
    __syncthreads();                       // all waves done reading hid
    {
        float* rp = &hid[0][0];            // reuse hid LDS as red[4][8][64]
        #pragma unroll
        for (int tk = 0; tk < 8; tk++)
            rp[(wvid * 8 + tk) * 64 + lane] = pa[tk] + pb[tk];
    }
    __syncthreads();
    int tk = wvid, hh = lane;
    float acc0 = g_buf[S_FB2 + hh], acc1 = acc0;
    {
        const float* rp = &hid[0][0];
        #pragma unroll
        for (int w = 0; w < 4; w++) {
            acc0 += rp[(w * 8 + tk) * 64 + hh];
            acc1 += rp[(w * 8 + tk + 4) * 64 + hh];
        }
    }
    #pragma unroll
    for (int ph = 0; ph < 2; ph++) {
        int tkk = tk + 4 * ph;
        float res = ox[tkk][hh] + (ph ? acc1 : acc0);
        float mean = wave_sum(res) * (1.f / 64.f);
        float dv = res - mean;
        float var = wave_sum(dv * dv) * (1.f / 64.f);
        float ln = dv * rsqrtf(var + 1e-5f) * g_buf[S_L2G + hh] + g_buf[S_L2B + hh];
        g_buf[OFF_O2 + (size_t)(tok0 + tkk) * HH + hh] = ln;
    }
}

// ---------------- final combine + horizon conv (layer-1 h is OFF_H1) ----------------
__global__ void k_final(void* out) {
    int n = blockIdx.x, b = blockIdx.y;
    int h = threadIdx.x;
    __shared__ float comb[HH];
    comb[h] = g_buf[OFF_H1 + ((size_t)n * 32 + b) * 64 + h] * g_buf[S_WS + n * HH + h]
            + g_buf[OFF_O2 + ((size_t)b * NN + n) * 64 + h] * g_buf[S_WT + n * HH + h];
    __syncthreads();
    if (h < HORIZON) {
        float acc = g_buf[S_CB + h];
        #pragma unroll
        for (int i = 0; i < HH; i++) acc += comb[i] * g_buf[S_CW + h * HH + i];
        size_t oi = ((size_t)b * HORIZON + h) * NN + n;
        if (g_flag) ((bf16*)out)[oi] = __float2bfloat16(acc);
        else        ((float*)out)[oi] = acc;
    }
}

extern "C" void kernel_launch(void* const* d_in, const int* in_sizes, int n_in,
                              void* d_out, int out_size, void* d_ws, size_t ws_size,
                              hipStream_t stream) {
    PtrPack pk;
    for (int i = 0; i < 32; i++) pk.p[i] = d_in[i];

    k_detect<<<1, 64, 0, stream>>>(d_in[1]);
    k_ingest<<<4133, 256, 0, stream>>>(pk);
    k_adj<<<NN, 512, 0, stream>>>();
    k_nodew_all<<<22335, 256, 0, stream>>>();
    k_pe<<<1, 768, 0, stream>>>();
    k_ax0<<<dim3(39, 12), 256, 0, stream>>>();
    k_xprep0<<<dim3(12, NN), 256, 0, stream>>>();
    k_zero<<<2456, 256, 0, stream>>>(OFF_H0, 628736);
    k_zero<<<2456, 256, 0, stream>>>(OFF_H1, 628736);

    // ---- pipelined supersteps: L0 t=s, L1 t=s-1 ----
    k_gateM<<<2 * NN, 256, 0, stream>>>(0);
    k_updM<<<2 * NN, 256, 0, stream>>>(0);
    for (int s = 1; s <= TT; s++) {
        k_aggB<<<dim3(5, 32, 3), 256, 0, stream>>>(s, 0);  // A@H0, A@H1, AX1[s-1]
        k_gateM<<<2 * NN, 256, 0, stream>>>(s);
        k_aggB<<<dim3(5, 32, 2), 256, 0, stream>>>(s, 1);  // A@ZH0, A@ZH1
        k_updM<<<2 * NN, 256, 0, stream>>>(s);
    }

    // ---- transformer branch ----
    k_attn<<<2456, 256, 0, stream>>>();
    k_ffn<<<1228, 256, 0, stream>>>();
    // ---- combine + conv ----
    k_final<<<dim3(NN, BB), 64, 0, stream>>>(d_out);
}

// Round 4
// 2154.726 us; speedup vs baseline: 1.3664x; 1.0139x over previous
//
#include <hip/hip_runtime.h>
#include <hip/hip_bf16.h>

typedef __hip_bfloat16 bf16;

constexpr int NN = 307, TT = 12, BB = 32, HH = 64, EE = 10, HEADS = 4, HD = 16, HORIZON = 12;

// ---------------- staged fp32 input offsets ----------------
constexpr int S_SRC = 0,       S_EMB = 117888,  S_GW0 = 120958,  S_GB0 = 287358,
              S_UW0 = 288638,  S_UB0 = 371838,  S_GW1 = 372478,  S_GB1 = 700158,
              S_UW1 = 701438,  S_UB1 = 865278,  S_MLW = 865918,  S_MLB = 865982,
              S_WQ  = 866046,  S_BQ  = 870142,  S_WK  = 870206,  S_BK  = 874302,
              S_WV  = 874366,  S_BV  = 878462,  S_WO  = 878526,  S_BO  = 882622,
              S_FW1 = 882686,  S_FB1 = 948222,  S_FW2 = 949246,  S_FB2 = 1014782,
              S_L1G = 1014846, S_L1B = 1014910, S_L2G = 1014974, S_L2B = 1015038,
              S_WS  = 1015102, S_WT  = 1034750, S_CW  = 1054398, S_CB  = 1055166;

// ---------------- fp32 work regions ----------------
constexpr size_t OFF_A    = 1055178;   // 307*307
constexpr size_t OFF_OUT0 = 1149427;   // [t][n][b][c] 12*307*2048
constexpr size_t OFF_H0   = 8694259;   // [n][b][c] 307*2048 (layer 0)
constexpr size_t OFF_ZH0  = 9322995;
constexpr size_t OFF_R0   = 9951731;
constexpr size_t OFF_AX0  = 11209203;  // [t][n][b] 12*307*32
constexpr size_t OFF_AX1  = 11327091;  // [t][n][b][c] 12*307*2048
constexpr size_t OFF_PE   = 18871923;  // 12*64
constexpr size_t OFF_OLN  = 18872691;
constexpr size_t OFF_O2   = 19501427;
constexpr size_t OFF_WB   = 20130164;  // fp32 reordered per-node GRU weights

// Reordered weight blocks (fp32; bf16 storage fails: scan amplifies to 0.19 absmax — r3)
constexpr size_t G0X = OFF_WB +        0;  // 307*2*128
constexpr size_t G0H = OFF_WB +    78592;  // 307*128*128
constexpr size_t BG0 = OFF_WB +  5108480;  // 307*128
constexpr size_t U0X = OFF_WB +  5147776;  // 307*2*64
constexpr size_t U0H = OFF_WB +  5187072;  // 307*128*64
constexpr size_t BU0 = OFF_WB +  7702016;  // 307*64
constexpr size_t G1X = OFF_WB +  7721664;  // 307*128*128
constexpr size_t G1H = OFF_WB + 12751552;  // 307*128*128
constexpr size_t BG1 = OFF_WB + 17781440;  // 307*128
constexpr size_t U1X = OFF_WB + 17820736;  // 307*128*64
constexpr size_t U1H = OFF_WB + 20335680;  // 307*128*64
constexpr size_t BU1 = OFF_WB + 22850624;  // 307*64
constexpr size_t OFF_GXP = OFF_WB + 22870272;       // [t][n][b][128] L0 preact x-part (bias folded)
constexpr size_t OFF_UXP = OFF_GXP + 15089664;      // [t][n][b][64]
constexpr size_t OFF_H1  = OFF_UXP + 7544832;       // layer-1 state buffers
constexpr size_t OFF_ZH1 = OFF_H1  + 628736;
constexpr size_t OFF_R1  = OFF_ZH1 + 628736;
constexpr size_t OFF_AGG0 = OFF_R1  + 628736;       // A@H (or A@ZH) per layer
constexpr size_t OFF_AGG1 = OFF_AGG0 + 628736;
constexpr size_t OFF_AT   = OFF_AGG1 + 628736;      // A^T (307*307), r16
constexpr size_t G_TOTAL  = OFF_AT + 94249 + 4096;

// r15->r16: (a) aggB mode0 z=2 DROPPED — OUT0[s-1] is bitwise == H0 at that
// point (updM lay0 writes both), so A@OUT0[s-1] == A@H0: z=0 now dual-writes
// AGG0 and AX1[s-1] (same loop, same accumulation order -> bitwise identical;
// mode0 blocks 480->320). (b) As staging had an 8-way LDS WRITE bank conflict
// (SQ_LDS_BANK_CONFLICT=921600/dispatch: As[k][i] with k lane-fast, stride 68
// -> banks (k*4)%32). Fixed by staging from a one-time A^T copy (written in
// k_adj): i lane-fast -> coalesced global read + conflict-free LDS write.

__device__ float g_buf[G_TOTAL];
__device__ int g_flag;   // 1 = inputs are bf16, 0 = fp32

__device__ __forceinline__ float wave_sum(float v) {
    #pragma unroll
    for (int off = 32; off > 0; off >>= 1) v += __shfl_xor(v, off, 64);
    return v;
}

// ---------------- dtype detection ----------------
__global__ void k_detect(const void* emb_raw) {
    const bf16* p = (const bf16*)emb_raw;
    int lane = threadIdx.x;
    float v = __bfloat162float(p[lane]);
    bool plaus = (v == v) && (fabsf(v) <= 1e4f) && (v == 0.f || fabsf(v) >= 1e-4f);
    float c = wave_sum(plaus ? 1.f : 0.f);
    if (lane == 0) g_flag = (c >= 52.f) ? 1 : 0;
}

// ---------------- ingest all inputs as fp32 ----------------
struct PtrPack { const void* p[32]; };
__device__ const int D_CNT[32] = {117888,3070,166400,1280,83200,640,327680,1280,163840,640,
                                  64,64,4096,64,4096,64,4096,64,4096,64,
                                  65536,1024,65536,64,64,64,64,64,19648,19648,768,12};
__device__ const int D_OFF[32] = {S_SRC,S_EMB,S_GW0,S_GB0,S_UW0,S_UB0,S_GW1,S_GB1,S_UW1,S_UB1,
                                  S_MLW,S_MLB,S_WQ,S_BQ,S_WK,S_BK,S_WV,S_BV,S_WO,S_BO,
                                  S_FW1,S_FB1,S_FW2,S_FB2,S_L1G,S_L1B,S_L2G,S_L2B,S_WS,S_WT,S_CW,S_CB};
__device__ const int D_CHK[33] = {0,461,473,1123,1128,1453,1456,2736,2741,3381,3384,3385,3386,
                                  3402,3403,3419,3420,3436,3437,3453,3454,3710,3714,3970,3971,
                                  3972,3973,3974,3975,4052,4129,4132,4133};

__global__ void k_ingest(PtrPack pk) {
    int bid = blockIdx.x;
    int s = 0;
    while (s < 31 && bid >= D_CHK[s + 1]) s++;
    int i = (bid - D_CHK[s]) * 256 + threadIdx.x;
    if (i >= D_CNT[s]) return;
    float v;
    if (g_flag) v = __bfloat162float(((const bf16*)pk.p[s])[i]);
    else        v = ((const float*)pk.p[s])[i];
    g_buf[(size_t)D_OFF[s] + i] = v;
}

// ---------------- adjacency (also writes A^T for aggB staging — r16) ----------------
__global__ void k_adj() {
    int n = blockIdx.x;
    int tid = threadIdx.x;            // 512
    __shared__ float en[EE];
    __shared__ float red[512];
    if (tid < EE) en[tid] = g_buf[S_EMB + n * EE + tid];
    __syncthreads();
    bool act = tid < NN;
    float d = 0.f;
    if (act) {
        #pragma unroll
        for (int e = 0; e < EE; e++) d += en[e] * g_buf[S_EMB + tid * EE + e];
        d = fmaxf(d, 0.f);
    }
    red[tid] = act ? d : -1e30f;
    __syncthreads();
    for (int s = 256; s > 0; s >>= 1) { if (tid < s) red[tid] = fmaxf(red[tid], red[tid + s]); __syncthreads(); }
    float mx = red[0];
    __syncthreads();
    float ex = act ? expf(d - mx) : 0.f;
    red[tid] = ex;
    __syncthreads();
    for (int s = 256; s > 0; s >>= 1) { if (tid < s) red[tid] += red[tid + s]; __syncthreads(); }
    float inv = 1.f / red[0];
    if (act) {
        float av = ex * inv;
        g_buf[OFF_A  + (size_t)n * NN + tid] = av;       // A[n][m]
        g_buf[OFF_AT + (size_t)tid * NN + n] = av;       // AT[m][n]
    }
}

// ---------------- per-node GRU weights -> fp32, reordered into Wx/Wh blocks ----------------
// r14: 4 outputs/thread, compile-time divisors per segment, float4 stores.
__global__ void k_nodew_all() {
    unsigned i4 = blockIdx.x * 256u + threadIdx.x;
    if (i4 >= 5717568u) return;
    float a0 = 0.f, a1 = 0.f, a2 = 0.f, a3 = 0.f;
    size_t dst;
    unsigned n;

    #define NW_ACCUM(SRCOFF, JCONST) do {                                  \
        const float* eb = g_buf + S_EMB + n * EE;                          \
        const float* wp = g_buf + (SRCOFF) + j;                            \
        _Pragma("unroll")                                                  \
        for (int e = 0; e < EE; e++) {                                     \
            float ev = eb[e];                                              \
            a0 += ev * wp[0]; a1 += ev * wp[1];                            \
            a2 += ev * wp[2]; a3 += ev * wp[3];                            \
            wp += (JCONST);                                                \
        }                                                                  \
    } while (0)

    if (i4 < 1277120u) {               // s0: gw0, J=16640 (J4=4160)
        unsigned rem = i4;
        n = rem / 4160u;
        unsigned j = (rem - n * 4160u) * 4u;
        unsigned o = j & 127u, kk = j >> 7;
        unsigned k = (kk >= 65u) ? 1u : 0u, i = kk - k * 65u;
        dst = (i == 0u) ? G0X + ((size_t)(n * 2u + k)) * 128u + o
                        : G0H + ((size_t)(n * 128u + k * 64u + (i - 1u))) * 128u + o;
        NW_ACCUM(S_GW0, 16640u);
    } else if (i4 < 1286944u) {        // s1: gb0, J=128 (J4=32)
        unsigned rem = i4 - 1277120u;
        n = rem >> 5;
        unsigned j = (rem & 31u) * 4u;
        dst = BG0 + (size_t)n * 128u + j;
        NW_ACCUM(S_GB0, 128u);
    } else if (i4 < 1925504u) {        // s2: uw0, J=8320 (J4=2080)
        unsigned rem = i4 - 1286944u;
        n = rem / 2080u;
        unsigned j = (rem - n * 2080u) * 4u;
        unsigned o = j & 63u, kk = j >> 6;
        unsigned k = (kk >= 65u) ? 1u : 0u, i = kk - k * 65u;
        dst = (i == 0u) ? U0X + ((size_t)(n * 2u + k)) * 64u + o
                        : U0H + ((size_t)(n * 128u + k * 64u + (i - 1u))) * 64u + o;
        NW_ACCUM(S_UW0, 8320u);
    } else if (i4 < 1930416u) {        // s3: ub0, J=64 (J4=16)
        unsigned rem = i4 - 1925504u;
        n = rem >> 4;
        unsigned j = (rem & 15u) * 4u;
        dst = BU0 + (size_t)n * 64u + j;
        NW_ACCUM(S_UB0, 64u);
    } else if (i4 < 4445360u) {        // s4: gw1, J=32768 (J4=8192)
        unsigned rem = i4 - 1930416u;
        n = rem >> 13;
        unsigned j = (rem & 8191u) * 4u;
        unsigned o = j & 127u, kk = j >> 7;
        unsigned k = kk >> 7, i = kk & 127u;
        dst = (i < 64u) ? G1X + ((size_t)(n * 128u + k * 64u + i)) * 128u + o
                        : G1H + ((size_t)(n * 128u + k * 64u + (i - 64u))) * 128u + o;
        NW_ACCUM(S_GW1, 32768u);
    } else if (i4 < 4455184u) {        // s5: gb1, J=128 (J4=32)
        unsigned rem = i4 - 4445360u;
        n = rem >> 5;
        unsigned j = (rem & 31u) * 4u;
        dst = BG1 + (size_t)n * 128u + j;
        NW_ACCUM(S_GB1, 128u);
    } else if (i4 < 5712656u) {        // s6: uw1, J=16384 (J4=4096)
        unsigned rem = i4 - 4455184u;
        n = rem >> 12;
        unsigned j = (rem & 4095u) * 4u;
        unsigned o = j & 63u, kk = j >> 6;
        unsigned k = kk >> 7, i = kk & 127u;
        dst = (i < 64u) ? U1X + ((size_t)(n * 128u + k * 64u + i)) * 64u + o
                        : U1H + ((size_t)(n * 128u + k * 64u + (i - 64u))) * 64u + o;
        NW_ACCUM(S_UW1, 16384u);
    } else {                           // s7: ub1, J=64 (J4=16)
        unsigned rem = i4 - 5712656u;
        n = rem >> 4;
        unsigned j = (rem & 15u) * 4u;
        dst = BU1 + (size_t)n * 64u + j;
        NW_ACCUM(S_UB1, 64u);
    }
    #undef NW_ACCUM
    *(float4*)&g_buf[dst] = make_float4(a0, a1, a2, a3);
}

// ---------------- positional embedding ----------------
__global__ void k_pe() {
    int tid = threadIdx.x;            // 768
    int t = tid >> 6, h = tid & 63;
    float ex = (float)(h & ~1) / 64.f;
    float ang = (float)t * powf(10000.f, -ex);
    g_buf[OFF_PE + tid] = (h & 1) ? cosf(ang) : sinf(ang);
}

__global__ void k_zero(size_t off, int cnt) {
    int i = blockIdx.x * 256 + threadIdx.x;
    if (i < cnt) g_buf[off + i] = 0.f;
}

// ---------------- AX0[t][n][b] = sum_m A[n,m] * src[b,t,m] ----------------
__global__ __launch_bounds__(256) void k_ax0() {
    int t = blockIdx.y;
    int n0 = blockIdx.x * 8;
    int b = threadIdx.x & 31, nl = threadIdx.x >> 5;
    __shared__ float As[8][68];
    __shared__ float xs[32][65];
    float acc = 0.f;
    for (int m0 = 0; m0 < NN; m0 += 64) {
        int jend = min(64, NN - m0);
        for (int idx = threadIdx.x; idx < 8 * 64; idx += 256) {
            int i = idx >> 6, jj = idx & 63;
            int n = n0 + i, m = m0 + jj;
            As[i][jj] = (n < NN && m < NN) ? g_buf[OFF_A + (size_t)n * NN + m] : 0.f;
        }
        for (int idx = threadIdx.x; idx < 32 * 64; idx += 256) {
            int bb = idx >> 6, jj = idx & 63;
            int m = m0 + jj;
            xs[bb][jj] = (m < NN) ? g_buf[S_SRC + ((size_t)bb * TT + t) * NN + m] : 0.f;
        }
        __syncthreads();
        for (int jj = 0; jj < jend; jj++) acc += As[nl][jj] * xs[b][jj];
        __syncthreads();
    }
    int n = n0 + nl;
    if (n < NN) g_buf[OFF_AX0 + ((size_t)t * NN + n) * 32 + b] = acc;
}

// ---------------- batched agg GEMM: z selects job ----------------
// mode 0 (z<2): z=0 H0->AGG0 (+dual-write AX1[s-1]); z=1 H1->AGG1
// mode 1 (z<2): ZH0->AGG0, ZH1->AGG1
// r16: As staged from A^T (coalesced + conflict-free); K-chunk 64.
__global__ __launch_bounds__(256) void k_aggB(int s, int mode) {
    int z = blockIdx.z;
    size_t srcOff, dstOff;
    float* __restrict__ dstp2 = nullptr;
    if (mode == 0) {
        if (z == 0) { srcOff = OFF_H0; dstOff = OFF_AGG0;
                      dstp2 = g_buf + OFF_AX1 + (size_t)(s - 1) * 628736; }
        else        { srcOff = OFF_H1; dstOff = OFF_AGG1; }
    } else {
        srcOff = z ? OFF_ZH1 : OFF_ZH0;
        dstOff = z ? OFF_AGG1 : OFF_AGG0;
    }
    const float* __restrict__ srcp = g_buf + srcOff;
    float* __restrict__ dstp = g_buf + dstOff;
    int n0 = blockIdx.x * 64;
    int col0 = blockIdx.y * 64;
    int tid = threadIdx.x;
    int tn = tid >> 4, tc = tid & 15;
    __shared__ float As[64][68];
    __shared__ float Xs[64][64];
    float acc[4][4];
    #pragma unroll
    for (int i = 0; i < 4; i++)
        #pragma unroll
        for (int j = 0; j < 4; j++) acc[i][j] = 0.f;
    for (int k0 = 0; k0 < NN; k0 += 64) {
        // As[k][i] = A[n0+i][m0+k] staged from AT[m0+k][n0+i]; i lane-fast ->
        // coalesced global + conflict-free LDS write (r16).
        for (int idx = tid; idx < 64 * 64; idx += 256) {
            int i = idx & 63, k = idx >> 6;
            int n = n0 + i, m = k0 + k;
            As[k][i] = (n < NN && m < NN) ? g_buf[OFF_AT + (size_t)m * NN + n] : 0.f;
        }
        for (int idx = tid; idx < 64 * 16; idx += 256) {
            int c4 = idx & 15, k = idx >> 4;
            int m = k0 + k;
            float4 v = (m < NN) ? *(const float4*)&srcp[(size_t)m * 2048 + col0 + c4 * 4]
                                : make_float4(0.f, 0.f, 0.f, 0.f);
            *(float4*)&Xs[k][c4 * 4] = v;
        }
        __syncthreads();
        #pragma unroll
        for (int k = 0; k < 64; k++) {
            float4 a4 = *(const float4*)&As[k][tn * 4];
            float4 x4 = *(const float4*)&Xs[k][tc * 4];
            const float* aa = (const float*)&a4;
            const float* xx = (const float*)&x4;
            #pragma unroll
            for (int i = 0; i < 4; i++)
                #pragma unroll
                for (int j = 0; j < 4; j++) acc[i][j] += aa[i] * xx[j];
        }
        __syncthreads();
    }
    #pragma unroll
    for (int i = 0; i < 4; i++) {
        int n = n0 + tn * 4 + i;
        if (n < NN) {
            float4 v = make_float4(acc[i][0], acc[i][1], acc[i][2], acc[i][3]);
            size_t doff = (size_t)n * 2048 + col0 + tc * 4;
            *(float4*)&dstp[doff] = v;
            if (dstp2) *(float4*)&dstp2[doff] = v;
        }
    }
}

// ---------------- x-part preact precompute, layer 0 (K=2); grid (12, NN) ----------------
__global__ __launch_bounds__(256) void k_xprep0() {
    int t = blockIdx.x, n = blockIdx.y, tid = threadIdx.x;
    __shared__ float xv[32], ax[32];
    if (tid < 32) {
        xv[tid] = g_buf[S_SRC + ((size_t)tid * TT + t) * NN + n];
        ax[tid] = g_buf[OFF_AX0 + ((size_t)t * NN + n) * 32 + tid];
    }
    __syncthreads();
    size_t pbase = ((size_t)t * NN + n) * 32;
    for (int idx = tid; idx < 4096; idx += 256) {
        int b = idx >> 7, o = idx & 127;
        g_buf[OFF_GXP + (pbase + b) * 128 + o] =
            g_buf[BG0 + (size_t)n * 128 + o]
          + g_buf[G0X + ((size_t)n * 2 + 0) * 128 + o] * xv[b]
          + g_buf[G0X + ((size_t)n * 2 + 1) * 128 + o] * ax[b];
    }
    for (int idx = tid; idx < 2048; idx += 256) {
        int b = idx >> 6, o = idx & 63;
        g_buf[OFF_UXP + (pbase + b) * 64 + o] =
            g_buf[BU0 + (size_t)n * 64 + o]
          + g_buf[U0X + ((size_t)n * 2 + 0) * 64 + o] * xv[b]
          + g_buf[U0X + ((size_t)n * 2 + 1) * 64 + o] * ax[b];
    }
}

// ======== merged pipelined gate (r15: direct global weight streaming) ========
// smem: xh 32*136 | xx 32*136 (no Wl; no K-loop barriers)
__global__ __launch_bounds__(256) void k_gateM(int s) {
    __shared__ float smem[8704];
    float* xh = smem;
    float* xx = smem + 4352;
    int lay = (blockIdx.x >= NN) ? 1 : 0;
    int n = blockIdx.x - lay * NN;
    int t = lay ? (s - 1) : s;
    if (t < 0 || t >= TT) return;
    int tid = threadIdx.x;
    size_t Hoff = lay ? OFF_H1 : OFF_H0;
    size_t Aoff = lay ? OFF_AGG1 : OFF_AGG0;
    for (int idx = tid; idx < 4096; idx += 256) {
        int bl = idx >> 7, c = idx & 127;
        float v = (c < 64) ? g_buf[Hoff + (size_t)n * 2048 + bl * 64 + c]
                           : g_buf[Aoff + (size_t)n * 2048 + bl * 64 + (c - 64)];
        xh[bl * 136 + c] = v;
    }
    if (lay) {
        size_t pb = ((size_t)t * NN + n) * 2048;
        for (int idx = tid; idx < 4096; idx += 256) {
            int bl = idx >> 7, c = idx & 127;
            float v = (c < 64) ? g_buf[OFF_OUT0 + pb + bl * 64 + c]
                               : g_buf[OFF_AX1 + pb + bl * 64 + (c - 64)];
            xx[bl * 136 + c] = v;
        }
    }
    __syncthreads();
    int o = tid & 63, bl0 = (tid >> 6) * 8;
    size_t pbase = ((size_t)t * NN + n) * 32;
    float accz[8], accr[8];
    if (lay) {
        #pragma unroll
        for (int j = 0; j < 8; j++) {
            accz[j] = g_buf[BG1 + (size_t)n * 128 + o];
            accr[j] = g_buf[BG1 + (size_t)n * 128 + o + 64];
        }
    } else {
        #pragma unroll
        for (int j = 0; j < 8; j++) {
            accz[j] = g_buf[OFF_GXP + (pbase + bl0 + j) * 128 + o];
            accr[j] = g_buf[OFF_GXP + (pbase + bl0 + j) * 128 + o + 64];
        }
    }

#define GATE_MAC(WP, XP)                                                       \
    _Pragma("unroll 2")                                                        \
    for (int kq = 0; kq < 128; kq += 4) {                                      \
        float w00 = (WP)[(kq + 0) * 128 + o], w01 = (WP)[(kq + 0) * 128 + o + 64]; \
        float w10 = (WP)[(kq + 1) * 128 + o], w11 = (WP)[(kq + 1) * 128 + o + 64]; \
        float w20 = (WP)[(kq + 2) * 128 + o], w21 = (WP)[(kq + 2) * 128 + o + 64]; \
        float w30 = (WP)[(kq + 3) * 128 + o], w31 = (WP)[(kq + 3) * 128 + o + 64]; \
        _Pragma("unroll")                                                      \
        for (int j = 0; j < 8; j++) {                                          \
            float4 xv = *(const float4*)&(XP)[(bl0 + j) * 136 + kq];           \
            accz[j] += xv.x * w00 + xv.y * w10 + xv.z * w20 + xv.w * w30;      \
            accr[j] += xv.x * w01 + xv.y * w11 + xv.z * w21 + xv.w * w31;      \
        }                                                                      \
    }

    if (lay) {
        const float* __restrict__ W0 = g_buf + G1X + (size_t)n * 16384;
        GATE_MAC(W0, xx);
        if (t > 0) {
            const float* __restrict__ W1 = g_buf + G1H + (size_t)n * 16384;
            GATE_MAC(W1, xh);
        }
    } else if (t > 0) {
        const float* __restrict__ W0 = g_buf + G0H + (size_t)n * 16384;
        GATE_MAC(W0, xh);
    }
#undef GATE_MAC

    size_t ZHoff = lay ? OFF_ZH1 : OFF_ZH0;
    size_t Roff  = lay ? OFF_R1 : OFF_R0;
    #pragma unroll
    for (int j = 0; j < 8; j++) {
        int b = bl0 + j;
        float z = 1.f / (1.f + expf(-accz[j]));
        float r = 1.f / (1.f + expf(-accr[j]));
        float hv = xh[b * 136 + o];
        g_buf[ZHoff + (size_t)n * 2048 + (size_t)b * 64 + o] = z * hv;
        g_buf[Roff  + (size_t)n * 2048 + (size_t)b * 64 + o] = r;
    }
}

// ======== merged pipelined update (r15: direct global weight streaming) ========
__global__ __launch_bounds__(256) void k_updM(int s) {
    __shared__ float smem[8704];
    float* xh = smem;
    float* xx = smem + 4352;
    int lay = (blockIdx.x >= NN) ? 1 : 0;
    int n = blockIdx.x - lay * NN;
    int t = lay ? (s - 1) : s;
    if (t < 0 || t >= TT) return;
    int tid = threadIdx.x;
    size_t ZHoff = lay ? OFF_ZH1 : OFF_ZH0;
    size_t Aoff  = lay ? OFF_AGG1 : OFF_AGG0;
    for (int idx = tid; idx < 4096; idx += 256) {
        int bl = idx >> 7, c = idx & 127;
        float v = (c < 64) ? g_buf[ZHoff + (size_t)n * 2048 + bl * 64 + c]
                           : g_buf[Aoff + (size_t)n * 2048 + bl * 64 + (c - 64)];
        xh[bl * 136 + c] = v;
    }
    if (lay) {
        size_t pb = ((size_t)t * NN + n) * 2048;
        for (int idx = tid; idx < 4096; idx += 256) {
            int bl = idx >> 7, c = idx & 127;
            float v = (c < 64) ? g_buf[OFF_OUT0 + pb + bl * 64 + c]
                               : g_buf[OFF_AX1 + pb + bl * 64 + (c - 64)];
            xx[bl * 136 + c] = v;
        }
    }
    __syncthreads();
    int o = tid & 63, bl0 = (tid >> 6) * 8;
    size_t pbase = ((size_t)t * NN + n) * 32;
    float acc[8];
    if (lay) {
        #pragma unroll
        for (int j = 0; j < 8; j++) acc[j] = g_buf[BU1 + (size_t)n * 64 + o];
    } else {
        #pragma unroll
        for (int j = 0; j < 8; j++) acc[j] = g_buf[OFF_UXP + (pbase + bl0 + j) * 64 + o];
    }

#define UPD_MAC(WP, XP)                                                        \
    _Pragma("unroll 2")                                                        \
    for (int kq = 0; kq < 128; kq += 4) {                                      \
        float w0 = (WP)[(kq + 0) * 64 + o];                                    \
        float w1 = (WP)[(kq + 1) * 64 + o];                                    \
        float w2 = (WP)[(kq + 2) * 64 + o];                                    \
        float w3 = (WP)[(kq + 3) * 64 + o];                                    \
        _Pragma("unroll")                                                      \
        for (int j = 0; j < 8; j++) {                                          \
            float4 xv = *(const float4*)&(XP)[(bl0 + j) * 136 + kq];           \
            acc[j] += xv.x * w0 + xv.y * w1 + xv.z * w2 + xv.w * w3;           \
        }                                                                      \
    }

    if (lay) {
        const float* __restrict__ W0 = g_buf + U1X + (size_t)n * 8192;
        UPD_MAC(W0, xx);
        if (t > 0) {
            const float* __restrict__ W1 = g_buf + U1H + (size_t)n * 8192;
            UPD_MAC(W1, xh);
        }
    } else if (t > 0) {
        const float* __restrict__ W0 = g_buf + U0H + (size_t)n * 8192;
        UPD_MAC(W0, xh);
    }
#undef UPD_MAC

    size_t Hoff = lay ? OFF_H1 : OFF_H0;
    size_t Roff = lay ? OFF_R1 : OFF_R0;
    #pragma unroll
    for (int j = 0; j < 8; j++) {
        int b = bl0 + j;
        size_t base = (size_t)n * 2048 + (size_t)b * 64 + o;
        float hc = tanhf(acc[j]);
        float r = g_buf[Roff + base];
        float hold = g_buf[Hoff + base];
        float hn = r * hold + (1.f - r) * hc;
        g_buf[Hoff + base] = hn;
        if (!lay) g_buf[OFF_OUT0 + (pbase + b) * 64 + o] = hn;
    }
}

// ---------------- fused attention (t=T-1 only) + LN1; 4 (b,n) per block ----------------
// r13: i4-blocked projection — float4 broadcast x reads, coalesced w loads.
__global__ __launch_bounds__(256) void k_attn() {
    int wid = threadIdx.x >> 6;
    int lane = threadIdx.x & 63;
    int g = blockIdx.x * 4 + wid;
    int b = g / NN, n = g - b * NN;
    __shared__ float x[4][TT][HH], kk[4][TT][HH], vv[4][TT][HH];
    __shared__ float q[4][HH], o1[4][HH], sc[4][HEADS][TT], aw[4][HEADS][TT];
    float mw = g_buf[S_MLW + lane];
    float mb = g_buf[S_MLB + lane];
    #pragma unroll
    for (int tt = 0; tt < TT; tt++) {
        float s = g_buf[S_SRC + ((size_t)b * TT + tt) * NN + n];
        x[wid][tt][lane] = s * mw + mb + g_buf[OFF_PE + tt * HH + lane];
    }
    __syncthreads();
    float ka[TT], va[TT];
    #pragma unroll
    for (int tt = 0; tt < TT; tt++) { ka[tt] = g_buf[S_BK + lane]; va[tt] = g_buf[S_BV + lane]; }
    float qa = g_buf[S_BQ + lane];
    for (int i0 = 0; i0 < HH; i0 += 4) {
        float wk0 = g_buf[S_WK + (i0 + 0) * HH + lane];
        float wk1 = g_buf[S_WK + (i0 + 1) * HH + lane];
        float wk2 = g_buf[S_WK + (i0 + 2) * HH + lane];
        float wk3 = g_buf[S_WK + (i0 + 3) * HH + lane];
        float wv0 = g_buf[S_WV + (i0 + 0) * HH + lane];
        float wv1 = g_buf[S_WV + (i0 + 1) * HH + lane];
        float wv2 = g_buf[S_WV + (i0 + 2) * HH + lane];
        float wv3 = g_buf[S_WV + (i0 + 3) * HH + lane];
        float wq0 = g_buf[S_WQ + (i0 + 0) * HH + lane];
        float wq1 = g_buf[S_WQ + (i0 + 1) * HH + lane];
        float wq2 = g_buf[S_WQ + (i0 + 2) * HH + lane];
        float wq3 = g_buf[S_WQ + (i0 + 3) * HH + lane];
        float4 xq = *(const float4*)&x[wid][TT - 1][i0];
        qa += xq.x * wq0 + xq.y * wq1 + xq.z * wq2 + xq.w * wq3;
        #pragma unroll
        for (int tt = 0; tt < TT; tt++) {
            float4 xv4 = *(const float4*)&x[wid][tt][i0];   // broadcast b128
            ka[tt] += xv4.x * wk0 + xv4.y * wk1 + xv4.z * wk2 + xv4.w * wk3;
            va[tt] += xv4.x * wv0 + xv4.y * wv1 + xv4.z * wv2 + xv4.w * wv3;
        }
    }
    #pragma unroll
    for (int tt = 0; tt < TT; tt++) { kk[wid][tt][lane] = ka[tt]; vv[wid][tt][lane] = va[tt]; }
    q[wid][lane] = qa;
    __syncthreads();
    if (lane < HEADS * TT) {
        int head = lane / TT, ts = lane - head * TT;
        float s = 0.f;
        #pragma unroll
        for (int d = 0; d < HD; d++) s += q[wid][head * HD + d] * kk[wid][ts][head * HD + d];
        sc[wid][head][ts] = s * 0.25f;
    }
    __syncthreads();
    if (lane < HEADS * TT) {
        int head = lane / TT, ts = lane - head * TT;
        float mx = -1e30f;
        #pragma unroll
        for (int j = 0; j < TT; j++) mx = fmaxf(mx, sc[wid][head][j]);
        float sm = 0.f;
        #pragma unroll
        for (int j = 0; j < TT; j++) sm += expf(sc[wid][head][j] - mx);
        aw[wid][head][ts] = expf(sc[wid][head][ts] - mx) / sm;
    }
    __syncthreads();
    int head = lane >> 4;
    float oa = 0.f;
    #pragma unroll
    for (int tt = 0; tt < TT; tt++) oa += aw[wid][head][tt] * vv[wid][tt][lane];
    o1[wid][lane] = oa;
    __syncthreads();
    float acc = g_buf[S_BO + lane];
    for (int i0 = 0; i0 < HH; i0 += 4) {
        float w0 = g_buf[S_WO + (i0 + 0) * HH + lane];
        float w1 = g_buf[S_WO + (i0 + 1) * HH + lane];
        float w2 = g_buf[S_WO + (i0 + 2) * HH + lane];
        float w3 = g_buf[S_WO + (i0 + 3) * HH + lane];
        float4 ov = *(const float4*)&o1[wid][i0];
        acc += ov.x * w0 + ov.y * w1 + ov.z * w2 + ov.w * w3;
    }
    float res = x[wid][TT - 1][lane] + acc;
    float mean = wave_sum(res) * (1.f / 64.f);
    float dv = res - mean;
    float var = wave_sum(dv * dv) * (1.f / 64.f);
    float ln = dv * rsqrtf(var + 1e-5f) * g_buf[S_L1G + lane] + g_buf[S_L1B + lane];
    g_buf[OFF_OLN + ((size_t)b * NN + n) * HH + lane] = ln;
}

// ---------------- FFN + LN2; 8 tokens per block ----------------
// r13 rewrite: phase1 i4-blocked 4-j register tile; phase2 j-split across the
// 4 waves (w2 loaded 1x/block) + cross-wave reduction reusing hid[] LDS.
__global__ __launch_bounds__(256) void k_ffn() {
    int tok0 = blockIdx.x * 8;
    int tid = threadIdx.x;
    int lane = tid & 63, wvid = tid >> 6;
    __shared__ float ox[8][HH];
    __shared__ float hid[8][1024];
    for (int idx = tid; idx < 8 * HH; idx += 256) {
        int tk = idx >> 6, hh = idx & 63;
        ox[tk][hh] = g_buf[OFF_OLN + (size_t)(tok0 + tk) * HH + hh];
    }
    __syncthreads();
    // ---- phase 1: hid = relu(ox @ w1 + b1); thread owns 4 j (tid+256p) x 8 tk ----
    {
        float acc[4][8];
        #pragma unroll
        for (int p = 0; p < 4; p++) {
            float bj = g_buf[S_FB1 + tid + 256 * p];
            #pragma unroll
            for (int tk = 0; tk < 8; tk++) acc[p][tk] = bj;
        }
        for (int i0 = 0; i0 < HH; i0 += 4) {
            float w1r[4][4];
            #pragma unroll
            for (int qq = 0; qq < 4; qq++)
                #pragma unroll
                for (int p = 0; p < 4; p++)
                    w1r[p][qq] = g_buf[S_FW1 + (size_t)(i0 + qq) * 1024 + tid + 256 * p];
            #pragma unroll
            for (int tk = 0; tk < 8; tk++) {
                float4 xo = *(const float4*)&ox[tk][i0];    // broadcast b128
                const float* xp = (const float*)&xo;
                #pragma unroll
                for (int p = 0; p < 4; p++)
                    acc[p][tk] += xp[0] * w1r[p][0] + xp[1] * w1r[p][1]
                                + xp[2] * w1r[p][2] + xp[3] * w1r[p][3];
            }
        }
        #pragma unroll
        for (int p = 0; p < 4; p++)
            #pragma unroll
            for (int tk = 0; tk < 8; tk++)
                hid[tk][tid + 256 * p] = fmaxf(acc[p][tk], 0.f);
    }
    __syncthreads();
    // ---- phase 2: each wave covers j in [wvid*256, wvid*256+256) for ALL 8 tk ----
    float pa[8], pb[8];
    #pragma unroll
    for (int tk = 0; tk < 8; tk++) { pa[tk] = 0.f; pb[tk] = 0.f; }
    {
        int jbase = wvid * 256;
        #pragma unroll 2
        for (int j4 = 0; j4 < 256; j4 += 4) {
            int j0 = jbase + j4;
            float w0 = g_buf[S_FW2 + (size_t)(j0 + 0) * HH + lane];
            float w1 = g_buf[S_FW2 + (size_t)(j0 + 1) * HH + lane];
            float w2 = g_buf[S_FW2 + (size_t)(j0 + 2) * HH + lane];
            float w3 = g_buf[S_FW2 + (size_t)(j0 + 3) * HH + lane];
            #pragma unroll
            for (int tk = 0; tk < 8; tk++) {
                float4 h4 = *(const float4*)&hid[tk][j0];   // broadcast b128
                pa[tk] += h4.x * w0 + h4.y * w1;
                pb[tk] += h4.z * w2 + h4.w * w3;
            }
        }
    }
    __syncthreads();                       // all waves done reading hid
    {
        float* rp = &hid[0][0];            // reuse hid LDS as red[4][8][64]
        #pragma unroll
        for (int tk = 0; tk < 8; tk++)
            rp[(wvid * 8 + tk) * 64 + lane] = pa[tk] + pb[tk];
    }
    __syncthreads();
    int tk = wvid, hh = lane;
    float acc0 = g_buf[S_FB2 + hh], acc1 = acc0;
    {
        const float* rp = &hid[0][0];
        #pragma unroll
        for (int w = 0; w < 4; w++) {
            acc0 += rp[(w * 8 + tk) * 64 + hh];
            acc1 += rp[(w * 8 + tk + 4) * 64 + hh];
        }
    }
    #pragma unroll
    for (int ph = 0; ph < 2; ph++) {
        int tkk = tk + 4 * ph;
        float res = ox[tkk][hh] + (ph ? acc1 : acc0);
        float mean = wave_sum(res) * (1.f / 64.f);
        float dv = res - mean;
        float var = wave_sum(dv * dv) * (1.f / 64.f);
        float ln = dv * rsqrtf(var + 1e-5f) * g_buf[S_L2G + hh] + g_buf[S_L2B + hh];
        g_buf[OFF_O2 + (size_t)(tok0 + tkk) * HH + hh] = ln;
    }
}

// ---------------- final combine + horizon conv (layer-1 h is OFF_H1) ----------------
__global__ void k_final(void* out) {
    int n = blockIdx.x, b = blockIdx.y;
    int h = threadIdx.x;
    __shared__ float comb[HH];
    comb[h] = g_buf[OFF_H1 + ((size_t)n * 32 + b) * 64 + h] * g_buf[S_WS + n * HH + h]
            + g_buf[OFF_O2 + ((size_t)b * NN + n) * 64 + h] * g_buf[S_WT + n * HH + h];
    __syncthreads();
    if (h < HORIZON) {
        float acc = g_buf[S_CB + h];
        #pragma unroll
        for (int i = 0; i < HH; i++) acc += comb[i] * g_buf[S_CW + h * HH + i];
        size_t oi = ((size_t)b * HORIZON + h) * NN + n;
        if (g_flag) ((bf16*)out)[oi] = __float2bfloat16(acc);
        else        ((float*)out)[oi] = acc;
    }
}

extern "C" void kernel_launch(void* const* d_in, const int* in_sizes, int n_in,
                              void* d_out, int out_size, void* d_ws, size_t ws_size,
                              hipStream_t stream) {
    PtrPack pk;
    for (int i = 0; i < 32; i++) pk.p[i] = d_in[i];

    k_detect<<<1, 64, 0, stream>>>(d_in[1]);
    k_ingest<<<4133, 256, 0, stream>>>(pk);
    k_adj<<<NN, 512, 0, stream>>>();
    k_nodew_all<<<22335, 256, 0, stream>>>();
    k_pe<<<1, 768, 0, stream>>>();
    k_ax0<<<dim3(39, 12), 256, 0, stream>>>();
    k_xprep0<<<dim3(12, NN), 256, 0, stream>>>();
    k_zero<<<2456, 256, 0, stream>>>(OFF_H0, 628736);
    k_zero<<<2456, 256, 0, stream>>>(OFF_H1, 628736);

    // ---- pipelined supersteps: L0 t=s, L1 t=s-1 ----
    k_gateM<<<2 * NN, 256, 0, stream>>>(0);
    k_updM<<<2 * NN, 256, 0, stream>>>(0);
    for (int s = 1; s <= TT; s++) {
        k_aggB<<<dim3(5, 32, 2), 256, 0, stream>>>(s, 0);  // A@H0 (dual->AX1[s-1]), A@H1
        k_gateM<<<2 * NN, 256, 0, stream>>>(s);
        k_aggB<<<dim3(5, 32, 2), 256, 0, stream>>>(s, 1);  // A@ZH0, A@ZH1
        k_updM<<<2 * NN, 256, 0, stream>>>(s);
    }

    // ---- transformer branch ----
    k_attn<<<2456, 256, 0, stream>>>();
    k_ffn<<<1228, 256, 0, stream>>>();
    // ---- combine + conv ----
    k_final<<<dim3(NN, BB), 64, 0, stream>>>(d_out);
}

// Round 5
// 1854.528 us; speedup vs baseline: 1.5876x; 1.1619x over previous
//
#include <hip/hip_runtime.h>
#include <hip/hip_bf16.h>

typedef __hip_bfloat16 bf16;

constexpr int NN = 307, TT = 12, BB = 32, HH = 64, EE = 10, HEADS = 4, HD = 16, HORIZON = 12;

// ---------------- staged fp32 input offsets ----------------
constexpr int S_SRC = 0,       S_EMB = 117888,  S_GW0 = 120958,  S_GB0 = 287358,
              S_UW0 = 288638,  S_UB0 = 371838,  S_GW1 = 372478,  S_GB1 = 700158,
              S_UW1 = 701438,  S_UB1 = 865278,  S_MLW = 865918,  S_MLB = 865982,
              S_WQ  = 866046,  S_BQ  = 870142,  S_WK  = 870206,  S_BK  = 874302,
              S_WV  = 874366,  S_BV  = 878462,  S_WO  = 878526,  S_BO  = 882622,
              S_FW1 = 882686,  S_FB1 = 948222,  S_FW2 = 949246,  S_FB2 = 1014782,
              S_L1G = 1014846, S_L1B = 1014910, S_L2G = 1014974, S_L2B = 1015038,
              S_WS  = 1015102, S_WT  = 1034750, S_CW  = 1054398, S_CB  = 1055166;

// ---------------- fp32 work regions ----------------
constexpr size_t OFF_A    = 1055178;   // 307*307
constexpr size_t OFF_OUT0 = 1149427;   // [t][n][b][c] 12*307*2048
constexpr size_t OFF_H0   = 8694259;   // [n][b][c] 307*2048 (layer 0)
constexpr size_t OFF_ZH0  = 9322995;
constexpr size_t OFF_R0   = 9951731;
constexpr size_t OFF_AX0  = 11209203;  // [t][n][b] 12*307*32
constexpr size_t OFF_AX1  = 11327091;  // [t][n][b][c] 12*307*2048
constexpr size_t OFF_PE   = 18871923;  // 12*64
constexpr size_t OFF_OLN  = 18872691;
constexpr size_t OFF_O2   = 19501427;
constexpr size_t OFF_WB   = 20130164;  // fp32 reordered per-node GRU weights

// Reordered weight blocks (fp32; bf16 storage fails: scan amplifies to 0.19 absmax — r3)
constexpr size_t G0X = OFF_WB +        0;  // 307*2*128
constexpr size_t G0H = OFF_WB +    78592;  // 307*128*128
constexpr size_t BG0 = OFF_WB +  5108480;  // 307*128
constexpr size_t U0X = OFF_WB +  5147776;  // 307*2*64
constexpr size_t U0H = OFF_WB +  5187072;  // 307*128*64
constexpr size_t BU0 = OFF_WB +  7702016;  // 307*64
constexpr size_t G1X = OFF_WB +  7721664;  // 307*128*128
constexpr size_t G1H = OFF_WB + 12751552;  // 307*128*128
constexpr size_t BG1 = OFF_WB + 17781440;  // 307*128
constexpr size_t U1X = OFF_WB + 17820736;  // 307*128*64
constexpr size_t U1H = OFF_WB + 20335680;  // 307*128*64
constexpr size_t BU1 = OFF_WB + 22850624;  // 307*64
constexpr size_t OFF_GXP = OFF_WB + 22870272;       // [t][n][b][128] L0 preact x-part (bias folded)
constexpr size_t OFF_UXP = OFF_GXP + 15089664;      // [t][n][b][64]
constexpr size_t OFF_H1  = OFF_UXP + 7544832;       // layer-1 state buffers
constexpr size_t OFF_ZH1 = OFF_H1  + 628736;
constexpr size_t OFF_R1  = OFF_ZH1 + 628736;
constexpr size_t OFF_AGG0 = OFF_R1  + 628736;       // A@H (or A@ZH) per layer
constexpr size_t OFF_AGG1 = OFF_AGG0 + 628736;
constexpr size_t OFF_AT   = OFF_AGG1 + 628736;      // A^T (307*307), r16
constexpr size_t G_TOTAL  = OFF_AT + 94249 + 4096;

// r16->r17 post-mortem: r16 gained only ~30us -> aggB wasn't the superstep cost;
// chain kernels are LATENCY/OCCUPANCY-bound (gateM/updM 614 blocks = 2.4/CU,
// aggB 320 = 1.25/CU; per-thread FMA time ~1.7us vs ~40us dispatch). r17:
// (a) gateM split by OUTPUT half (z-blocks / r-blocks, grid (614,2)) — W traffic
// unchanged (each block reads only its 64 W cols), ZH/R writes disjoint,
// 1228 blocks ~4.8/CU. (b) updM split by BATCH half (grid (614,2)), LDS 35->17KB.
// (c) aggB tile 64x64 -> 32x64 (grid (10,32,2) = 640 blocks). (d) k_zero REMOVED:
// (t==0)?0: guards on hv/hold cover every stale-H read (incl. cross-iteration
// staleness). Accumulation order bitwise identical everywhere.

__device__ float g_buf[G_TOTAL];
__device__ int g_flag;   // 1 = inputs are bf16, 0 = fp32

__device__ __forceinline__ float wave_sum(float v) {
    #pragma unroll
    for (int off = 32; off > 0; off >>= 1) v += __shfl_xor(v, off, 64);
    return v;
}

// ---------------- dtype detection ----------------
__global__ void k_detect(const void* emb_raw) {
    const bf16* p = (const bf16*)emb_raw;
    int lane = threadIdx.x;
    float v = __bfloat162float(p[lane]);
    bool plaus = (v == v) && (fabsf(v) <= 1e4f) && (v == 0.f || fabsf(v) >= 1e-4f);
    float c = wave_sum(plaus ? 1.f : 0.f);
    if (lane == 0) g_flag = (c >= 52.f) ? 1 : 0;
}

// ---------------- ingest all inputs as fp32 ----------------
struct PtrPack { const void* p[32]; };
__device__ const int D_CNT[32] = {117888,3070,166400,1280,83200,640,327680,1280,163840,640,
                                  64,64,4096,64,4096,64,4096,64,4096,64,
                                  65536,1024,65536,64,64,64,64,64,19648,19648,768,12};
__device__ const int D_OFF[32] = {S_SRC,S_EMB,S_GW0,S_GB0,S_UW0,S_UB0,S_GW1,S_GB1,S_UW1,S_UB1,
                                  S_MLW,S_MLB,S_WQ,S_BQ,S_WK,S_BK,S_WV,S_BV,S_WO,S_BO,
                                  S_FW1,S_FB1,S_FW2,S_FB2,S_L1G,S_L1B,S_L2G,S_L2B,S_WS,S_WT,S_CW,S_CB};
__device__ const int D_CHK[33] = {0,461,473,1123,1128,1453,1456,2736,2741,3381,3384,3385,3386,
                                  3402,3403,3419,3420,3436,3437,3453,3454,3710,3714,3970,3971,
                                  3972,3973,3974,3975,4052,4129,4132,4133};

__global__ void k_ingest(PtrPack pk) {
    int bid = blockIdx.x;
    int s = 0;
    while (s < 31 && bid >= D_CHK[s + 1]) s++;
    int i = (bid - D_CHK[s]) * 256 + threadIdx.x;
    if (i >= D_CNT[s]) return;
    float v;
    if (g_flag) v = __bfloat162float(((const bf16*)pk.p[s])[i]);
    else        v = ((const float*)pk.p[s])[i];
    g_buf[(size_t)D_OFF[s] + i] = v;
}

// ---------------- adjacency (also writes A^T for aggB staging — r16) ----------------
__global__ void k_adj() {
    int n = blockIdx.x;
    int tid = threadIdx.x;            // 512
    __shared__ float en[EE];
    __shared__ float red[512];
    if (tid < EE) en[tid] = g_buf[S_EMB + n * EE + tid];
    __syncthreads();
    bool act = tid < NN;
    float d = 0.f;
    if (act) {
        #pragma unroll
        for (int e = 0; e < EE; e++) d += en[e] * g_buf[S_EMB + tid * EE + e];
        d = fmaxf(d, 0.f);
    }
    red[tid] = act ? d : -1e30f;
    __syncthreads();
    for (int s = 256; s > 0; s >>= 1) { if (tid < s) red[tid] = fmaxf(red[tid], red[tid + s]); __syncthreads(); }
    float mx = red[0];
    __syncthreads();
    float ex = act ? expf(d - mx) : 0.f;
    red[tid] = ex;
    __syncthreads();
    for (int s = 256; s > 0; s >>= 1) { if (tid < s) red[tid] += red[tid + s]; __syncthreads(); }
    float inv = 1.f / red[0];
    if (act) {
        float av = ex * inv;
        g_buf[OFF_A  + (size_t)n * NN + tid] = av;       // A[n][m]
        g_buf[OFF_AT + (size_t)tid * NN + n] = av;       // AT[m][n]
    }
}

// ---------------- per-node GRU weights -> fp32, reordered into Wx/Wh blocks ----------------
// r14: 4 outputs/thread, compile-time divisors per segment, float4 stores.
__global__ void k_nodew_all() {
    unsigned i4 = blockIdx.x * 256u + threadIdx.x;
    if (i4 >= 5717568u) return;
    float a0 = 0.f, a1 = 0.f, a2 = 0.f, a3 = 0.f;
    size_t dst;
    unsigned n;

    #define NW_ACCUM(SRCOFF, JCONST) do {                                  \
        const float* eb = g_buf + S_EMB + n * EE;                          \
        const float* wp = g_buf + (SRCOFF) + j;                            \
        _Pragma("unroll")                                                  \
        for (int e = 0; e < EE; e++) {                                     \
            float ev = eb[e];                                              \
            a0 += ev * wp[0]; a1 += ev * wp[1];                            \
            a2 += ev * wp[2]; a3 += ev * wp[3];                            \
            wp += (JCONST);                                                \
        }                                                                  \
    } while (0)

    if (i4 < 1277120u) {               // s0: gw0, J=16640 (J4=4160)
        unsigned rem = i4;
        n = rem / 4160u;
        unsigned j = (rem - n * 4160u) * 4u;
        unsigned o = j & 127u, kk = j >> 7;
        unsigned k = (kk >= 65u) ? 1u : 0u, i = kk - k * 65u;
        dst = (i == 0u) ? G0X + ((size_t)(n * 2u + k)) * 128u + o
                        : G0H + ((size_t)(n * 128u + k * 64u + (i - 1u))) * 128u + o;
        NW_ACCUM(S_GW0, 16640u);
    } else if (i4 < 1286944u) {        // s1: gb0, J=128 (J4=32)
        unsigned rem = i4 - 1277120u;
        n = rem >> 5;
        unsigned j = (rem & 31u) * 4u;
        dst = BG0 + (size_t)n * 128u + j;
        NW_ACCUM(S_GB0, 128u);
    } else if (i4 < 1925504u) {        // s2: uw0, J=8320 (J4=2080)
        unsigned rem = i4 - 1286944u;
        n = rem / 2080u;
        unsigned j = (rem - n * 2080u) * 4u;
        unsigned o = j & 63u, kk = j >> 6;
        unsigned k = (kk >= 65u) ? 1u : 0u, i = kk - k * 65u;
        dst = (i == 0u) ? U0X + ((size_t)(n * 2u + k)) * 64u + o
                        : U0H + ((size_t)(n * 128u + k * 64u + (i - 1u))) * 64u + o;
        NW_ACCUM(S_UW0, 8320u);
    } else if (i4 < 1930416u) {        // s3: ub0, J=64 (J4=16)
        unsigned rem = i4 - 1925504u;
        n = rem >> 4;
        unsigned j = (rem & 15u) * 4u;
        dst = BU0 + (size_t)n * 64u + j;
        NW_ACCUM(S_UB0, 64u);
    } else if (i4 < 4445360u) {        // s4: gw1, J=32768 (J4=8192)
        unsigned rem = i4 - 1930416u;
        n = rem >> 13;
        unsigned j = (rem & 8191u) * 4u;
        unsigned o = j & 127u, kk = j >> 7;
        unsigned k = kk >> 7, i = kk & 127u;
        dst = (i < 64u) ? G1X + ((size_t)(n * 128u + k * 64u + i)) * 128u + o
                        : G1H + ((size_t)(n * 128u + k * 64u + (i - 64u))) * 128u + o;
        NW_ACCUM(S_GW1, 32768u);
    } else if (i4 < 4455184u) {        // s5: gb1, J=128 (J4=32)
        unsigned rem = i4 - 4445360u;
        n = rem >> 5;
        unsigned j = (rem & 31u) * 4u;
        dst = BG1 + (size_t)n * 128u + j;
        NW_ACCUM(S_GB1, 128u);
    } else if (i4 < 5712656u) {        // s6: uw1, J=16384 (J4=4096)
        unsigned rem = i4 - 4455184u;
        n = rem >> 12;
        unsigned j = (rem & 4095u) * 4u;
        unsigned o = j & 63u, kk = j >> 6;
        unsigned k = kk >> 7, i = kk & 127u;
        dst = (i < 64u) ? U1X + ((size_t)(n * 128u + k * 64u + i)) * 64u + o
                        : U1H + ((size_t)(n * 128u + k * 64u + (i - 64u))) * 64u + o;
        NW_ACCUM(S_UW1, 16384u);
    } else {                           // s7: ub1, J=64 (J4=16)
        unsigned rem = i4 - 5712656u;
        n = rem >> 4;
        unsigned j = (rem & 15u) * 4u;
        dst = BU1 + (size_t)n * 64u + j;
        NW_ACCUM(S_UB1, 64u);
    }
    #undef NW_ACCUM
    *(float4*)&g_buf[dst] = make_float4(a0, a1, a2, a3);
}

// ---------------- positional embedding ----------------
__global__ void k_pe() {
    int tid = threadIdx.x;            // 768
    int t = tid >> 6, h = tid & 63;
    float ex = (float)(h & ~1) / 64.f;
    float ang = (float)t * powf(10000.f, -ex);
    g_buf[OFF_PE + tid] = (h & 1) ? cosf(ang) : sinf(ang);
}

// ---------------- AX0[t][n][b] = sum_m A[n,m] * src[b,t,m] ----------------
__global__ __launch_bounds__(256) void k_ax0() {
    int t = blockIdx.y;
    int n0 = blockIdx.x * 8;
    int b = threadIdx.x & 31, nl = threadIdx.x >> 5;
    __shared__ float As[8][68];
    __shared__ float xs[32][65];
    float acc = 0.f;
    for (int m0 = 0; m0 < NN; m0 += 64) {
        int jend = min(64, NN - m0);
        for (int idx = threadIdx.x; idx < 8 * 64; idx += 256) {
            int i = idx >> 6, jj = idx & 63;
            int n = n0 + i, m = m0 + jj;
            As[i][jj] = (n < NN && m < NN) ? g_buf[OFF_A + (size_t)n * NN + m] : 0.f;
        }
        for (int idx = threadIdx.x; idx < 32 * 64; idx += 256) {
            int bb = idx >> 6, jj = idx & 63;
            int m = m0 + jj;
            xs[bb][jj] = (m < NN) ? g_buf[S_SRC + ((size_t)bb * TT + t) * NN + m] : 0.f;
        }
        __syncthreads();
        for (int jj = 0; jj < jend; jj++) acc += As[nl][jj] * xs[b][jj];
        __syncthreads();
    }
    int n = n0 + nl;
    if (n < NN) g_buf[OFF_AX0 + ((size_t)t * NN + n) * 32 + b] = acc;
}

// ---------------- batched agg GEMM: z selects job ----------------
// mode 0 (z<2): z=0 H0->AGG0 (+dual-write AX1[s-1]); z=1 H1->AGG1
// mode 1 (z<2): ZH0->AGG0, ZH1->AGG1
// r17: tile 32n x 64c, grid (10,32,2) = 640 blocks (was 320 @1.25/CU).
__global__ __launch_bounds__(256) void k_aggB(int s, int mode) {
    int z = blockIdx.z;
    size_t srcOff, dstOff;
    float* __restrict__ dstp2 = nullptr;
    if (mode == 0) {
        if (z == 0) { srcOff = OFF_H0; dstOff = OFF_AGG0;
                      dstp2 = g_buf + OFF_AX1 + (size_t)(s - 1) * 628736; }
        else        { srcOff = OFF_H1; dstOff = OFF_AGG1; }
    } else {
        srcOff = z ? OFF_ZH1 : OFF_ZH0;
        dstOff = z ? OFF_AGG1 : OFF_AGG0;
    }
    const float* __restrict__ srcp = g_buf + srcOff;
    float* __restrict__ dstp = g_buf + dstOff;
    int n0 = blockIdx.x * 32;
    int col0 = blockIdx.y * 64;
    int tid = threadIdx.x;
    int tn = tid >> 4, tc = tid & 15;       // i0 = tn*2, col = tc*4
    __shared__ float As[64][34];
    __shared__ float Xs[64][64];
    float acc[2][4];
    #pragma unroll
    for (int i = 0; i < 2; i++)
        #pragma unroll
        for (int j = 0; j < 4; j++) acc[i][j] = 0.f;
    for (int k0 = 0; k0 < NN; k0 += 64) {
        // As[k][i] = A[n0+i][k0+k] from AT[k0+k][n0+i]; i lane-fast ->
        // coalesced global + conflict-free LDS write.
        for (int idx = tid; idx < 64 * 32; idx += 256) {
            int i = idx & 31, k = idx >> 5;
            int n = n0 + i, m = k0 + k;
            As[k][i] = (n < NN && m < NN) ? g_buf[OFF_AT + (size_t)m * NN + n] : 0.f;
        }
        for (int idx = tid; idx < 64 * 16; idx += 256) {
            int c4 = idx & 15, k = idx >> 4;
            int m = k0 + k;
            float4 v = (m < NN) ? *(const float4*)&srcp[(size_t)m * 2048 + col0 + c4 * 4]
                                : make_float4(0.f, 0.f, 0.f, 0.f);
            *(float4*)&Xs[k][c4 * 4] = v;
        }
        __syncthreads();
        #pragma unroll
        for (int k = 0; k < 64; k++) {
            float a0 = As[k][tn * 2];
            float a1 = As[k][tn * 2 + 1];
            float4 x4 = *(const float4*)&Xs[k][tc * 4];
            const float* xx = (const float*)&x4;
            #pragma unroll
            for (int j = 0; j < 4; j++) {
                acc[0][j] += a0 * xx[j];
                acc[1][j] += a1 * xx[j];
            }
        }
        __syncthreads();
    }
    #pragma unroll
    for (int i = 0; i < 2; i++) {
        int n = n0 + tn * 2 + i;
        if (n < NN) {
            float4 v = make_float4(acc[i][0], acc[i][1], acc[i][2], acc[i][3]);
            size_t doff = (size_t)n * 2048 + col0 + tc * 4;
            *(float4*)&dstp[doff] = v;
            if (dstp2) *(float4*)&dstp2[doff] = v;
        }
    }
}

// ---------------- x-part preact precompute, layer 0 (K=2); grid (12, NN) ----------------
__global__ __launch_bounds__(256) void k_xprep0() {
    int t = blockIdx.x, n = blockIdx.y, tid = threadIdx.x;
    __shared__ float xv[32], ax[32];
    if (tid < 32) {
        xv[tid] = g_buf[S_SRC + ((size_t)tid * TT + t) * NN + n];
        ax[tid] = g_buf[OFF_AX0 + ((size_t)t * NN + n) * 32 + tid];
    }
    __syncthreads();
    size_t pbase = ((size_t)t * NN + n) * 32;
    for (int idx = tid; idx < 4096; idx += 256) {
        int b = idx >> 7, o = idx & 127;
        g_buf[OFF_GXP + (pbase + b) * 128 + o] =
            g_buf[BG0 + (size_t)n * 128 + o]
          + g_buf[G0X + ((size_t)n * 2 + 0) * 128 + o] * xv[b]
          + g_buf[G0X + ((size_t)n * 2 + 1) * 128 + o] * ax[b];
    }
    for (int idx = tid; idx < 2048; idx += 256) {
        int b = idx >> 6, o = idx & 63;
        g_buf[OFF_UXP + (pbase + b) * 64 + o] =
            g_buf[BU0 + (size_t)n * 64 + o]
          + g_buf[U0X + ((size_t)n * 2 + 0) * 64 + o] * xv[b]
          + g_buf[U0X + ((size_t)n * 2 + 1) * 64 + o] * ax[b];
    }
}

// ======== merged gate, r17: split by output half; grid (2NN, 2) ========
// half 0: z outputs (W cols 0..63) -> writes ZH; half 1: r outputs -> writes R.
// Each block reads only its 64 W columns -> total W traffic unchanged.
__global__ __launch_bounds__(256) void k_gateM(int s) {
    __shared__ float smem[8704];
    float* xh = smem;
    float* xx = smem + 4352;
    int lay = (blockIdx.x >= NN) ? 1 : 0;
    int n = blockIdx.x - lay * NN;
    int half = blockIdx.y;
    int t = lay ? (s - 1) : s;
    if (t < 0 || t >= TT) return;
    int tid = threadIdx.x;
    size_t Hoff = lay ? OFF_H1 : OFF_H0;
    size_t Aoff = lay ? OFF_AGG1 : OFF_AGG0;
    for (int idx = tid; idx < 4096; idx += 256) {
        int bl = idx >> 7, c = idx & 127;
        float v = (c < 64) ? g_buf[Hoff + (size_t)n * 2048 + bl * 64 + c]
                           : g_buf[Aoff + (size_t)n * 2048 + bl * 64 + (c - 64)];
        xh[bl * 136 + c] = v;
    }
    if (lay) {
        size_t pb = ((size_t)t * NN + n) * 2048;
        for (int idx = tid; idx < 4096; idx += 256) {
            int bl = idx >> 7, c = idx & 127;
            float v = (c < 64) ? g_buf[OFF_OUT0 + pb + bl * 64 + c]
                               : g_buf[OFF_AX1 + pb + bl * 64 + (c - 64)];
            xx[bl * 136 + c] = v;
        }
    }
    __syncthreads();
    int o = tid & 63, bl0 = (tid >> 6) * 8;
    int oc = half * 64 + o;                    // W column
    size_t pbase = ((size_t)t * NN + n) * 32;
    float acc[8];
    if (lay) {
        float b0 = g_buf[BG1 + (size_t)n * 128 + oc];
        #pragma unroll
        for (int j = 0; j < 8; j++) acc[j] = b0;
    } else {
        #pragma unroll
        for (int j = 0; j < 8; j++)
            acc[j] = g_buf[OFF_GXP + (pbase + bl0 + j) * 128 + oc];
    }

#define GATE_MAC(WP, XP)                                                       \
    _Pragma("unroll 2")                                                        \
    for (int kq = 0; kq < 128; kq += 4) {                                      \
        float w0 = (WP)[(kq + 0) * 128 + oc];                                  \
        float w1 = (WP)[(kq + 1) * 128 + oc];                                  \
        float w2 = (WP)[(kq + 2) * 128 + oc];                                  \
        float w3 = (WP)[(kq + 3) * 128 + oc];                                  \
        _Pragma("unroll")                                                      \
        for (int j = 0; j < 8; j++) {                                          \
            float4 xv = *(const float4*)&(XP)[(bl0 + j) * 136 + kq];           \
            acc[j] += xv.x * w0 + xv.y * w1 + xv.z * w2 + xv.w * w3;           \
        }                                                                      \
    }

    if (lay) {
        const float* __restrict__ W0 = g_buf + G1X + (size_t)n * 16384;
        GATE_MAC(W0, xx);
        if (t > 0) {
            const float* __restrict__ W1 = g_buf + G1H + (size_t)n * 16384;
            GATE_MAC(W1, xh);
        }
    } else if (t > 0) {
        const float* __restrict__ W0 = g_buf + G0H + (size_t)n * 16384;
        GATE_MAC(W0, xh);
    }
#undef GATE_MAC

    if (half == 0) {
        size_t ZHoff = lay ? OFF_ZH1 : OFF_ZH0;
        #pragma unroll
        for (int j = 0; j < 8; j++) {
            int b = bl0 + j;
            float zz = 1.f / (1.f + expf(-acc[j]));
            float hv = (t == 0) ? 0.f : xh[b * 136 + o];
            g_buf[ZHoff + (size_t)n * 2048 + (size_t)b * 64 + o] = zz * hv;
        }
    } else {
        size_t Roff = lay ? OFF_R1 : OFF_R0;
        #pragma unroll
        for (int j = 0; j < 8; j++) {
            int b = bl0 + j;
            float r = 1.f / (1.f + expf(-acc[j]));
            g_buf[Roff + (size_t)n * 2048 + (size_t)b * 64 + o] = r;
        }
    }
}

// ======== merged update, r17: split by batch half; grid (2NN, 2) ========
// half selects b in [half*16, half*16+16); LDS 17KB (stage only needed rows).
__global__ __launch_bounds__(256) void k_updM(int s) {
    __shared__ float smem[4352];
    float* xh = smem;
    float* xx = smem + 2176;
    int lay = (blockIdx.x >= NN) ? 1 : 0;
    int n = blockIdx.x - lay * NN;
    int half = blockIdx.y;
    int t = lay ? (s - 1) : s;
    if (t < 0 || t >= TT) return;
    int tid = threadIdx.x;
    size_t ZHoff = lay ? OFF_ZH1 : OFF_ZH0;
    size_t Aoff  = lay ? OFF_AGG1 : OFF_AGG0;
    for (int idx = tid; idx < 2048; idx += 256) {
        int bl = idx >> 7, c = idx & 127;
        int bg = half * 16 + bl;
        float v = (c < 64) ? g_buf[ZHoff + (size_t)n * 2048 + bg * 64 + c]
                           : g_buf[Aoff + (size_t)n * 2048 + bg * 64 + (c - 64)];
        xh[bl * 136 + c] = v;
    }
    if (lay) {
        size_t pb = ((size_t)t * NN + n) * 2048;
        for (int idx = tid; idx < 2048; idx += 256) {
            int bl = idx >> 7, c = idx & 127;
            int bg = half * 16 + bl;
            float v = (c < 64) ? g_buf[OFF_OUT0 + pb + bg * 64 + c]
                               : g_buf[OFF_AX1 + pb + bg * 64 + (c - 64)];
            xx[bl * 136 + c] = v;
        }
    }
    __syncthreads();
    int o = tid & 63, bl0 = (tid >> 6) * 4;    // local batch-block, j 0..3
    size_t pbase = ((size_t)t * NN + n) * 32;
    float acc[4];
    if (lay) {
        float b0 = g_buf[BU1 + (size_t)n * 64 + o];
        #pragma unroll
        for (int j = 0; j < 4; j++) acc[j] = b0;
    } else {
        #pragma unroll
        for (int j = 0; j < 4; j++)
            acc[j] = g_buf[OFF_UXP + (pbase + half * 16 + bl0 + j) * 64 + o];
    }

#define UPD_MAC(WP, XP)                                                        \
    _Pragma("unroll 2")                                                        \
    for (int kq = 0; kq < 128; kq += 4) {                                      \
        float w0 = (WP)[(kq + 0) * 64 + o];                                    \
        float w1 = (WP)[(kq + 1) * 64 + o];                                    \
        float w2 = (WP)[(kq + 2) * 64 + o];                                    \
        float w3 = (WP)[(kq + 3) * 64 + o];                                    \
        _Pragma("unroll")                                                      \
        for (int j = 0; j < 4; j++) {                                          \
            float4 xv = *(const float4*)&(XP)[(bl0 + j) * 136 + kq];           \
            acc[j] += xv.x * w0 + xv.y * w1 + xv.z * w2 + xv.w * w3;           \
        }                                                                      \
    }

    if (lay) {
        const float* __restrict__ W0 = g_buf + U1X + (size_t)n * 8192;
        UPD_MAC(W0, xx);
        if (t > 0) {
            const float* __restrict__ W1 = g_buf + U1H + (size_t)n * 8192;
            UPD_MAC(W1, xh);
        }
    } else if (t > 0) {
        const float* __restrict__ W0 = g_buf + U0H + (size_t)n * 8192;
        UPD_MAC(W0, xh);
    }
#undef UPD_MAC

    size_t Hoff = lay ? OFF_H1 : OFF_H0;
    size_t Roff = lay ? OFF_R1 : OFF_R0;
    #pragma unroll
    for (int j = 0; j < 4; j++) {
        int bg = half * 16 + bl0 + j;
        size_t base = (size_t)n * 2048 + (size_t)bg * 64 + o;
        float hc = tanhf(acc[j]);
        float r = g_buf[Roff + base];
        float hold = (t == 0) ? 0.f : g_buf[Hoff + base];
        float hn = r * hold + (1.f - r) * hc;
        g_buf[Hoff + base] = hn;
        if (!lay) g_buf[OFF_OUT0 + (pbase + bg) * 64 + o] = hn;
    }
}

// ---------------- fused attention (t=T-1 only) + LN1; 4 (b,n) per block ----------------
// r13: i4-blocked projection — float4 broadcast x reads, coalesced w loads.
__global__ __launch_bounds__(256) void k_attn() {
    int wid = threadIdx.x >> 6;
    int lane = threadIdx.x & 63;
    int g = blockIdx.x * 4 + wid;
    int b = g / NN, n = g - b * NN;
    __shared__ float x[4][TT][HH], kk[4][TT][HH], vv[4][TT][HH];
    __shared__ float q[4][HH], o1[4][HH], sc[4][HEADS][TT], aw[4][HEADS][TT];
    float mw = g_buf[S_MLW + lane];
    float mb = g_buf[S_MLB + lane];
    #pragma unroll
    for (int tt = 0; tt < TT; tt++) {
        float s = g_buf[S_SRC + ((size_t)b * TT + tt) * NN + n];
        x[wid][tt][lane] = s * mw + mb + g_buf[OFF_PE + tt * HH + lane];
    }
    __syncthreads();
    float ka[TT], va[TT];
    #pragma unroll
    for (int tt = 0; tt < TT; tt++) { ka[tt] = g_buf[S_BK + lane]; va[tt] = g_buf[S_BV + lane]; }
    float qa = g_buf[S_BQ + lane];
    for (int i0 = 0; i0 < HH; i0 += 4) {
        float wk0 = g_buf[S_WK + (i0 + 0) * HH + lane];
        float wk1 = g_buf[S_WK + (i0 + 1) * HH + lane];
        float wk2 = g_buf[S_WK + (i0 + 2) * HH + lane];
        float wk3 = g_buf[S_WK + (i0 + 3) * HH + lane];
        float wv0 = g_buf[S_WV + (i0 + 0) * HH + lane];
        float wv1 = g_buf[S_WV + (i0 + 1) * HH + lane];
        float wv2 = g_buf[S_WV + (i0 + 2) * HH + lane];
        float wv3 = g_buf[S_WV + (i0 + 3) * HH + lane];
        float wq0 = g_buf[S_WQ + (i0 + 0) * HH + lane];
        float wq1 = g_buf[S_WQ + (i0 + 1) * HH + lane];
        float wq2 = g_buf[S_WQ + (i0 + 2) * HH + lane];
        float wq3 = g_buf[S_WQ + (i0 + 3) * HH + lane];
        float4 xq = *(const float4*)&x[wid][TT - 1][i0];
        qa += xq.x * wq0 + xq.y * wq1 + xq.z * wq2 + xq.w * wq3;
        #pragma unroll
        for (int tt = 0; tt < TT; tt++) {
            float4 xv4 = *(const float4*)&x[wid][tt][i0];   // broadcast b128
            ka[tt] += xv4.x * wk0 + xv4.y * wk1 + xv4.z * wk2 + xv4.w * wk3;
            va[tt] += xv4.x * wv0 + xv4.y * wv1 + xv4.z * wv2 + xv4.w * wv3;
        }
    }
    #pragma unroll
    for (int tt = 0; tt < TT; tt++) { kk[wid][tt][lane] = ka[tt]; vv[wid][tt][lane] = va[tt]; }
    q[wid][lane] = qa;
    __syncthreads();
    if (lane < HEADS * TT) {
        int head = lane / TT, ts = lane - head * TT;
        float s = 0.f;
        #pragma unroll
        for (int d = 0; d < HD; d++) s += q[wid][head * HD + d] * kk[wid][ts][head * HD + d];
        sc[wid][head][ts] = s * 0.25f;
    }
    __syncthreads();
    if (lane < HEADS * TT) {
        int head = lane / TT, ts = lane - head * TT;
        float mx = -1e30f;
        #pragma unroll
        for (int j = 0; j < TT; j++) mx = fmaxf(mx, sc[wid][head][j]);
        float sm = 0.f;
        #pragma unroll
        for (int j = 0; j < TT; j++) sm += expf(sc[wid][head][j] - mx);
        aw[wid][head][ts] = expf(sc[wid][head][ts] - mx) / sm;
    }
    __syncthreads();
    int head = lane >> 4;
    float oa = 0.f;
    #pragma unroll
    for (int tt = 0; tt < TT; tt++) oa += aw[wid][head][tt] * vv[wid][tt][lane];
    o1[wid][lane] = oa;
    __syncthreads();
    float acc = g_buf[S_BO + lane];
    for (int i0 = 0; i0 < HH; i0 += 4) {
        float w0 = g_buf[S_WO + (i0 + 0) * HH + lane];
        float w1 = g_buf[S_WO + (i0 + 1) * HH + lane];
        float w2 = g_buf[S_WO + (i0 + 2) * HH + lane];
        float w3 = g_buf[S_WO + (i0 + 3) * HH + lane];
        float4 ov = *(const float4*)&o1[wid][i0];
        acc += ov.x * w0 + ov.y * w1 + ov.z * w2 + ov.w * w3;
    }
    float res = x[wid][TT - 1][lane] + acc;
    float mean = wave_sum(res) * (1.f / 64.f);
    float dv = res - mean;
    float var = wave_sum(dv * dv) * (1.f / 64.f);
    float ln = dv * rsqrtf(var + 1e-5f) * g_buf[S_L1G + lane] + g_buf[S_L1B + lane];
    g_buf[OFF_OLN + ((size_t)b * NN + n) * HH + lane] = ln;
}

// ---------------- FFN + LN2; 8 tokens per block ----------------
// r13 rewrite: phase1 i4-blocked 4-j register tile; phase2 j-split across the
// 4 waves (w2 loaded 1x/block) + cross-wave reduction reusing hid[] LDS.
__global__ __launch_bounds__(256) void k_ffn() {
    int tok0 = blockIdx.x * 8;
    int tid = threadIdx.x;
    int lane = tid & 63, wvid = tid >> 6;
    __shared__ float ox[8][HH];
    __shared__ float hid[8][1024];
    for (int idx = tid; idx < 8 * HH; idx += 256) {
        int tk = idx >> 6, hh = idx & 63;
        ox[tk][hh] = g_buf[OFF_OLN + (size_t)(tok0 + tk) * HH + hh];
    }
    __syncthreads();
    // ---- phase 1: hid = relu(ox @ w1 + b1); thread owns 4 j (tid+256p) x 8 tk ----
    {
        float acc[4][8];
        #pragma unroll
        for (int p = 0; p < 4; p++) {
            float bj = g_buf[S_FB1 + tid + 256 * p];
            #pragma unroll
            for (int tk = 0; tk < 8; tk++) acc[p][tk] = bj;
        }
        for (int i0 = 0; i0 < HH; i0 += 4) {
            float w1r[4][4];
            #pragma unroll
            for (int qq = 0; qq < 4; qq++)
                #pragma unroll
                for (int p = 0; p < 4; p++)
                    w1r[p][qq] = g_buf[S_FW1 + (size_t)(i0 + qq) * 1024 + tid + 256 * p];
            #pragma unroll
            for (int tk = 0; tk < 8; tk++) {
                float4 xo = *(const float4*)&ox[tk][i0];    // broadcast b128
                const float* xp = (const float*)&xo;
                #pragma unroll
                for (int p = 0; p < 4; p++)
                    acc[p][tk] += xp[0] * w1r[p][0] + xp[1] * w1r[p][1]
                                + xp[2] * w1r[p][2] + xp[3] * w1r[p][3];
            }
        }
        #pragma unroll
        for (int p = 0; p < 4; p++)
            #pragma unroll
            for (int tk = 0; tk < 8; tk++)
                hid[tk][tid + 256 * p] = fmaxf(acc[p][tk], 0.f);
    }
    __syncthreads();
    // ---- phase 2: each wave covers j in [wvid*256, wvid*256+256) for ALL 8 tk ----
    float pa[8], pb[8];
    #pragma unroll
    for (int tk = 0; tk < 8; tk++) { pa[tk] = 0.f; pb[tk] = 0.f; }
    {
        int jbase = wvid * 256;
        #pragma unroll 2
        for (int j4 = 0; j4 < 256; j4 += 4) {
            int j0 = jbase + j4;
            float w0 = g_buf[S_FW2 + (size_t)(j0 + 0) * HH + lane];
            float w1 = g_buf[S_FW2 + (size_t)(j0 + 1) * HH + lane];
            float w2 = g_buf[S_FW2 + (size_t)(j0 + 2) * HH + lane];
            float w3 = g_buf[S_FW2 + (size_t)(j0 + 3) * HH + lane];
            #pragma unroll
            for (int tk = 0; tk < 8; tk++) {
                float4 h4 = *(const float4*)&hid[tk][j0];   // broadcast b128
                pa[tk] += h4.x * w0 + h4.y * w1;
                pb[tk] += h4.z * w2 + h4.w * w3;
            }
        }
    }
    __syncthreads();                       // all waves done reading hid
    {
        float* rp = &hid[0][0];            // reuse hid LDS as red[4][8][64]
        #pragma unroll
        for (int tk = 0; tk < 8; tk++)
            rp[(wvid * 8 + tk) * 64 + lane] = pa[tk] + pb[tk];
    }
    __syncthreads();
    int tk = wvid, hh = lane;
    float acc0 = g_buf[S_FB2 + hh], acc1 = acc0;
    {
        const float* rp = &hid[0][0];
        #pragma unroll
        for (int w = 0; w < 4; w++) {
            acc0 += rp[(w * 8 + tk) * 64 + hh];
            acc1 += rp[(w * 8 + tk + 4) * 64 + hh];
        }
    }
    #pragma unroll
    for (int ph = 0; ph < 2; ph++) {
        int tkk = tk + 4 * ph;
        float res = ox[tkk][hh] + (ph ? acc1 : acc0);
        float mean = wave_sum(res) * (1.f / 64.f);
        float dv = res - mean;
        float var = wave_sum(dv * dv) * (1.f / 64.f);
        float ln = dv * rsqrtf(var + 1e-5f) * g_buf[S_L2G + hh] + g_buf[S_L2B + hh];
        g_buf[OFF_O2 + (size_t)(tok0 + tkk) * HH + hh] = ln;
    }
}

// ---------------- final combine + horizon conv (layer-1 h is OFF_H1) ----------------
__global__ void k_final(void* out) {
    int n = blockIdx.x, b = blockIdx.y;
    int h = threadIdx.x;
    __shared__ float comb[HH];
    comb[h] = g_buf[OFF_H1 + ((size_t)n * 32 + b) * 64 + h] * g_buf[S_WS + n * HH + h]
            + g_buf[OFF_O2 + ((size_t)b * NN + n) * 64 + h] * g_buf[S_WT + n * HH + h];
    __syncthreads();
    if (h < HORIZON) {
        float acc = g_buf[S_CB + h];
        #pragma unroll
        for (int i = 0; i < HH; i++) acc += comb[i] * g_buf[S_CW + h * HH + i];
        size_t oi = ((size_t)b * HORIZON + h) * NN + n;
        if (g_flag) ((bf16*)out)[oi] = __float2bfloat16(acc);
        else        ((float*)out)[oi] = acc;
    }
}

extern "C" void kernel_launch(void* const* d_in, const int* in_sizes, int n_in,
                              void* d_out, int out_size, void* d_ws, size_t ws_size,
                              hipStream_t stream) {
    PtrPack pk;
    for (int i = 0; i < 32; i++) pk.p[i] = d_in[i];

    k_detect<<<1, 64, 0, stream>>>(d_in[1]);
    k_ingest<<<4133, 256, 0, stream>>>(pk);
    k_adj<<<NN, 512, 0, stream>>>();
    k_nodew_all<<<22335, 256, 0, stream>>>();
    k_pe<<<1, 768, 0, stream>>>();
    k_ax0<<<dim3(39, 12), 256, 0, stream>>>();
    k_xprep0<<<dim3(12, NN), 256, 0, stream>>>();
    // k_zero removed (r17): (t==0) guards in gateM/updM cover stale H/ZH reads.

    // ---- pipelined supersteps: L0 t=s, L1 t=s-1 ----
    k_gateM<<<dim3(2 * NN, 2), 256, 0, stream>>>(0);
    k_updM<<<dim3(2 * NN, 2), 256, 0, stream>>>(0);
    for (int s = 1; s <= TT; s++) {
        k_aggB<<<dim3(10, 32, 2), 256, 0, stream>>>(s, 0);  // A@H0 (dual->AX1[s-1]), A@H1
        k_gateM<<<dim3(2 * NN, 2), 256, 0, stream>>>(s);
        k_aggB<<<dim3(10, 32, 2), 256, 0, stream>>>(s, 1);  // A@ZH0, A@ZH1
        k_updM<<<dim3(2 * NN, 2), 256, 0, stream>>>(s);
    }

    // ---- transformer branch ----
    k_attn<<<2456, 256, 0, stream>>>();
    k_ffn<<<1228, 256, 0, stream>>>();
    // ---- combine + conv ----
    k_final<<<dim3(NN, BB), 64, 0, stream>>>(d_out);
}